// Round 1
// baseline (4866.230 us; speedup 1.0000x reference)
//
#include <hip/hip_runtime.h>

#define EPSF 1e-5f

// ---------------------------------------------------------------------------
// Conv 3x3, reflect-pad 1, stride 1, + bias + ReLU. fp32 baseline.
// Block: 256 threads = 16x16 output pixels. Each thread: KTILE output chans.
// Loop over input channels in chunks of CCHUNK=8 staged into LDS (18x18 halo).
// ---------------------------------------------------------------------------
template<int KTILE>
__global__ __launch_bounds__(256) void conv3x3_relu(
    const float* __restrict__ in, const float* __restrict__ wgt,
    const float* __restrict__ bias, float* __restrict__ out,
    int C, int K, int H, int W) {
  constexpr int CCHUNK = 8;
  const int tx = threadIdx.x;
  const int px = tx & 15, py = tx >> 4;
  const int w0 = blockIdx.x * 16, h0 = blockIdx.y * 16;
  const int kt_per = K / KTILE;
  const int kt = blockIdx.z % kt_per;
  const int n  = blockIdx.z / kt_per;
  const int k0 = kt * KTILE;

  __shared__ float lds[CCHUNK * 324];  // 18*18 = 324 per channel

  float acc[KTILE];
#pragma unroll
  for (int k = 0; k < KTILE; ++k) acc[k] = 0.f;

  const float* inN = in + (size_t)n * C * H * W;

  for (int cb = 0; cb < C; cb += CCHUNK) {
    // stage CCHUNK channels of the 18x18 halo tile (reflect boundary)
    for (int e = tx; e < CCHUNK * 324; e += 256) {
      int cc = e / 324;
      int r  = e - cc * 324;
      int y = r / 18, x = r - y * 18;
      int gy = h0 - 1 + y; gy = gy < 0 ? -gy : (gy >= H ? 2 * H - 2 - gy : gy);
      int gx = w0 - 1 + x; gx = gx < 0 ? -gx : (gx >= W ? 2 * W - 2 - gx : gx);
      lds[e] = inN[((cb + cc) * H + gy) * W + gx];
    }
    __syncthreads();
#pragma unroll 1
    for (int cc = 0; cc < CCHUNK; ++cc) {
      const float* t = &lds[cc * 324 + py * 18 + px];
      float x0 = t[0],  x1 = t[1],  x2 = t[2];
      float x3 = t[18], x4 = t[19], x5 = t[20];
      float x6 = t[36], x7 = t[37], x8 = t[38];
      const float* wp = wgt + ((size_t)k0 * C + (cb + cc)) * 9;
#pragma unroll
      for (int k = 0; k < KTILE; ++k) {
        const float* wk = wp + (size_t)k * C * 9;
        acc[k] += x0 * wk[0] + x1 * wk[1] + x2 * wk[2]
                + x3 * wk[3] + x4 * wk[4] + x5 * wk[5]
                + x6 * wk[6] + x7 * wk[7] + x8 * wk[8];
      }
    }
    __syncthreads();
  }

  size_t obase = (((size_t)n * K + k0) * H + (h0 + py)) * W + (w0 + px);
#pragma unroll
  for (int k = 0; k < KTILE; ++k) {
    float v = acc[k] + bias[k0 + k];
    out[obase + (size_t)k * H * W] = v > 0.f ? v : 0.f;
  }
}

// ---------------------------------------------------------------------------
// Wavelet unpool (k=2,s=2 grouped convT with Haar filters) fused with the
// rpad(1)+crop shift:  y[i][j] = unpool[|i-1|][|j-1|]  (reflect at leading edge)
// out dims: NC x 2Hh x 2Wh
// ---------------------------------------------------------------------------
__global__ void unpool_shift(const float* __restrict__ ll, const float* __restrict__ lh,
                             const float* __restrict__ hl, const float* __restrict__ hh,
                             float* __restrict__ out, int NC, int Hh, int Wh) {
  const int Wo = 2 * Wh, Ho = 2 * Hh;
  size_t total = (size_t)NC * Ho * Wo;
  size_t idx = (size_t)blockIdx.x * blockDim.x + threadIdx.x;
  if (idx >= total) return;
  int j  = (int)(idx % Wo);
  int i  = (int)((idx / Wo) % Ho);
  int nc = (int)(idx / ((size_t)Wo * Ho));
  int si = (i == 0) ? 1 : i - 1;
  int sj = (j == 0) ? 1 : j - 1;
  float sa = (si & 1) ? 1.f : -1.f;
  float sb = (sj & 1) ? 1.f : -1.f;
  size_t base = ((size_t)nc * Hh + (si >> 1)) * Wh + (sj >> 1);
  out[idx] = 0.5f * (ll[base] + sb * lh[base] + sa * hl[base] + sa * sb * hh[base]);
}

// ---------------------------------------------------------------------------
// Final wavelet unpool fused with rpad(1) (no crop): out 258x258 from 128 bands
// ---------------------------------------------------------------------------
__global__ void unpool_rpad(const float* __restrict__ ll, const float* __restrict__ lh,
                            const float* __restrict__ hl, const float* __restrict__ hh,
                            float* __restrict__ out, int NC, int Hh, int Wh) {
  const int Hu = 2 * Hh, Wu = 2 * Wh;          // 256
  const int Wo = Wu + 2, Ho = Hu + 2;          // 258
  size_t total = (size_t)NC * Ho * Wo;
  size_t idx = (size_t)blockIdx.x * blockDim.x + threadIdx.x;
  if (idx >= total) return;
  int j  = (int)(idx % Wo);
  int i  = (int)((idx / Wo) % Ho);
  int nc = (int)(idx / ((size_t)Wo * Ho));
  int si = i - 1; si = si < 0 ? -si : (si >= Hu ? 2 * Hu - 2 - si : si);
  int sj = j - 1; sj = sj < 0 ? -sj : (sj >= Wu ? 2 * Wu - 2 - sj : sj);
  float sa = (si & 1) ? 1.f : -1.f;
  float sb = (sj & 1) ? 1.f : -1.f;
  size_t base = ((size_t)nc * Hh + (si >> 1)) * Wh + (sj >> 1);
  out[idx] = 0.5f * (ll[base] + sb * lh[base] + sa * hl[base] + sa * sb * hh[base]);
}

// ---------------------------------------------------------------------------
// AdaIN support kernels
// ---------------------------------------------------------------------------
// Pack 8 class masks (downsampled ::2, first 128) into per-pixel bitmasks.
__global__ void pack_masks(const float* __restrict__ cmask, const float* __restrict__ smask,
                           unsigned* __restrict__ cbits, unsigned* __restrict__ sbits) {
  int idx = blockIdx.x * 256 + threadIdx.x;   // < 16384
  if (idx >= 16384) return;
  int h = idx >> 7, w = idx & 127;
  unsigned cb = 0, sb = 0;
#pragma unroll
  for (int k = 0; k < 8; ++k) {
    int off = (k * 256 + 2 * h) * 256 + 2 * w;
    if (cmask[off] != 0.f) cb |= (1u << k);
    if (smask[off] != 0.f) sb |= (1u << k);
  }
  cbits[idx] = cb;
  sbits[idx] = sb;
}

// Per-class any() over the FULL 256x256 masks. flagc[k] = any(cmask[k]),
// sany[k] = any(smask[k]).
__global__ void mask_flags(const float* __restrict__ cmask, const float* __restrict__ smask,
                           float* __restrict__ flagc, float* __restrict__ sany) {
  int k = blockIdx.x;
  const float* cm = cmask + (size_t)k * 65536;
  const float* sm = smask + (size_t)k * 65536;
  int ca = 0, sa = 0;
  for (int i = threadIdx.x; i < 65536; i += 256) {
    ca |= (cm[i] != 0.f);
    sa |= (sm[i] != 0.f);
  }
#pragma unroll
  for (int off = 32; off > 0; off >>= 1) {
    ca |= __shfl_xor(ca, off, 64);
    sa |= __shfl_xor(sa, off, 64);
  }
  __shared__ int rc[4], rs[4];
  int wv = threadIdx.x >> 6;
  if ((threadIdx.x & 63) == 0) { rc[wv] = ca; rs[wv] = sa; }
  __syncthreads();
  if (threadIdx.x == 0) {
    flagc[k] = (rc[0] | rc[1] | rc[2] | rc[3]) ? 1.f : 0.f;
    sany[k]  = (rs[0] | rs[1] | rs[2] | rs[3]) ? 1.f : 0.f;
  }
}

// Masked per-class stats over 128x128 per (n,c): cnt/s1/s2 for each of 8
// classes; optionally global stats. feat is raw; EPS added here.
// out layout: out[(k*3+comp)*NC + b]; gout[comp*NC + b].
template<bool GLOBAL>
__global__ __launch_bounds__(256) void masked_stats_k(
    const float* __restrict__ feat, const unsigned* __restrict__ bits,
    float* __restrict__ out, float* __restrict__ gout, int NC) {
  constexpr int NV = GLOBAL ? 27 : 24;
  const int b = blockIdx.x;
  const float* f = feat + (size_t)b * 16384;
  float acc[NV];
#pragma unroll
  for (int j = 0; j < NV; ++j) acc[j] = 0.f;

  for (int i = threadIdx.x; i < 16384; i += 256) {
    float v  = f[i] + EPSF;
    float nz = (v != 0.f) ? 1.f : 0.f;
    float v2 = v * v;
    unsigned m = bits[i];
#pragma unroll
    for (int k = 0; k < 8; ++k) {
      float mk = (float)((m >> k) & 1u);
      acc[k * 3 + 0] += mk * nz;
      acc[k * 3 + 1] += mk * v;
      acc[k * 3 + 2] += mk * v2;
    }
    if (GLOBAL) { acc[24] += nz; acc[25] += v; acc[26] += v2; }
  }

#pragma unroll
  for (int j = 0; j < NV; ++j) {
    float v = acc[j];
#pragma unroll
    for (int off = 32; off > 0; off >>= 1) v += __shfl_xor(v, off, 64);
    acc[j] = v;
  }
  __shared__ float red[4][NV];
  int lane = threadIdx.x & 63, wv = threadIdx.x >> 6;
  if (lane == 0) {
#pragma unroll
    for (int j = 0; j < NV; ++j) red[wv][j] = acc[j];
  }
  __syncthreads();
  int tid = threadIdx.x;
  if (tid < NV) {
    float s = red[0][tid] + red[1][tid] + red[2][tid] + red[3][tid];
    if (tid < 24) out[tid * NC + b] = s;
    else if (GLOBAL) gout[(tid - 24) * NC + b] = s;
  }
}

// scale/shift per (k,n,c)
__global__ void finalize_ss(const float* __restrict__ cst, const float* __restrict__ sst,
                            const float* __restrict__ gst, const float* __restrict__ flagc,
                            const float* __restrict__ sany,
                            float* __restrict__ scal, float* __restrict__ shft, int NC) {
  int idx = blockIdx.x * blockDim.x + threadIdx.x;
  if (idx >= 8 * NC) return;
  int k = idx / NC, b = idx - k * NC;
  float ccnt = cst[(k * 3 + 0) * NC + b];
  float cs1  = cst[(k * 3 + 1) * NC + b];
  float cs2  = cst[(k * 3 + 2) * NC + b];
  float cmn  = cs1 / fmaxf(ccnt, 1.f);
  float cvv  = (cs2 - ccnt * cmn * cmn) / fmaxf(ccnt - 1.f, 1.f) + EPSF;
  float cstd = sqrtf(cvv);
  float scnt, ss1, ss2;
  if (sany[k] == 0.f) {
    scnt = gst[0 * NC + b]; ss1 = gst[1 * NC + b]; ss2 = gst[2 * NC + b];
  } else {
    scnt = sst[(k * 3 + 0) * NC + b];
    ss1  = sst[(k * 3 + 1) * NC + b];
    ss2  = sst[(k * 3 + 2) * NC + b];
  }
  float smn  = ss1 / fmaxf(scnt, 1.f);
  float svv  = (ss2 - scnt * smn * smn) / fmaxf(scnt - 1.f, 1.f) + EPSF;
  float sstd = sqrtf(svv);
  float fl = flagc[k];
  float r  = sstd / cstd;
  scal[idx] = fl * r;
  shft[idx] = fl * (smn - cmn * r);
}

// res = cfe * sum_k cm_k*scale_k + sum_k cm_k*shift_k
__global__ void adain_apply(const float* __restrict__ content, const unsigned* __restrict__ bits,
                            const float* __restrict__ scal, const float* __restrict__ shft,
                            float* __restrict__ out, int NC) {
  int b = blockIdx.x;
  float sc[8], sh[8];
#pragma unroll
  for (int k = 0; k < 8; ++k) { sc[k] = scal[k * NC + b]; sh[k] = shft[k * NC + b]; }
  const float* src = content + (size_t)b * 16384;
  float* dst = out + (size_t)b * 16384;
  for (int i = threadIdx.x; i < 16384; i += 256) {
    float v = src[i] + EPSF;
    unsigned m = bits[i];
    float a = 0.f, d = 0.f;
#pragma unroll
    for (int k = 0; k < 8; ++k) {
      float mk = (float)((m >> k) & 1u);
      a += mk * sc[k];
      d += mk * sh[k];
    }
    dst[i] = v * a + d;
  }
}

// ---------------------------------------------------------------------------
static void launch_conv(const float* in, const float* w, const float* b, float* out,
                        int C, int K, int H, int W, int ktile, hipStream_t s) {
  dim3 grid(W / 16, H / 16, 4 * (K / ktile));
  if (ktile == 8) conv3x3_relu<8><<<grid, 256, 0, s>>>(in, w, b, out, C, K, H, W);
  else            conv3x3_relu<16><<<grid, 256, 0, s>>>(in, w, b, out, C, K, H, W);
}

extern "C" void kernel_launch(void* const* d_in, const int* in_sizes, int n_in,
                              void* d_out, int out_size, void* d_ws, size_t ws_size,
                              hipStream_t stream) {
  const float* f1   = (const float*)d_in[0];
  const float* f2   = (const float*)d_in[1];
  const float* s2lh = (const float*)d_in[2];
  const float* s2hl = (const float*)d_in[3];
  const float* s2hh = (const float*)d_in[4];
  const float* s1lh = (const float*)d_in[5];
  const float* s1hl = (const float*)d_in[6];
  const float* s1hh = (const float*)d_in[7];
  const float* s0lh = (const float*)d_in[8];
  const float* s0hl = (const float*)d_in[9];
  const float* s0hh = (const float*)d_in[10];
  const float* cmask = (const float*)d_in[11];
  const float* smask = (const float*)d_in[12];
  const float* w11 = (const float*)d_in[13]; const float* b11 = (const float*)d_in[14];
  const float* w12 = (const float*)d_in[15]; const float* b12 = (const float*)d_in[16];
  const float* w21 = (const float*)d_in[17]; const float* b21 = (const float*)d_in[18];
  const float* w22 = (const float*)d_in[19]; const float* b22 = (const float*)d_in[20];
  const float* w23 = (const float*)d_in[21]; const float* b23 = (const float*)d_in[22];
  const float* w24 = (const float*)d_in[23]; const float* b24 = (const float*)d_in[24];
  const float* w31 = (const float*)d_in[25]; const float* b31 = (const float*)d_in[26];
  const float* w32 = (const float*)d_in[27]; const float* b32 = (const float*)d_in[28];
  const float* w33 = (const float*)d_in[29]; const float* b33 = (const float*)d_in[30];

  // Ping-pong buffers live inside d_out (each 8,388,608 floats; total 67.1MB
  // of the 68.2MB output buffer). Final kernel rewrites all of d_out.
  float* A = (float*)d_out;
  float* B = A + 8388608;

  // Workspace layout (floats)
  float* Wf   = (float*)d_ws;
  float* t12  = Wf;                 // 4,194,304
  float* cst  = Wf + 4194304;       // 24*512
  float* sst  = cst + 12288;        // 24*512
  float* gst  = sst + 12288;        // 3*512
  float* scal = gst + 1536;         // 8*512
  float* shft = scal + 4096;        // 8*512
  float* flagc = shft + 4096;       // 8
  float* sany  = flagc + 8;         // 8
  unsigned* cbits = (unsigned*)(sany + 8);   // 16384
  unsigned* sbits = cbits + 16384;           // 16384

  const int NC = 512;  // 4*128 for AdaIN stage

  // mask preprocessing (independent)
  pack_masks<<<64, 256, 0, stream>>>(cmask, smask, cbits, sbits);
  mask_flags<<<8, 256, 0, stream>>>(cmask, smask, flagc, sany);

  // L1: f2 (4,512,32,32) -> A (4,512,32,32)
  launch_conv(f2, w11, b11, A, 512, 512, 32, 32, 8, stream);
  // L2: -> B (4,256,32,32)
  launch_conv(A, w12, b12, B, 512, 256, 32, 32, 8, stream);
  // unpool+shift: B + s2 -> A (4,256,64,64)
  unpool_shift<<<4194304 / 256, 256, 0, stream>>>(B, s2lh, s2hl, s2hh, A, 1024, 32, 32);
  // L3..L5: 256->256 @64
  launch_conv(A, w21, b21, B, 256, 256, 64, 64, 16, stream);
  launch_conv(B, w22, b22, A, 256, 256, 64, 64, 16, stream);
  launch_conv(A, w23, b23, B, 256, 256, 64, 64, 16, stream);
  // L6: 256->128 @64 : B -> A (4,128,64,64)
  launch_conv(B, w24, b24, A, 256, 128, 64, 64, 8, stream);
  // unpool+shift: A + s1 -> B (4,128,128,128)
  unpool_shift<<<8388608 / 256, 256, 0, stream>>>(A, s1lh, s1hl, s1hh, B, 512, 64, 64);

  // AdaIN: content=B, style=f1 -> A
  masked_stats_k<false><<<512, 256, 0, stream>>>(B, cbits, cst, nullptr, NC);
  masked_stats_k<true><<<512, 256, 0, stream>>>(f1, sbits, sst, gst, NC);
  finalize_ss<<<16, 256, 0, stream>>>(cst, sst, gst, flagc, sany, scal, shft, NC);
  adain_apply<<<512, 256, 0, stream>>>(B, cbits, scal, shft, A, NC);

  // L7..L8: 128->128 @128
  launch_conv(A, w31, b31, B, 128, 128, 128, 128, 16, stream);
  launch_conv(B, w32, b32, A, 128, 128, 128, 128, 16, stream);
  // L9: 128->64 @128 : A -> t12 (ws)
  launch_conv(A, w33, b33, t12, 128, 64, 128, 128, 8, stream);

  // final unpool + rpad -> d_out (4,64,258,258)
  unpool_rpad<<<66564, 256, 0, stream>>>(t12, s0lh, s0hl, s0hh, (float*)d_out, 256, 128, 128);
}

// Round 3
// 1187.831 us; speedup vs baseline: 4.0967x; 4.0967x over previous
//
#include <hip/hip_runtime.h>

#define EPSF 1e-5f

typedef __attribute__((ext_vector_type(8)))  short short8;
typedef __attribute__((ext_vector_type(16))) float f32x16;

__device__ __forceinline__ unsigned short f2bf(float f) {
  unsigned u = __builtin_bit_cast(unsigned, f);
  unsigned r = (u + 0x7FFFu + ((u >> 16) & 1u)) >> 16;   // RNE
  return (unsigned short)r;
}
__device__ __forceinline__ float bf2f(unsigned short h) {
  unsigned u = ((unsigned)h) << 16;
  return __builtin_bit_cast(float, u);
}

// ---------------------------------------------------------------------------
// Weight pre-transpose: W[K][C][3][3] fp32 -> Wt[tap][C/8][K][8] bf16
// ---------------------------------------------------------------------------
__global__ void wt_prep(const float* __restrict__ w, unsigned short* __restrict__ wt,
                        int C, int K) {
  int C8 = C >> 3;
  int idx = blockIdx.x * 256 + threadIdx.x;
  if (idx >= K * C8) return;
  int k = idx / C8, ch = idx - k * C8;
  const float* src = w + ((size_t)k * C + ch * 8) * 9;
#pragma unroll
  for (int tap = 0; tap < 9; ++tap) {
    short8 v;
#pragma unroll
    for (int cl = 0; cl < 8; ++cl) v[cl] = (short)f2bf(src[cl * 9 + tap]);
    *(short8*)(wt + ((size_t)(tap * C8 + ch) * K + k) * 8) = v;
  }
}

// ---------------------------------------------------------------------------
// fp32 NCHW -> bf16 NC8HW8
// ---------------------------------------------------------------------------
__global__ void nchw_to_nc8(const float* __restrict__ in, unsigned short* __restrict__ out,
                            int C8, int HW, int total) {
  int idx = blockIdx.x * 256 + threadIdx.x;
  if (idx >= total) return;
  int pix = idx % HW; int t = idx / HW; int ch = t % C8; int n = t / C8;
  const float* s = in + ((size_t)(n * C8 + ch) * 8) * HW + pix;
  short8 v;
#pragma unroll
  for (int cl = 0; cl < 8; ++cl) v[cl] = (short)f2bf(s[(size_t)cl * HW]);
  *(short8*)(out + (size_t)idx * 8) = v;
}

// ---------------------------------------------------------------------------
// Conv 3x3 reflect-pad + bias + ReLU, bf16 MFMA implicit GEMM.
// act: NC8HW8 bf16, wt: [9][C/8][K][8] bf16, out: NC8HW8 bf16.
// Block: 256 thr = 4 waves. Tile: 64 out-chans x 256 pixels (16x16).
// Wave: 64 chans x 64 pixels via 2x2 frags of mfma_f32_32x32x16_bf16.
// ---------------------------------------------------------------------------
__global__ __launch_bounds__(256) void conv3x3_mfma(
    const unsigned short* __restrict__ act, const unsigned short* __restrict__ wt,
    const float* __restrict__ bias, unsigned short* __restrict__ out,
    int C, int K, int H, int W) {
  const int C8 = C >> 3, K8 = K >> 3;
  const int HW = H * W;
  const int tid = threadIdx.x;
  const int lane = tid & 63, wid = tid >> 6;
  const int l31 = lane & 31, lhi = lane >> 5;
  const int w0 = blockIdx.x * 16, h0 = blockIdx.y * 16;
  const int kbn = K >> 6;
  const int kb = blockIdx.z % kbn;
  const int n  = blockIdx.z / kbn;
  const int k0 = kb * 64;

  __shared__ __align__(16) unsigned short smem[16384];  // 32 KB
  __shared__ float sbias[64];
  if (tid < 64) sbias[tid] = bias[k0 + tid];

  // staging address precompute: 1296 slots (16B each), padded to 1536
  int g16[6];
#pragma unroll
  for (int it = 0; it < 6; ++it) {
    int slot = it * 256 + wid * 64 + lane;
    int s = slot < 1296 ? slot : 0;
    int chi = s / 324; int r = s - chi * 324;
    int y = r / 18, x = r - y * 18;
    int gy = h0 - 1 + y; gy = gy < 0 ? -gy : (gy >= H ? 2 * H - 2 - gy : gy);
    int gx = w0 - 1 + x; gx = gx < 0 ? -gx : (gx >= W ? 2 * W - 2 - gx : gx);
    g16[it] = ((n * C8 + chi) * H + gy) * W + gx;
  }

  // B-fragment pixel coords (fixed per lane)
  const int pbase = wid * 64;
  int pb[2];
#pragma unroll
  for (int nf = 0; nf < 2; ++nf) {
    int p = pbase + nf * 32 + l31;
    pb[nf] = (p >> 4) * 18 + (p & 15);
  }
  // A-fragment per-lane weight offset pieces
  int wb[2][2];
#pragma unroll
  for (int ks = 0; ks < 2; ++ks)
#pragma unroll
    for (int mf = 0; mf < 2; ++mf)
      wb[ks][mf] = (ks * 2 + lhi) * K + k0 + mf * 32 + l31;

  f32x16 acc[2][2] = {};

  const int nchunk = C >> 5;
  for (int ci = 0; ci < nchunk; ++ci) {
    __syncthreads();
#pragma unroll
    for (int it = 0; it < 6; ++it) {
      const unsigned short* g = act + ((size_t)g16[it] + (size_t)ci * 4 * HW) * 8;
      __builtin_amdgcn_global_load_lds(
          (const __attribute__((address_space(1))) unsigned int*)g,
          (__attribute__((address_space(3))) unsigned int*)&smem[(it * 256 + wid * 64) * 8],
          16, 0, 0);
    }
    __syncthreads();

    for (int tap = 0; tap < 9; ++tap) {
      int ty = tap / 3, txx = tap - ty * 3;
      int tapoff = ty * 18 + txx;
      short8 a[2][2], b[2][2];
#pragma unroll
      for (int ks = 0; ks < 2; ++ks) {
#pragma unroll
        for (int mf = 0; mf < 2; ++mf) {
          size_t off = ((size_t)(tap * C8 + ci * 4) * K + wb[ks][mf]) * 8;
          a[mf][ks] = *(const short8*)(wt + off);
        }
#pragma unroll
        for (int nf = 0; nf < 2; ++nf) {
          int ls = ((ks * 2 + lhi) * 324 + pb[nf] + tapoff) * 8;
          b[nf][ks] = *(const short8*)&smem[ls];
        }
      }
#pragma unroll
      for (int ks = 0; ks < 2; ++ks)
#pragma unroll
        for (int mf = 0; mf < 2; ++mf)
#pragma unroll
          for (int nf = 0; nf < 2; ++nf)
            acc[mf][nf] = __builtin_amdgcn_mfma_f32_32x32x16_bf16(
                a[mf][ks], b[nf][ks], acc[mf][nf], 0, 0, 0);
    }
  }

  // epilogue: bias + relu + pack bf16 into smem as NC8HW8 tile [ch8][pix256][8]
  __syncthreads();
#pragma unroll
  for (int mf = 0; mf < 2; ++mf)
#pragma unroll
    for (int nf = 0; nf < 2; ++nf) {
      int pix = pbase + nf * 32 + l31;
#pragma unroll
      for (int rp = 0; rp < 8; ++rp) {
        const int r0 = rp * 2;
        int row0 = (r0 & 3) + 8 * (r0 >> 2) + 4 * lhi;   // row within 32
        int c64 = mf * 32 + row0;
        float v0 = acc[mf][nf][r0]     + sbias[c64];
        float v1 = acc[mf][nf][r0 + 1] + sbias[c64 + 1];
        v0 = v0 > 0.f ? v0 : 0.f;
        v1 = v1 > 0.f ? v1 : 0.f;
        unsigned pk = (unsigned)f2bf(v0) | ((unsigned)f2bf(v1) << 16);
        int chh = mf * 4 + (r0 >> 2);
        int clo = (r0 & 3) + 4 * lhi;
        *(unsigned*)&smem[((chh * 256 + pix) * 8 + clo)] = pk;
      }
    }
  __syncthreads();
  // coalesced copy-out
#pragma unroll
  for (int i = 0; i < 8; ++i) {
    int slot = i * 256 + tid;           // 2048 slots of 16B
    int ch = slot >> 8;
    int p = slot & 255;
    int py = p >> 4, px = p & 15;
    short8 v = *(const short8*)&smem[slot * 8];
    *(short8*)(out + (((size_t)(n * K8 + (k0 >> 3) + ch) * H + h0 + py) * W + w0 + px) * 8) = v;
  }
}

// ---------------------------------------------------------------------------
// Wavelet unpool fused with rpad(1)+crop shift, NC8HW8 bf16 ll / fp32 bands.
// out NC8HW8 bf16, dims N x C x 2Hh x 2Wh
// ---------------------------------------------------------------------------
__global__ void unpool_shift_nc8(const unsigned short* __restrict__ ll,
                                 const float* __restrict__ lh, const float* __restrict__ hl,
                                 const float* __restrict__ hh, unsigned short* __restrict__ out,
                                 int C8, int Hh, int Wh, int total) {
  int idx = blockIdx.x * 256 + threadIdx.x;
  if (idx >= total) return;
  const int Ho = 2 * Hh, Wo = 2 * Wh;
  int j = idx % Wo; int t = idx / Wo;
  int i = t % Ho; t /= Ho;
  int ch = t % C8; int n = t / C8;
  int si = (i == 0) ? 1 : i - 1;
  int sj = (j == 0) ? 1 : j - 1;
  float sa = (si & 1) ? 1.f : -1.f;
  float sb = (sj & 1) ? 1.f : -1.f;
  int hy = si >> 1, hx = sj >> 1;
  size_t HWh = (size_t)Hh * Wh;
  const unsigned short* lp = ll + ((size_t)(n * C8 + ch) * HWh + hy * Wh + hx) * 8;
  size_t bb = ((size_t)(n * C8 + ch) * 8 * Hh + hy) * Wh + hx;
  short8 res;
#pragma unroll
  for (int cl = 0; cl < 8; ++cl) {
    float v = 0.5f * (bf2f(lp[cl]) + sb * lh[bb + cl * HWh] + sa * hl[bb + cl * HWh]
                      + sa * sb * hh[bb + cl * HWh]);
    res[cl] = (short)f2bf(v);
  }
  *(short8*)(out + (size_t)idx * 8) = res;
}

// ---------------------------------------------------------------------------
// Final unpool fused with rpad(1): NC8HW8 bf16 ll -> fp32 NCHW d_out (4,64,258,258)
// ---------------------------------------------------------------------------
__global__ void unpool_rpad_final(const unsigned short* __restrict__ ll,
                                  const float* __restrict__ lh, const float* __restrict__ hl,
                                  const float* __restrict__ hh, float* __restrict__ out) {
  size_t idx = (size_t)blockIdx.x * 256 + threadIdx.x;
  if (idx >= (size_t)4 * 64 * 258 * 258) return;
  int j = (int)(idx % 258); size_t t = idx / 258;
  int i = (int)(t % 258); t /= 258;
  int c = (int)(t & 63); int n = (int)(t >> 6);
  int si = i - 1; si = si < 0 ? -si : (si >= 256 ? 510 - si : si);
  int sj = j - 1; sj = sj < 0 ? -sj : (sj >= 256 ? 510 - sj : sj);
  float sa = (si & 1) ? 1.f : -1.f;
  float sb = (sj & 1) ? 1.f : -1.f;
  int hy = si >> 1, hx = sj >> 1;
  float lv = bf2f(ll[((size_t)(n * 8 + (c >> 3)) * 16384 + hy * 128 + hx) * 8 + (c & 7)]);
  size_t bb = ((size_t)(n * 64 + c) * 128 + hy) * 128 + hx;
  out[idx] = 0.5f * (lv + sb * lh[bb] + sa * hl[bb] + sa * sb * hh[bb]);
}

// ---------------------------------------------------------------------------
// AdaIN support
// ---------------------------------------------------------------------------
__global__ void pack_masks(const float* __restrict__ cmask, const float* __restrict__ smask,
                           unsigned* __restrict__ cbits, unsigned* __restrict__ sbits) {
  int idx = blockIdx.x * 256 + threadIdx.x;
  if (idx >= 16384) return;
  int h = idx >> 7, w = idx & 127;
  unsigned cb = 0, sb = 0;
#pragma unroll
  for (int k = 0; k < 8; ++k) {
    int off = (k * 256 + 2 * h) * 256 + 2 * w;
    if (cmask[off] != 0.f) cb |= (1u << k);
    if (smask[off] != 0.f) sb |= (1u << k);
  }
  cbits[idx] = cb;
  sbits[idx] = sb;
}

__global__ void mask_flags(const float* __restrict__ cmask, const float* __restrict__ smask,
                           float* __restrict__ flagc, float* __restrict__ sany) {
  int k = blockIdx.x;
  const float* cm = cmask + (size_t)k * 65536;
  const float* sm = smask + (size_t)k * 65536;
  int ca = 0, sa = 0;
  for (int i = threadIdx.x; i < 65536; i += 256) {
    ca |= (cm[i] != 0.f);
    sa |= (sm[i] != 0.f);
  }
#pragma unroll
  for (int off = 32; off > 0; off >>= 1) {
    ca |= __shfl_xor(ca, off, 64);
    sa |= __shfl_xor(sa, off, 64);
  }
  __shared__ int rc[4], rs[4];
  int wv = threadIdx.x >> 6;
  if ((threadIdx.x & 63) == 0) { rc[wv] = ca; rs[wv] = sa; }
  __syncthreads();
  if (threadIdx.x == 0) {
    flagc[k] = (rc[0] | rc[1] | rc[2] | rc[3]) ? 1.f : 0.f;
    sany[k]  = (rs[0] | rs[1] | rs[2] | rs[3]) ? 1.f : 0.f;
  }
}

// content stats (bf16 NC8HW8): per (n,c) block
__global__ __launch_bounds__(256) void masked_stats_bf16(
    const unsigned short* __restrict__ feat, const unsigned* __restrict__ bits,
    float* __restrict__ outp, int NC) {
  constexpr int NV = 24;
  int b = blockIdx.x; int n = b >> 7, c = b & 127;
  const unsigned short* f = feat + (size_t)(n * 16 + (c >> 3)) * 16384 * 8 + (c & 7);
  float acc[NV];
#pragma unroll
  for (int j = 0; j < NV; ++j) acc[j] = 0.f;
  for (int i = threadIdx.x; i < 16384; i += 256) {
    float v = bf2f(f[(size_t)i * 8]) + EPSF;
    float nz = (v != 0.f) ? 1.f : 0.f;
    float v2 = v * v;
    unsigned m = bits[i];
#pragma unroll
    for (int k = 0; k < 8; ++k) {
      float mk = (float)((m >> k) & 1u);
      acc[k * 3 + 0] += mk * nz;
      acc[k * 3 + 1] += mk * v;
      acc[k * 3 + 2] += mk * v2;
    }
  }
#pragma unroll
  for (int j = 0; j < NV; ++j) {
    float v = acc[j];
#pragma unroll
    for (int off = 32; off > 0; off >>= 1) v += __shfl_xor(v, off, 64);
    acc[j] = v;
  }
  __shared__ float red[4][NV];
  int lane = threadIdx.x & 63, wv = threadIdx.x >> 6;
  if (lane == 0) {
#pragma unroll
    for (int j = 0; j < NV; ++j) red[wv][j] = acc[j];
  }
  __syncthreads();
  int tid = threadIdx.x;
  if (tid < NV) {
    float s = red[0][tid] + red[1][tid] + red[2][tid] + red[3][tid];
    outp[tid * NC + b] = s;
  }
}

// style stats (fp32 NCHW) with global stats
__global__ __launch_bounds__(256) void masked_stats_f32g(
    const float* __restrict__ feat, const unsigned* __restrict__ bits,
    float* __restrict__ outp, float* __restrict__ gout, int NC) {
  constexpr int NV = 27;
  const int b = blockIdx.x;
  const float* f = feat + (size_t)b * 16384;
  float acc[NV];
#pragma unroll
  for (int j = 0; j < NV; ++j) acc[j] = 0.f;
  for (int i = threadIdx.x; i < 16384; i += 256) {
    float v = f[i] + EPSF;
    float nz = (v != 0.f) ? 1.f : 0.f;
    float v2 = v * v;
    unsigned m = bits[i];
#pragma unroll
    for (int k = 0; k < 8; ++k) {
      float mk = (float)((m >> k) & 1u);
      acc[k * 3 + 0] += mk * nz;
      acc[k * 3 + 1] += mk * v;
      acc[k * 3 + 2] += mk * v2;
    }
    acc[24] += nz; acc[25] += v; acc[26] += v2;
  }
#pragma unroll
  for (int j = 0; j < NV; ++j) {
    float v = acc[j];
#pragma unroll
    for (int off = 32; off > 0; off >>= 1) v += __shfl_xor(v, off, 64);
    acc[j] = v;
  }
  __shared__ float red[4][NV];
  int lane = threadIdx.x & 63, wv = threadIdx.x >> 6;
  if (lane == 0) {
#pragma unroll
    for (int j = 0; j < NV; ++j) red[wv][j] = acc[j];
  }
  __syncthreads();
  int tid = threadIdx.x;
  if (tid < NV) {
    float s = red[0][tid] + red[1][tid] + red[2][tid] + red[3][tid];
    if (tid < 24) outp[tid * NC + b] = s;
    else gout[(tid - 24) * NC + b] = s;
  }
}

__global__ void finalize_ss(const float* __restrict__ cst, const float* __restrict__ sst,
                            const float* __restrict__ gst, const float* __restrict__ flagc,
                            const float* __restrict__ sany,
                            float* __restrict__ scal, float* __restrict__ shft, int NC) {
  int idx = blockIdx.x * blockDim.x + threadIdx.x;
  if (idx >= 8 * NC) return;
  int k = idx / NC, b = idx - k * NC;
  float ccnt = cst[(k * 3 + 0) * NC + b];
  float cs1  = cst[(k * 3 + 1) * NC + b];
  float cs2  = cst[(k * 3 + 2) * NC + b];
  float cmn  = cs1 / fmaxf(ccnt, 1.f);
  float cvv  = (cs2 - ccnt * cmn * cmn) / fmaxf(ccnt - 1.f, 1.f) + EPSF;
  float cstd = sqrtf(cvv);
  float scnt, ss1, ss2;
  if (sany[k] == 0.f) {
    scnt = gst[0 * NC + b]; ss1 = gst[1 * NC + b]; ss2 = gst[2 * NC + b];
  } else {
    scnt = sst[(k * 3 + 0) * NC + b];
    ss1  = sst[(k * 3 + 1) * NC + b];
    ss2  = sst[(k * 3 + 2) * NC + b];
  }
  float smn  = ss1 / fmaxf(scnt, 1.f);
  float svv  = (ss2 - scnt * smn * smn) / fmaxf(scnt - 1.f, 1.f) + EPSF;
  float sstd = sqrtf(svv);
  float fl = flagc[k];
  float r  = sstd / cstd;
  scal[idx] = fl * r;
  shft[idx] = fl * (smn - cmn * r);
}

// apply, NC8HW8 bf16 in/out; block per (n, c_hi) of content C=128
__global__ void adain_apply_nc8(const unsigned short* __restrict__ content,
                                const unsigned* __restrict__ bits,
                                const float* __restrict__ scal, const float* __restrict__ shft,
                                unsigned short* __restrict__ out) {
  int ch = blockIdx.x & 15, n = blockIdx.x >> 4;
  __shared__ float ssc[8][8], ssh[8][8];
  if (threadIdx.x < 64) {
    int k = threadIdx.x >> 3, cl = threadIdx.x & 7;
    int c = ch * 8 + cl;
    ssc[k][cl] = scal[k * 512 + n * 128 + c];
    ssh[k][cl] = shft[k * 512 + n * 128 + c];
  }
  __syncthreads();
  const unsigned short* src = content + (size_t)blockIdx.x * 16384 * 8;
  unsigned short* dst = out + (size_t)blockIdx.x * 16384 * 8;
  for (int p = threadIdx.x; p < 16384; p += 256) {
    unsigned m = bits[p];
    float sc[8], sh[8];
#pragma unroll
    for (int cl = 0; cl < 8; ++cl) { sc[cl] = 0.f; sh[cl] = 0.f; }
    for (int k = 0; k < 8; ++k) {
      if ((m >> k) & 1u) {
#pragma unroll
        for (int cl = 0; cl < 8; ++cl) { sc[cl] += ssc[k][cl]; sh[cl] += ssh[k][cl]; }
      }
    }
    short8 v = *(const short8*)(src + (size_t)p * 8);
    short8 r;
#pragma unroll
    for (int cl = 0; cl < 8; ++cl) {
      float f = bf2f((unsigned short)v[cl]) + EPSF;
      r[cl] = (short)f2bf(f * sc[cl] + sh[cl]);
    }
    *(short8*)(dst + (size_t)p * 8) = r;
  }
}

// ---------------------------------------------------------------------------
static void launch_conv(const unsigned short* act, const unsigned short* wt,
                        const float* bias, unsigned short* out,
                        int C, int K, int H, int W, hipStream_t s) {
  dim3 g(W / 16, H / 16, 4 * (K / 64));
  conv3x3_mfma<<<g, 256, 0, s>>>(act, wt, bias, out, C, K, H, W);
}

extern "C" void kernel_launch(void* const* d_in, const int* in_sizes, int n_in,
                              void* d_out, int out_size, void* d_ws, size_t ws_size,
                              hipStream_t stream) {
  const float* f1   = (const float*)d_in[0];
  const float* f2   = (const float*)d_in[1];
  const float* s2lh = (const float*)d_in[2];
  const float* s2hl = (const float*)d_in[3];
  const float* s2hh = (const float*)d_in[4];
  const float* s1lh = (const float*)d_in[5];
  const float* s1hl = (const float*)d_in[6];
  const float* s1hh = (const float*)d_in[7];
  const float* s0lh = (const float*)d_in[8];
  const float* s0hl = (const float*)d_in[9];
  const float* s0hh = (const float*)d_in[10];
  const float* cmask = (const float*)d_in[11];
  const float* smask = (const float*)d_in[12];
  const float* w11 = (const float*)d_in[13]; const float* b11 = (const float*)d_in[14];
  const float* w12 = (const float*)d_in[15]; const float* b12 = (const float*)d_in[16];
  const float* w21 = (const float*)d_in[17]; const float* b21 = (const float*)d_in[18];
  const float* w22 = (const float*)d_in[19]; const float* b22 = (const float*)d_in[20];
  const float* w23 = (const float*)d_in[21]; const float* b23 = (const float*)d_in[22];
  const float* w24 = (const float*)d_in[23]; const float* b24 = (const float*)d_in[24];
  const float* w31 = (const float*)d_in[25]; const float* b31 = (const float*)d_in[26];
  const float* w32 = (const float*)d_in[27]; const float* b32 = (const float*)d_in[28];
  const float* w33 = (const float*)d_in[29]; const float* b33 = (const float*)d_in[30];

  // bf16 NC8HW8 ping-pong inside d_out (each 8,388,608 elems * 2B = 16.78 MB)
  unsigned short* A = (unsigned short*)d_out;
  unsigned short* B = A + 8388608;

  // workspace layout (bytes)
  char* wsb = (char*)d_ws;
  unsigned short* wtb = (unsigned short*)wsb;          // 5,971,968 elems bf16
  const size_t o11 = 0,        o12 = 2359296, o21 = 3538944, o22 = 4128768,
               o23 = 4718592,  o24 = 5308416, o31 = 5603328, o32 = 5750784,
               o33 = 5898240;                           // total 5,971,968
  unsigned short* f2c = (unsigned short*)(wsb + 11943936);   // 2,097,152 elems
  unsigned* cbits = (unsigned*)(wsb + 16138240);             // 16384 u32
  unsigned* sbits = (unsigned*)(wsb + 16203776);
  float* cst  = (float*)(wsb + 16269312);                    // 24*512
  float* sst  = (float*)(wsb + 16318464);                    // 24*512
  float* gst  = (float*)(wsb + 16367616);                    // 3*512
  float* scal = (float*)(wsb + 16373760);                    // 8*512
  float* shft = (float*)(wsb + 16390144);                    // 8*512
  float* flagc = (float*)(wsb + 16406528);                   // 8
  float* sany  = (float*)(wsb + 16406560);                   // 8
  // t12 (L9 output, 4,194,304 elems bf16 = 8,388,608 B) overlaps Wt11..Wt22,
  // all of which are consumed before L9 runs. Rewritten by wt_prep every call.
  unsigned short* t12 = (unsigned short*)wsb;

  const int NC = 512;

  // weight transposes (bf16, MFMA-friendly layout)
  wt_prep<<<(512 * 64 + 255) / 256, 256, 0, stream>>>(w11, wtb + o11, 512, 512);
  wt_prep<<<(256 * 64 + 255) / 256, 256, 0, stream>>>(w12, wtb + o12, 512, 256);
  wt_prep<<<(256 * 32 + 255) / 256, 256, 0, stream>>>(w21, wtb + o21, 256, 256);
  wt_prep<<<(256 * 32 + 255) / 256, 256, 0, stream>>>(w22, wtb + o22, 256, 256);
  wt_prep<<<(256 * 32 + 255) / 256, 256, 0, stream>>>(w23, wtb + o23, 256, 256);
  wt_prep<<<(128 * 32 + 255) / 256, 256, 0, stream>>>(w24, wtb + o24, 256, 128);
  wt_prep<<<(128 * 16 + 255) / 256, 256, 0, stream>>>(w31, wtb + o31, 128, 128);
  wt_prep<<<(128 * 16 + 255) / 256, 256, 0, stream>>>(w32, wtb + o32, 128, 128);
  wt_prep<<<( 64 * 16 + 255) / 256, 256, 0, stream>>>(w33, wtb + o33, 128,  64);

  // f2 -> bf16 NC8HW8
  nchw_to_nc8<<<(262144 + 255) / 256, 256, 0, stream>>>(f2, f2c, 64, 1024, 262144);

  // masks
  pack_masks<<<64, 256, 0, stream>>>(cmask, smask, cbits, sbits);
  mask_flags<<<8, 256, 0, stream>>>(cmask, smask, flagc, sany);

  // conv chain
  launch_conv(f2c, wtb + o11, b11, A, 512, 512, 32, 32, stream);
  launch_conv(A,   wtb + o12, b12, B, 512, 256, 32, 32, stream);
  unpool_shift_nc8<<<(524288 + 255) / 256, 256, 0, stream>>>(B, s2lh, s2hl, s2hh, A, 32, 32, 32, 524288);
  launch_conv(A,   wtb + o21, b21, B, 256, 256, 64, 64, stream);
  launch_conv(B,   wtb + o22, b22, A, 256, 256, 64, 64, stream);
  launch_conv(A,   wtb + o23, b23, B, 256, 256, 64, 64, stream);
  launch_conv(B,   wtb + o24, b24, A, 256, 128, 64, 64, stream);
  unpool_shift_nc8<<<(1048576 + 255) / 256, 256, 0, stream>>>(A, s1lh, s1hl, s1hh, B, 16, 64, 64, 1048576);

  // AdaIN: content=B (bf16), style=f1 (fp32) -> A
  masked_stats_bf16<<<512, 256, 0, stream>>>(B, cbits, cst, NC);
  masked_stats_f32g<<<512, 256, 0, stream>>>(f1, sbits, sst, gst, NC);
  finalize_ss<<<16, 256, 0, stream>>>(cst, sst, gst, flagc, sany, scal, shft, NC);
  adain_apply_nc8<<<64, 256, 0, stream>>>(B, cbits, scal, shft, A);

  launch_conv(A, wtb + o31, b31, B, 128, 128, 128, 128, stream);
  launch_conv(B, wtb + o32, b32, A, 128, 128, 128, 128, stream);
  launch_conv(A, wtb + o33, b33, t12, 128, 64, 128, 128, stream);

  // final unpool + rpad -> d_out fp32 NCHW (4,64,258,258)
  const int FIN_TOTAL = 4 * 64 * 258 * 258;   // 17,040,384
  unpool_rpad_final<<<(FIN_TOTAL + 255) / 256, 256, 0, stream>>>(
      t12, s0lh, s0hl, s0hh, (float*)d_out);
}

// Round 5
// 651.103 us; speedup vs baseline: 7.4738x; 1.8243x over previous
//
#include <hip/hip_runtime.h>

#define EPSF 1e-5f

typedef __attribute__((ext_vector_type(8)))  short short8;
typedef __attribute__((ext_vector_type(4)))  float f32x4;
typedef __attribute__((ext_vector_type(16))) float f32x16;

__device__ __forceinline__ unsigned short f2bf(float f) {
  unsigned u = __builtin_bit_cast(unsigned, f);
  unsigned r = (u + 0x7FFFu + ((u >> 16) & 1u)) >> 16;   // RNE
  return (unsigned short)r;
}
__device__ __forceinline__ float bf2f(unsigned short h) {
  unsigned u = ((unsigned)h) << 16;
  return __builtin_bit_cast(float, u);
}

// ---------------------------------------------------------------------------
// Weight pre-transpose: W[K][C][3][3] fp32 -> Wt[tap][C/8][K][8] bf16
// ---------------------------------------------------------------------------
__global__ void wt_prep(const float* __restrict__ w, unsigned short* __restrict__ wt,
                        int C, int K) {
  int C8 = C >> 3;
  int idx = blockIdx.x * 256 + threadIdx.x;
  if (idx >= K * C8) return;
  int k = idx / C8, ch = idx - k * C8;
  const float* src = w + ((size_t)k * C + ch * 8) * 9;
#pragma unroll
  for (int tap = 0; tap < 9; ++tap) {
    short8 v;
#pragma unroll
    for (int cl = 0; cl < 8; ++cl) v[cl] = (short)f2bf(src[cl * 9 + tap]);
    *(short8*)(wt + ((size_t)(tap * C8 + ch) * K + k) * 8) = v;
  }
}

// ---------------------------------------------------------------------------
// fp32 NCHW -> bf16 NC8HW8
// ---------------------------------------------------------------------------
__global__ void nchw_to_nc8(const float* __restrict__ in, unsigned short* __restrict__ out,
                            int C8, int HW, int total) {
  int idx = blockIdx.x * 256 + threadIdx.x;
  if (idx >= total) return;
  int pix = idx % HW; int t = idx / HW; int ch = t % C8; int n = t / C8;
  const float* s = in + ((size_t)(n * C8 + ch) * 8) * HW + pix;
  short8 v;
#pragma unroll
  for (int cl = 0; cl < 8; ++cl) v[cl] = (short)f2bf(s[(size_t)cl * HW]);
  *(short8*)(out + (size_t)idx * 8) = v;
}

// ---------------------------------------------------------------------------
// Conv 3x3 reflect-pad, bf16 MFMA implicit GEMM, split-C + 2-phase prefetch.
// act: NC8HW8 bf16, wt: [9][C/8][K][8] bf16.
// Block: 256 thr = 4 waves, tile 64 out-chans x 256 pixels (16x16).
// Split sp handles C-range [sp*cps*32, ...); S==1 -> bias+relu+bf16 out,
// S>1 -> fp32 partial (NC8HW8-ordered, per-split stride 4*K*HW).
// ---------------------------------------------------------------------------
__global__ __launch_bounds__(256) void conv3x3_mfma(
    const unsigned short* __restrict__ act, const unsigned short* __restrict__ wt,
    const float* __restrict__ bias, unsigned short* __restrict__ out,
    float* __restrict__ partial, int C, int K, int H, int W, int S) {
  const int C8 = C >> 3, K8 = K >> 3;
  const int HW = H * W;
  const int tid = threadIdx.x;
  const int lane = tid & 63, wid = tid >> 6;
  const int l31 = lane & 31, lhi = lane >> 5;
  const int w0 = blockIdx.x * 16, h0 = blockIdx.y * 16;
  const int kbn = K >> 6;
  int zz = blockIdx.z;
  const int sp = zz % S; zz /= S;
  const int kb = zz % kbn;
  const int n  = zz / kbn;
  const int k0 = kb * 64;

  __shared__ __align__(16) unsigned short smem[24576];  // 2 x 1536 slots x 16B
  __shared__ float sbias[64];
  if (tid < 64) sbias[tid] = bias[k0 + tid];

  // staging address precompute: 1296 slots (16B each), padded to 1536
  int g16[6];
#pragma unroll
  for (int it = 0; it < 6; ++it) {
    int slot = it * 256 + wid * 64 + lane;
    int s = slot < 1296 ? slot : 0;
    int chi = s / 324; int r = s - chi * 324;
    int y = r / 18, x = r - y * 18;
    int gy = h0 - 1 + y; gy = gy < 0 ? -gy : (gy >= H ? 2 * H - 2 - gy : gy);
    int gx = w0 - 1 + x; gx = gx < 0 ? -gx : (gx >= W ? 2 * W - 2 - gx : gx);
    g16[it] = ((n * C8 + chi) * H + gy) * W + gx;
  }

  // B-fragment pixel coords (fixed per lane)
  const int pbase = wid * 64;
  int pb[2];
#pragma unroll
  for (int nf = 0; nf < 2; ++nf) {
    int p = pbase + nf * 32 + l31;
    pb[nf] = (p >> 4) * 18 + (p & 15);
  }
  // A-fragment per-lane weight offsets
  int wb[2][2];
#pragma unroll
  for (int ks = 0; ks < 2; ++ks)
#pragma unroll
    for (int mf = 0; mf < 2; ++mf)
      wb[ks][mf] = (ks * 2 + lhi) * K + k0 + mf * 32 + l31;

  f32x16 acc[2][2] = {};

  const int cps = (C >> 5) / S;   // chunks (of 32 chans) per split
  const int c0 = sp * cps;

#define STAGE(BSEL, CI)                                                          \
  {                                                                              \
    _Pragma("unroll")                                                            \
    for (int it = 0; it < 6; ++it) {                                             \
      const unsigned short* g = act + ((size_t)g16[it] + (size_t)(CI) * 4 * HW) * 8; \
      __builtin_amdgcn_global_load_lds(                                          \
          (const __attribute__((address_space(1))) unsigned int*)g,              \
          (__attribute__((address_space(3))) unsigned int*)                      \
              &smem[(BSEL) * 12288 + (it * 256 + wid * 64) * 8],                 \
          16, 0, 0);                                                             \
    }                                                                            \
  }

  STAGE(0, c0)

  for (int i = 0; i < cps; ++i) {
    __syncthreads();                       // buf (i&1) staged; prev reads done
    const int bsel = i & 1;
    const int boff = bsel * 12288;
    const int ci = c0 + i;
    for (int tap = 0; tap < 9; ++tap) {
      if (tap == 5 && i + 1 < cps) STAGE(bsel ^ 1, ci + 1)   // prefetch next
      int ty = tap / 3, txx = tap - ty * 3;
      int tapoff = ty * 18 + txx;
      short8 a[2][2], b[2][2];
#pragma unroll
      for (int ks = 0; ks < 2; ++ks) {
#pragma unroll
        for (int mf = 0; mf < 2; ++mf) {
          size_t off = ((size_t)(tap * C8 + ci * 4) * K + wb[ks][mf]) * 8;
          a[mf][ks] = *(const short8*)(wt + off);
        }
#pragma unroll
        for (int nf = 0; nf < 2; ++nf) {
          int ls = boff + ((ks * 2 + lhi) * 324 + pb[nf] + tapoff) * 8;
          b[nf][ks] = *(const short8*)&smem[ls];
        }
      }
#pragma unroll
      for (int ks = 0; ks < 2; ++ks)
#pragma unroll
        for (int mf = 0; mf < 2; ++mf)
#pragma unroll
          for (int nf = 0; nf < 2; ++nf)
            acc[mf][nf] = __builtin_amdgcn_mfma_f32_32x32x16_bf16(
                a[mf][ks], b[nf][ks], acc[mf][nf], 0, 0, 0);
    }
  }

  if (S > 1) {
    // fp32 partial write, NC8HW8 ordering, per-split stride 4*K*HW elems.
    // NOTE: pixel must be GLOBAL (h0/w0 applied) — tile-local pix was the
    // round-4 bug.
    float* P = partial + (size_t)sp * ((size_t)4 * K * HW);
#pragma unroll
    for (int mf = 0; mf < 2; ++mf)
#pragma unroll
      for (int nf = 0; nf < 2; ++nf) {
        int p = pbase + nf * 32 + l31;
        int gp = (h0 + (p >> 4)) * W + (w0 + (p & 15));
#pragma unroll
        for (int q = 0; q < 4; ++q) {
          size_t ad = ((size_t)(n * K8 + (k0 >> 3) + mf * 4 + q) * HW + gp) * 8 + 4 * lhi;
          f32x4 v = { acc[mf][nf][4 * q], acc[mf][nf][4 * q + 1],
                      acc[mf][nf][4 * q + 2], acc[mf][nf][4 * q + 3] };
          *(f32x4*)(P + ad) = v;
        }
      }
    return;
  }

  // S==1 epilogue: bias + relu + pack bf16 via LDS transpose
  __syncthreads();
#pragma unroll
  for (int mf = 0; mf < 2; ++mf)
#pragma unroll
    for (int nf = 0; nf < 2; ++nf) {
      int pix = pbase + nf * 32 + l31;
#pragma unroll
      for (int rp = 0; rp < 8; ++rp) {
        const int r0 = rp * 2;
        int row0 = (r0 & 3) + 8 * (r0 >> 2) + 4 * lhi;   // row within 32
        int c64 = mf * 32 + row0;
        float v0 = acc[mf][nf][r0]     + sbias[c64];
        float v1 = acc[mf][nf][r0 + 1] + sbias[c64 + 1];
        v0 = v0 > 0.f ? v0 : 0.f;
        v1 = v1 > 0.f ? v1 : 0.f;
        unsigned pk = (unsigned)f2bf(v0) | ((unsigned)f2bf(v1) << 16);
        int chh = mf * 4 + (r0 >> 2);
        int clo = (r0 & 3) + 4 * lhi;
        *(unsigned*)&smem[((chh * 256 + pix) * 8 + clo)] = pk;
      }
    }
  __syncthreads();
#pragma unroll
  for (int i = 0; i < 8; ++i) {
    int slot = i * 256 + tid;           // 2048 slots of 16B
    int ch = slot >> 8;
    int p = slot & 255;
    int py = p >> 4, px = p & 15;
    short8 v = *(const short8*)&smem[slot * 8];
    *(short8*)(out + (((size_t)(n * K8 + (k0 >> 3) + ch) * H + h0 + py) * W + w0 + px) * 8) = v;
  }
#undef STAGE
}

// ---------------------------------------------------------------------------
// combine split-C partials: sum + bias + relu + pack bf16 NC8HW8
// ---------------------------------------------------------------------------
__global__ void combine_bias_relu(const float* __restrict__ P, const float* __restrict__ bias,
                                  unsigned short* __restrict__ out, int S, int K8, int HW,
                                  int total8) {
  int idx = blockIdx.x * 256 + threadIdx.x;
  if (idx >= total8) return;
  int k8 = (idx / HW) % K8;
  const float* p = P + (size_t)idx * 8;
  size_t stride = (size_t)total8 * 8;
  float v[8];
#pragma unroll
  for (int c = 0; c < 8; ++c) v[c] = p[c];
  for (int s = 1; s < S; ++s) {
#pragma unroll
    for (int c = 0; c < 8; ++c) v[c] += p[(size_t)s * stride + c];
  }
  short8 r;
#pragma unroll
  for (int c = 0; c < 8; ++c) {
    float x = v[c] + bias[k8 * 8 + c];
    x = x > 0.f ? x : 0.f;
    r[c] = (short)f2bf(x);
  }
  *(short8*)(out + (size_t)idx * 8) = r;
}

// ---------------------------------------------------------------------------
// Wavelet unpool fused with rpad(1)+crop shift, NC8HW8 bf16 ll / fp32 bands.
// ---------------------------------------------------------------------------
__global__ void unpool_shift_nc8(const unsigned short* __restrict__ ll,
                                 const float* __restrict__ lh, const float* __restrict__ hl,
                                 const float* __restrict__ hh, unsigned short* __restrict__ out,
                                 int C8, int Hh, int Wh, int total) {
  int idx = blockIdx.x * 256 + threadIdx.x;
  if (idx >= total) return;
  const int Ho = 2 * Hh, Wo = 2 * Wh;
  int j = idx % Wo; int t = idx / Wo;
  int i = t % Ho; t /= Ho;
  int ch = t % C8; int n = t / C8;
  int si = (i == 0) ? 1 : i - 1;
  int sj = (j == 0) ? 1 : j - 1;
  float sa = (si & 1) ? 1.f : -1.f;
  float sb = (sj & 1) ? 1.f : -1.f;
  int hy = si >> 1, hx = sj >> 1;
  size_t HWh = (size_t)Hh * Wh;
  const unsigned short* lp = ll + ((size_t)(n * C8 + ch) * HWh + hy * Wh + hx) * 8;
  size_t bb = ((size_t)(n * C8 + ch) * 8 * Hh + hy) * Wh + hx;
  short8 res;
#pragma unroll
  for (int cl = 0; cl < 8; ++cl) {
    float v = 0.5f * (bf2f(lp[cl]) + sb * lh[bb + cl * HWh] + sa * hl[bb + cl * HWh]
                      + sa * sb * hh[bb + cl * HWh]);
    res[cl] = (short)f2bf(v);
  }
  *(short8*)(out + (size_t)idx * 8) = res;
}

// ---------------------------------------------------------------------------
// Final unpool fused with rpad(1): NC8HW8 bf16 ll -> fp32 NCHW (4,64,258,258)
// ---------------------------------------------------------------------------
__global__ void unpool_rpad_final(const unsigned short* __restrict__ ll,
                                  const float* __restrict__ lh, const float* __restrict__ hl,
                                  const float* __restrict__ hh, float* __restrict__ out) {
  size_t idx = (size_t)blockIdx.x * 256 + threadIdx.x;
  if (idx >= (size_t)4 * 64 * 258 * 258) return;
  int j = (int)(idx % 258); size_t t = idx / 258;
  int i = (int)(t % 258); t /= 258;
  int c = (int)(t & 63); int n = (int)(t >> 6);
  int si = i - 1; si = si < 0 ? -si : (si >= 256 ? 510 - si : si);
  int sj = j - 1; sj = sj < 0 ? -sj : (sj >= 256 ? 510 - sj : sj);
  float sa = (si & 1) ? 1.f : -1.f;
  float sb = (sj & 1) ? 1.f : -1.f;
  int hy = si >> 1, hx = sj >> 1;
  float lv = bf2f(ll[((size_t)(n * 8 + (c >> 3)) * 16384 + hy * 128 + hx) * 8 + (c & 7)]);
  size_t bb = ((size_t)(n * 64 + c) * 128 + hy) * 128 + hx;
  out[idx] = 0.5f * (lv + sb * lh[bb] + sa * hl[bb] + sa * sb * hh[bb]);
}

// ---------------------------------------------------------------------------
// AdaIN support
// ---------------------------------------------------------------------------
__global__ void pack_masks(const float* __restrict__ cmask, const float* __restrict__ smask,
                           unsigned* __restrict__ cbits, unsigned* __restrict__ sbits) {
  int idx = blockIdx.x * 256 + threadIdx.x;
  if (idx >= 16384) return;
  int h = idx >> 7, w = idx & 127;
  unsigned cb = 0, sb = 0;
#pragma unroll
  for (int k = 0; k < 8; ++k) {
    int off = (k * 256 + 2 * h) * 256 + 2 * w;
    if (cmask[off] != 0.f) cb |= (1u << k);
    if (smask[off] != 0.f) sb |= (1u << k);
  }
  cbits[idx] = cb;
  sbits[idx] = sb;
}

__global__ void mask_flags(const float* __restrict__ cmask, const float* __restrict__ smask,
                           float* __restrict__ flagc, float* __restrict__ sany) {
  int k = blockIdx.x;
  const float* cm = cmask + (size_t)k * 65536;
  const float* sm = smask + (size_t)k * 65536;
  int ca = 0, sa = 0;
  for (int i = threadIdx.x; i < 65536; i += 256) {
    ca |= (cm[i] != 0.f);
    sa |= (sm[i] != 0.f);
  }
#pragma unroll
  for (int off = 32; off > 0; off >>= 1) {
    ca |= __shfl_xor(ca, off, 64);
    sa |= __shfl_xor(sa, off, 64);
  }
  __shared__ int rc[4], rs[4];
  int wv = threadIdx.x >> 6;
  if ((threadIdx.x & 63) == 0) { rc[wv] = ca; rs[wv] = sa; }
  __syncthreads();
  if (threadIdx.x == 0) {
    flagc[k] = (rc[0] | rc[1] | rc[2] | rc[3]) ? 1.f : 0.f;
    sany[k]  = (rs[0] | rs[1] | rs[2] | rs[3]) ? 1.f : 0.f;
  }
}

__global__ __launch_bounds__(256) void masked_stats_bf16(
    const unsigned short* __restrict__ feat, const unsigned* __restrict__ bits,
    float* __restrict__ outp, int NC) {
  constexpr int NV = 24;
  int b = blockIdx.x; int n = b >> 7, c = b & 127;
  const unsigned short* f = feat + (size_t)(n * 16 + (c >> 3)) * 16384 * 8 + (c & 7);
  float acc[NV];
#pragma unroll
  for (int j = 0; j < NV; ++j) acc[j] = 0.f;
  for (int i = threadIdx.x; i < 16384; i += 256) {
    float v = bf2f(f[(size_t)i * 8]) + EPSF;
    float nz = (v != 0.f) ? 1.f : 0.f;
    float v2 = v * v;
    unsigned m = bits[i];
#pragma unroll
    for (int k = 0; k < 8; ++k) {
      float mk = (float)((m >> k) & 1u);
      acc[k * 3 + 0] += mk * nz;
      acc[k * 3 + 1] += mk * v;
      acc[k * 3 + 2] += mk * v2;
    }
  }
#pragma unroll
  for (int j = 0; j < NV; ++j) {
    float v = acc[j];
#pragma unroll
    for (int off = 32; off > 0; off >>= 1) v += __shfl_xor(v, off, 64);
    acc[j] = v;
  }
  __shared__ float red[4][NV];
  int lane = threadIdx.x & 63, wv = threadIdx.x >> 6;
  if (lane == 0) {
#pragma unroll
    for (int j = 0; j < NV; ++j) red[wv][j] = acc[j];
  }
  __syncthreads();
  int tid = threadIdx.x;
  if (tid < NV) {
    float s = red[0][tid] + red[1][tid] + red[2][tid] + red[3][tid];
    outp[tid * NC + b] = s;
  }
}

__global__ __launch_bounds__(256) void masked_stats_f32g(
    const float* __restrict__ feat, const unsigned* __restrict__ bits,
    float* __restrict__ outp, float* __restrict__ gout, int NC) {
  constexpr int NV = 27;
  const int b = blockIdx.x;
  const float* f = feat + (size_t)b * 16384;
  float acc[NV];
#pragma unroll
  for (int j = 0; j < NV; ++j) acc[j] = 0.f;
  for (int i = threadIdx.x; i < 16384; i += 256) {
    float v = f[i] + EPSF;
    float nz = (v != 0.f) ? 1.f : 0.f;
    float v2 = v * v;
    unsigned m = bits[i];
#pragma unroll
    for (int k = 0; k < 8; ++k) {
      float mk = (float)((m >> k) & 1u);
      acc[k * 3 + 0] += mk * nz;
      acc[k * 3 + 1] += mk * v;
      acc[k * 3 + 2] += mk * v2;
    }
    acc[24] += nz; acc[25] += v; acc[26] += v2;
  }
#pragma unroll
  for (int j = 0; j < NV; ++j) {
    float v = acc[j];
#pragma unroll
    for (int off = 32; off > 0; off >>= 1) v += __shfl_xor(v, off, 64);
    acc[j] = v;
  }
  __shared__ float red[4][NV];
  int lane = threadIdx.x & 63, wv = threadIdx.x >> 6;
  if (lane == 0) {
#pragma unroll
    for (int j = 0; j < NV; ++j) red[wv][j] = acc[j];
  }
  __syncthreads();
  int tid = threadIdx.x;
  if (tid < NV) {
    float s = red[0][tid] + red[1][tid] + red[2][tid] + red[3][tid];
    if (tid < 24) outp[tid * NC + b] = s;
    else gout[(tid - 24) * NC + b] = s;
  }
}

__global__ void finalize_ss(const float* __restrict__ cst, const float* __restrict__ sst,
                            const float* __restrict__ gst, const float* __restrict__ flagc,
                            const float* __restrict__ sany,
                            float* __restrict__ scal, float* __restrict__ shft, int NC) {
  int idx = blockIdx.x * blockDim.x + threadIdx.x;
  if (idx >= 8 * NC) return;
  int k = idx / NC, b = idx - k * NC;
  float ccnt = cst[(k * 3 + 0) * NC + b];
  float cs1  = cst[(k * 3 + 1) * NC + b];
  float cs2  = cst[(k * 3 + 2) * NC + b];
  float cmn  = cs1 / fmaxf(ccnt, 1.f);
  float cvv  = (cs2 - ccnt * cmn * cmn) / fmaxf(ccnt - 1.f, 1.f) + EPSF;
  float cstd = sqrtf(cvv);
  float scnt, ss1, ss2;
  if (sany[k] == 0.f) {
    scnt = gst[0 * NC + b]; ss1 = gst[1 * NC + b]; ss2 = gst[2 * NC + b];
  } else {
    scnt = sst[(k * 3 + 0) * NC + b];
    ss1  = sst[(k * 3 + 1) * NC + b];
    ss2  = sst[(k * 3 + 2) * NC + b];
  }
  float smn  = ss1 / fmaxf(scnt, 1.f);
  float svv  = (ss2 - scnt * smn * smn) / fmaxf(scnt - 1.f, 1.f) + EPSF;
  float sstd = sqrtf(svv);
  float fl = flagc[k];
  float r  = sstd / cstd;
  scal[idx] = fl * r;
  shft[idx] = fl * (smn - cmn * r);
}

__global__ void adain_apply_nc8(const unsigned short* __restrict__ content,
                                const unsigned* __restrict__ bits,
                                const float* __restrict__ scal, const float* __restrict__ shft,
                                unsigned short* __restrict__ out) {
  int ch = blockIdx.x & 15, n = blockIdx.x >> 4;
  __shared__ float ssc[8][8], ssh[8][8];
  if (threadIdx.x < 64) {
    int k = threadIdx.x >> 3, cl = threadIdx.x & 7;
    int c = ch * 8 + cl;
    ssc[k][cl] = scal[k * 512 + n * 128 + c];
    ssh[k][cl] = shft[k * 512 + n * 128 + c];
  }
  __syncthreads();
  const unsigned short* src = content + (size_t)blockIdx.x * 16384 * 8;
  unsigned short* dst = out + (size_t)blockIdx.x * 16384 * 8;
  for (int p = threadIdx.x; p < 16384; p += 256) {
    unsigned m = bits[p];
    float sc[8], sh[8];
#pragma unroll
    for (int cl = 0; cl < 8; ++cl) { sc[cl] = 0.f; sh[cl] = 0.f; }
    for (int k = 0; k < 8; ++k) {
      if ((m >> k) & 1u) {
#pragma unroll
        for (int cl = 0; cl < 8; ++cl) { sc[cl] += ssc[k][cl]; sh[cl] += ssh[k][cl]; }
      }
    }
    short8 v = *(const short8*)(src + (size_t)p * 8);
    short8 r;
#pragma unroll
    for (int cl = 0; cl < 8; ++cl) {
      float f = bf2f((unsigned short)v[cl]) + EPSF;
      r[cl] = (short)f2bf(f * sc[cl] + sh[cl]);
    }
    *(short8*)(dst + (size_t)p * 8) = r;
  }
}

// ---------------------------------------------------------------------------
static void launch_conv(const unsigned short* act, const unsigned short* wt,
                        const float* bias, unsigned short* out, float* partial,
                        int C, int K, int H, int W, int S, hipStream_t st) {
  dim3 g(W / 16, H / 16, 4 * (K / 64) * S);
  conv3x3_mfma<<<g, 256, 0, st>>>(act, wt, bias, out, partial, C, K, H, W, S);
  if (S > 1) {
    int total8 = 4 * (K >> 3) * H * W;
    combine_bias_relu<<<(total8 + 255) / 256, 256, 0, st>>>(
        partial, bias, out, S, K >> 3, H * W, total8);
  }
}

extern "C" void kernel_launch(void* const* d_in, const int* in_sizes, int n_in,
                              void* d_out, int out_size, void* d_ws, size_t ws_size,
                              hipStream_t stream) {
  const float* f1   = (const float*)d_in[0];
  const float* f2   = (const float*)d_in[1];
  const float* s2lh = (const float*)d_in[2];
  const float* s2hl = (const float*)d_in[3];
  const float* s2hh = (const float*)d_in[4];
  const float* s1lh = (const float*)d_in[5];
  const float* s1hl = (const float*)d_in[6];
  const float* s1hh = (const float*)d_in[7];
  const float* s0lh = (const float*)d_in[8];
  const float* s0hl = (const float*)d_in[9];
  const float* s0hh = (const float*)d_in[10];
  const float* cmask = (const float*)d_in[11];
  const float* smask = (const float*)d_in[12];
  const float* w11 = (const float*)d_in[13]; const float* b11 = (const float*)d_in[14];
  const float* w12 = (const float*)d_in[15]; const float* b12 = (const float*)d_in[16];
  const float* w21 = (const float*)d_in[17]; const float* b21 = (const float*)d_in[18];
  const float* w22 = (const float*)d_in[19]; const float* b22 = (const float*)d_in[20];
  const float* w23 = (const float*)d_in[21]; const float* b23 = (const float*)d_in[22];
  const float* w24 = (const float*)d_in[23]; const float* b24 = (const float*)d_in[24];
  const float* w31 = (const float*)d_in[25]; const float* b31 = (const float*)d_in[26];
  const float* w32 = (const float*)d_in[27]; const float* b32 = (const float*)d_in[28];
  const float* w33 = (const float*)d_in[29]; const float* b33 = (const float*)d_in[30];

  // d_out layout (68,161,536 B total):
  //   A bf16 [0, 16,777,216)   B bf16 [16,777,216, 33,554,432)
  //   P fp32 [33,554,432, 67,108,864)  -- split-C partials (exactly 32 MiB)
  unsigned short* A = (unsigned short*)d_out;
  unsigned short* B = A + 8388608;
  float* P = (float*)((char*)d_out + 33554432);

  // workspace layout (bytes)
  char* wsb = (char*)d_ws;
  unsigned short* wtb = (unsigned short*)wsb;          // 5,971,968 elems bf16
  const size_t o11 = 0,        o12 = 2359296, o21 = 3538944, o22 = 4128768,
               o23 = 4718592,  o24 = 5308416, o31 = 5603328, o32 = 5750784,
               o33 = 5898240;                           // total 5,971,968
  unsigned short* f2c = (unsigned short*)(wsb + 11943936);   // 2,097,152 elems
  unsigned* cbits = (unsigned*)(wsb + 16138240);             // 16384 u32
  unsigned* sbits = (unsigned*)(wsb + 16203776);
  float* cst  = (float*)(wsb + 16269312);                    // 24*512
  float* sst  = (float*)(wsb + 16318464);                    // 24*512
  float* gst  = (float*)(wsb + 16367616);                    // 3*512
  float* scal = (float*)(wsb + 16373760);                    // 8*512
  float* shft = (float*)(wsb + 16390144);                    // 8*512
  float* flagc = (float*)(wsb + 16406528);                   // 8
  float* sany  = (float*)(wsb + 16406560);                   // 8
  // t12 overlaps Wt11..Wt22 (all consumed before L9 runs); rewritten every call
  unsigned short* t12 = (unsigned short*)wsb;

  const int NC = 512;

  wt_prep<<<(512 * 64 + 255) / 256, 256, 0, stream>>>(w11, wtb + o11, 512, 512);
  wt_prep<<<(256 * 64 + 255) / 256, 256, 0, stream>>>(w12, wtb + o12, 512, 256);
  wt_prep<<<(256 * 32 + 255) / 256, 256, 0, stream>>>(w21, wtb + o21, 256, 256);
  wt_prep<<<(256 * 32 + 255) / 256, 256, 0, stream>>>(w22, wtb + o22, 256, 256);
  wt_prep<<<(256 * 32 + 255) / 256, 256, 0, stream>>>(w23, wtb + o23, 256, 256);
  wt_prep<<<(128 * 32 + 255) / 256, 256, 0, stream>>>(w24, wtb + o24, 256, 128);
  wt_prep<<<(128 * 16 + 255) / 256, 256, 0, stream>>>(w31, wtb + o31, 128, 128);
  wt_prep<<<(128 * 16 + 255) / 256, 256, 0, stream>>>(w32, wtb + o32, 128, 128);
  wt_prep<<<( 64 * 16 + 255) / 256, 256, 0, stream>>>(w33, wtb + o33, 128,  64);

  nchw_to_nc8<<<(262144 + 255) / 256, 256, 0, stream>>>(f2, f2c, 64, 1024, 262144);

  pack_masks<<<64, 256, 0, stream>>>(cmask, smask, cbits, sbits);
  mask_flags<<<8, 256, 0, stream>>>(cmask, smask, flagc, sany);

  // conv chain (S chosen so every conv == 512 blocks)
  launch_conv(f2c, wtb + o11, b11, A, P, 512, 512, 32, 32, 4, stream);
  launch_conv(A,   wtb + o12, b12, B, P, 512, 256, 32, 32, 8, stream);
  unpool_shift_nc8<<<(524288 + 255) / 256, 256, 0, stream>>>(B, s2lh, s2hl, s2hh, A, 32, 32, 32, 524288);
  launch_conv(A,   wtb + o21, b21, B, P, 256, 256, 64, 64, 2, stream);
  launch_conv(B,   wtb + o22, b22, A, P, 256, 256, 64, 64, 2, stream);
  launch_conv(A,   wtb + o23, b23, B, P, 256, 256, 64, 64, 2, stream);
  launch_conv(B,   wtb + o24, b24, A, P, 256, 128, 64, 64, 4, stream);
  unpool_shift_nc8<<<(1048576 + 255) / 256, 256, 0, stream>>>(A, s1lh, s1hl, s1hh, B, 16, 64, 64, 1048576);

  // AdaIN: content=B (bf16), style=f1 (fp32) -> A
  masked_stats_bf16<<<512, 256, 0, stream>>>(B, cbits, cst, NC);
  masked_stats_f32g<<<512, 256, 0, stream>>>(f1, sbits, sst, gst, NC);
  finalize_ss<<<16, 256, 0, stream>>>(cst, sst, gst, flagc, sany, scal, shft, NC);
  adain_apply_nc8<<<64, 256, 0, stream>>>(B, cbits, scal, shft, A);

  launch_conv(A, wtb + o31, b31, B, P, 128, 128, 128, 128, 1, stream);
  launch_conv(B, wtb + o32, b32, A, P, 128, 128, 128, 128, 1, stream);
  launch_conv(A, wtb + o33, b33, t12, P, 128, 64, 128, 128, 2, stream);

  // final unpool + rpad -> d_out fp32 NCHW (4,64,258,258)
  const int FIN_TOTAL = 4 * 64 * 258 * 258;   // 17,040,384
  unpool_rpad_final<<<(FIN_TOTAL + 255) / 256, 256, 0, stream>>>(
      t12, s0lh, s0hl, s0hh, (float*)d_out);
}

// Round 6
// 531.113 us; speedup vs baseline: 9.1623x; 1.2259x over previous
//
#include <hip/hip_runtime.h>

#define EPSF 1e-5f

typedef __attribute__((ext_vector_type(8)))  short short8;
typedef __attribute__((ext_vector_type(4)))  float f32x4;
typedef __attribute__((ext_vector_type(16))) float f32x16;

__device__ __forceinline__ unsigned short f2bf(float f) {
  unsigned u = __builtin_bit_cast(unsigned, f);
  unsigned r = (u + 0x7FFFu + ((u >> 16) & 1u)) >> 16;   // RNE
  return (unsigned short)r;
}
__device__ __forceinline__ float bf2f(unsigned short h) {
  unsigned u = ((unsigned)h) << 16;
  return __builtin_bit_cast(float, u);
}

// ---------------------------------------------------------------------------
// Weight pre-transpose: W[K][C][3][3] fp32 -> Wt[tap][C/8][K][8] bf16
// ---------------------------------------------------------------------------
__global__ void wt_prep(const float* __restrict__ w, unsigned short* __restrict__ wt,
                        int C, int K) {
  int C8 = C >> 3;
  int idx = blockIdx.x * 256 + threadIdx.x;
  if (idx >= K * C8) return;
  int k = idx / C8, ch = idx - k * C8;
  const float* src = w + ((size_t)k * C + ch * 8) * 9;
#pragma unroll
  for (int tap = 0; tap < 9; ++tap) {
    short8 v;
#pragma unroll
    for (int cl = 0; cl < 8; ++cl) v[cl] = (short)f2bf(src[cl * 9 + tap]);
    *(short8*)(wt + ((size_t)(tap * C8 + ch) * K + k) * 8) = v;
  }
}

// ---------------------------------------------------------------------------
// fp32 NCHW -> bf16 NC8HW8
// ---------------------------------------------------------------------------
__global__ void nchw_to_nc8(const float* __restrict__ in, unsigned short* __restrict__ out,
                            int C8, int HW, int total) {
  int idx = blockIdx.x * 256 + threadIdx.x;
  if (idx >= total) return;
  int pix = idx % HW; int t = idx / HW; int ch = t % C8; int n = t / C8;
  const float* s = in + ((size_t)(n * C8 + ch) * 8) * HW + pix;
  short8 v;
#pragma unroll
  for (int cl = 0; cl < 8; ++cl) v[cl] = (short)f2bf(s[(size_t)cl * HW]);
  *(short8*)(out + (size_t)idx * 8) = v;
}

// ---------------------------------------------------------------------------
// Conv 3x3 reflect-pad, bf16 MFMA implicit GEMM, split-C + 2-phase prefetch.
// act: NC8HW8 bf16, wt: [9][C/8][K][8] bf16.
// Block: 256 thr = 4 waves, tile 64 out-chans x 256 pixels (16x16).
// ---------------------------------------------------------------------------
__global__ __launch_bounds__(256) void conv3x3_mfma(
    const unsigned short* __restrict__ act, const unsigned short* __restrict__ wt,
    const float* __restrict__ bias, unsigned short* __restrict__ out,
    float* __restrict__ partial, int C, int K, int H, int W, int S) {
  const int C8 = C >> 3, K8 = K >> 3;
  const int HW = H * W;
  const int tid = threadIdx.x;
  const int lane = tid & 63, wid = tid >> 6;
  const int l31 = lane & 31, lhi = lane >> 5;
  const int w0 = blockIdx.x * 16, h0 = blockIdx.y * 16;
  const int kbn = K >> 6;
  int zz = blockIdx.z;
  const int sp = zz % S; zz /= S;
  const int kb = zz % kbn;
  const int n  = zz / kbn;
  const int k0 = kb * 64;

  __shared__ __align__(16) unsigned short smem[24576];  // 2 x 1536 slots x 16B
  __shared__ float sbias[64];
  if (tid < 64) sbias[tid] = bias[k0 + tid];

  // staging address precompute: 1296 slots (16B each), padded to 1536
  int g16[6];
#pragma unroll
  for (int it = 0; it < 6; ++it) {
    int slot = it * 256 + wid * 64 + lane;
    int s = slot < 1296 ? slot : 0;
    int chi = s / 324; int r = s - chi * 324;
    int y = r / 18, x = r - y * 18;
    int gy = h0 - 1 + y; gy = gy < 0 ? -gy : (gy >= H ? 2 * H - 2 - gy : gy);
    int gx = w0 - 1 + x; gx = gx < 0 ? -gx : (gx >= W ? 2 * W - 2 - gx : gx);
    g16[it] = ((n * C8 + chi) * H + gy) * W + gx;
  }

  // B-fragment pixel coords (fixed per lane)
  const int pbase = wid * 64;
  int pb[2];
#pragma unroll
  for (int nf = 0; nf < 2; ++nf) {
    int p = pbase + nf * 32 + l31;
    pb[nf] = (p >> 4) * 18 + (p & 15);
  }
  // A-fragment per-lane weight offsets
  int wb[2][2];
#pragma unroll
  for (int ks = 0; ks < 2; ++ks)
#pragma unroll
    for (int mf = 0; mf < 2; ++mf)
      wb[ks][mf] = (ks * 2 + lhi) * K + k0 + mf * 32 + l31;

  f32x16 acc[2][2] = {};

  const int cps = (C >> 5) / S;   // chunks (of 32 chans) per split
  const int c0 = sp * cps;

#define STAGE(BSEL, CI)                                                          \
  {                                                                              \
    _Pragma("unroll")                                                            \
    for (int it = 0; it < 6; ++it) {                                             \
      const unsigned short* g = act + ((size_t)g16[it] + (size_t)(CI) * 4 * HW) * 8; \
      __builtin_amdgcn_global_load_lds(                                          \
          (const __attribute__((address_space(1))) unsigned int*)g,              \
          (__attribute__((address_space(3))) unsigned int*)                      \
              &smem[(BSEL) * 12288 + (it * 256 + wid * 64) * 8],                 \
          16, 0, 0);                                                             \
    }                                                                            \
  }

  STAGE(0, c0)

  for (int i = 0; i < cps; ++i) {
    __syncthreads();                       // buf (i&1) staged; prev reads done
    const int bsel = i & 1;
    const int boff = bsel * 12288;
    const int ci = c0 + i;
    for (int tap = 0; tap < 9; ++tap) {
      if (tap == 5 && i + 1 < cps) STAGE(bsel ^ 1, ci + 1)   // prefetch next
      int ty = tap / 3, txx = tap - ty * 3;
      int tapoff = ty * 18 + txx;
      short8 a[2][2], b[2][2];
#pragma unroll
      for (int ks = 0; ks < 2; ++ks) {
#pragma unroll
        for (int mf = 0; mf < 2; ++mf) {
          size_t off = ((size_t)(tap * C8 + ci * 4) * K + wb[ks][mf]) * 8;
          a[mf][ks] = *(const short8*)(wt + off);
        }
#pragma unroll
        for (int nf = 0; nf < 2; ++nf) {
          int ls = boff + ((ks * 2 + lhi) * 324 + pb[nf] + tapoff) * 8;
          b[nf][ks] = *(const short8*)&smem[ls];
        }
      }
#pragma unroll
      for (int ks = 0; ks < 2; ++ks)
#pragma unroll
        for (int mf = 0; mf < 2; ++mf)
#pragma unroll
          for (int nf = 0; nf < 2; ++nf)
            acc[mf][nf] = __builtin_amdgcn_mfma_f32_32x32x16_bf16(
                a[mf][ks], b[nf][ks], acc[mf][nf], 0, 0, 0);
    }
  }

  if (S > 1) {
    // fp32 partial write, NC8HW8 ordering; pixel is GLOBAL (h0/w0 applied).
    float* P = partial + (size_t)sp * ((size_t)4 * K * HW);
#pragma unroll
    for (int mf = 0; mf < 2; ++mf)
#pragma unroll
      for (int nf = 0; nf < 2; ++nf) {
        int p = pbase + nf * 32 + l31;
        int gp = (h0 + (p >> 4)) * W + (w0 + (p & 15));
#pragma unroll
        for (int q = 0; q < 4; ++q) {
          size_t ad = ((size_t)(n * K8 + (k0 >> 3) + mf * 4 + q) * HW + gp) * 8 + 4 * lhi;
          f32x4 v = { acc[mf][nf][4 * q], acc[mf][nf][4 * q + 1],
                      acc[mf][nf][4 * q + 2], acc[mf][nf][4 * q + 3] };
          *(f32x4*)(P + ad) = v;
        }
      }
    return;
  }

  // S==1 epilogue: bias + relu + pack bf16 via LDS transpose
  __syncthreads();
#pragma unroll
  for (int mf = 0; mf < 2; ++mf)
#pragma unroll
    for (int nf = 0; nf < 2; ++nf) {
      int pix = pbase + nf * 32 + l31;
#pragma unroll
      for (int rp = 0; rp < 8; ++rp) {
        const int r0 = rp * 2;
        int row0 = (r0 & 3) + 8 * (r0 >> 2) + 4 * lhi;   // row within 32
        int c64 = mf * 32 + row0;
        float v0 = acc[mf][nf][r0]     + sbias[c64];
        float v1 = acc[mf][nf][r0 + 1] + sbias[c64 + 1];
        v0 = v0 > 0.f ? v0 : 0.f;
        v1 = v1 > 0.f ? v1 : 0.f;
        unsigned pk = (unsigned)f2bf(v0) | ((unsigned)f2bf(v1) << 16);
        int chh = mf * 4 + (r0 >> 2);
        int clo = (r0 & 3) + 4 * lhi;
        *(unsigned*)&smem[((chh * 256 + pix) * 8 + clo)] = pk;
      }
    }
  __syncthreads();
#pragma unroll
  for (int i = 0; i < 8; ++i) {
    int slot = i * 256 + tid;           // 2048 slots of 16B
    int ch = slot >> 8;
    int p = slot & 255;
    int py = p >> 4, px = p & 15;
    short8 v = *(const short8*)&smem[slot * 8];
    *(short8*)(out + (((size_t)(n * K8 + (k0 >> 3) + ch) * H + h0 + py) * W + w0 + px) * 8) = v;
  }
#undef STAGE
}

// ---------------------------------------------------------------------------
// combine split-C partials: sum + bias + relu + pack bf16 NC8HW8
// ---------------------------------------------------------------------------
__global__ void combine_bias_relu(const float* __restrict__ P, const float* __restrict__ bias,
                                  unsigned short* __restrict__ out, int S, int K8, int HW,
                                  int total8) {
  int idx = blockIdx.x * 256 + threadIdx.x;
  if (idx >= total8) return;
  int k8 = (idx / HW) % K8;
  const float* p = P + (size_t)idx * 8;
  size_t stride = (size_t)total8 * 8;
  float v[8];
#pragma unroll
  for (int c = 0; c < 8; ++c) v[c] = p[c];
  for (int s = 1; s < S; ++s) {
#pragma unroll
    for (int c = 0; c < 8; ++c) v[c] += p[(size_t)s * stride + c];
  }
  short8 r;
#pragma unroll
  for (int c = 0; c < 8; ++c) {
    float x = v[c] + bias[k8 * 8 + c];
    x = x > 0.f ? x : 0.f;
    r[c] = (short)f2bf(x);
  }
  *(short8*)(out + (size_t)idx * 8) = r;
}

// ---------------------------------------------------------------------------
// Wavelet unpool fused with rpad(1)+crop shift, NC8HW8 bf16 ll / fp32 bands.
// ---------------------------------------------------------------------------
__global__ void unpool_shift_nc8(const unsigned short* __restrict__ ll,
                                 const float* __restrict__ lh, const float* __restrict__ hl,
                                 const float* __restrict__ hh, unsigned short* __restrict__ out,
                                 int C8, int Hh, int Wh, int total) {
  int idx = blockIdx.x * 256 + threadIdx.x;
  if (idx >= total) return;
  const int Ho = 2 * Hh, Wo = 2 * Wh;
  int j = idx % Wo; int t = idx / Wo;
  int i = t % Ho; t /= Ho;
  int ch = t % C8; int n = t / C8;
  int si = (i == 0) ? 1 : i - 1;
  int sj = (j == 0) ? 1 : j - 1;
  float sa = (si & 1) ? 1.f : -1.f;
  float sb = (sj & 1) ? 1.f : -1.f;
  int hy = si >> 1, hx = sj >> 1;
  size_t HWh = (size_t)Hh * Wh;
  const unsigned short* lp = ll + ((size_t)(n * C8 + ch) * HWh + hy * Wh + hx) * 8;
  size_t bb = ((size_t)(n * C8 + ch) * 8 * Hh + hy) * Wh + hx;
  short8 res;
#pragma unroll
  for (int cl = 0; cl < 8; ++cl) {
    float v = 0.5f * (bf2f(lp[cl]) + sb * lh[bb + cl * HWh] + sa * hl[bb + cl * HWh]
                      + sa * sb * hh[bb + cl * HWh]);
    res[cl] = (short)f2bf(v);
  }
  *(short8*)(out + (size_t)idx * 8) = res;
}

// ---------------------------------------------------------------------------
// Final unpool fused with rpad(1): NC8HW8 bf16 ll -> fp32 NCHW (4,64,258,258)
// ---------------------------------------------------------------------------
__global__ void unpool_rpad_final(const unsigned short* __restrict__ ll,
                                  const float* __restrict__ lh, const float* __restrict__ hl,
                                  const float* __restrict__ hh, float* __restrict__ out) {
  size_t idx = (size_t)blockIdx.x * 256 + threadIdx.x;
  if (idx >= (size_t)4 * 64 * 258 * 258) return;
  int j = (int)(idx % 258); size_t t = idx / 258;
  int i = (int)(t % 258); t /= 258;
  int c = (int)(t & 63); int n = (int)(t >> 6);
  int si = i - 1; si = si < 0 ? -si : (si >= 256 ? 510 - si : si);
  int sj = j - 1; sj = sj < 0 ? -sj : (sj >= 256 ? 510 - sj : sj);
  float sa = (si & 1) ? 1.f : -1.f;
  float sb = (sj & 1) ? 1.f : -1.f;
  int hy = si >> 1, hx = sj >> 1;
  float lv = bf2f(ll[((size_t)(n * 8 + (c >> 3)) * 16384 + hy * 128 + hx) * 8 + (c & 7)]);
  size_t bb = ((size_t)(n * 64 + c) * 128 + hy) * 128 + hx;
  out[idx] = 0.5f * (lv + sb * lh[bb] + sa * hl[bb] + sa * sb * hh[bb]);
}

// ---------------------------------------------------------------------------
// AdaIN support
// ---------------------------------------------------------------------------
__global__ void pack_masks(const float* __restrict__ cmask, const float* __restrict__ smask,
                           unsigned* __restrict__ cbits, unsigned* __restrict__ sbits) {
  int idx = blockIdx.x * 256 + threadIdx.x;
  if (idx >= 16384) return;
  int h = idx >> 7, w = idx & 127;
  unsigned cb = 0, sb = 0;
#pragma unroll
  for (int k = 0; k < 8; ++k) {
    int off = (k * 256 + 2 * h) * 256 + 2 * w;
    if (cmask[off] != 0.f) cb |= (1u << k);
    if (smask[off] != 0.f) sb |= (1u << k);
  }
  cbits[idx] = cb;
  sbits[idx] = sb;
}

// 1024 threads/block, one block per class
__global__ __launch_bounds__(1024) void mask_flags(
    const float* __restrict__ cmask, const float* __restrict__ smask,
    float* __restrict__ flagc, float* __restrict__ sany) {
  int k = blockIdx.x;
  const float* cm = cmask + (size_t)k * 65536;
  const float* sm = smask + (size_t)k * 65536;
  int ca = 0, sa = 0;
  for (int i = threadIdx.x; i < 65536; i += 1024) {
    ca |= (cm[i] != 0.f);
    sa |= (sm[i] != 0.f);
  }
#pragma unroll
  for (int off = 32; off > 0; off >>= 1) {
    ca |= __shfl_xor(ca, off, 64);
    sa |= __shfl_xor(sa, off, 64);
  }
  __shared__ int rc[16], rs[16];
  int wv = threadIdx.x >> 6;
  if ((threadIdx.x & 63) == 0) { rc[wv] = ca; rs[wv] = sa; }
  __syncthreads();
  if (threadIdx.x == 0) {
    int c = 0, s = 0;
#pragma unroll
    for (int i = 0; i < 16; ++i) { c |= rc[i]; s |= rs[i]; }
    flagc[k] = c ? 1.f : 0.f;
    sany[k]  = s ? 1.f : 0.f;
  }
}

__global__ __launch_bounds__(256) void masked_stats_bf16(
    const unsigned short* __restrict__ feat, const unsigned* __restrict__ bits,
    float* __restrict__ outp, int NC) {
  constexpr int NV = 24;
  int b = blockIdx.x; int n = b >> 7, c = b & 127;
  const unsigned short* f = feat + (size_t)(n * 16 + (c >> 3)) * 16384 * 8 + (c & 7);
  float acc[NV];
#pragma unroll
  for (int j = 0; j < NV; ++j) acc[j] = 0.f;
  for (int i = threadIdx.x; i < 16384; i += 256) {
    float v = bf2f(f[(size_t)i * 8]) + EPSF;
    float nz = (v != 0.f) ? 1.f : 0.f;
    float v2 = v * v;
    unsigned m = bits[i];
#pragma unroll
    for (int k = 0; k < 8; ++k) {
      float mk = (float)((m >> k) & 1u);
      acc[k * 3 + 0] += mk * nz;
      acc[k * 3 + 1] += mk * v;
      acc[k * 3 + 2] += mk * v2;
    }
  }
#pragma unroll
  for (int j = 0; j < NV; ++j) {
    float v = acc[j];
#pragma unroll
    for (int off = 32; off > 0; off >>= 1) v += __shfl_xor(v, off, 64);
    acc[j] = v;
  }
  __shared__ float red[4][NV];
  int lane = threadIdx.x & 63, wv = threadIdx.x >> 6;
  if (lane == 0) {
#pragma unroll
    for (int j = 0; j < NV; ++j) red[wv][j] = acc[j];
  }
  __syncthreads();
  int tid = threadIdx.x;
  if (tid < NV) {
    float s = red[0][tid] + red[1][tid] + red[2][tid] + red[3][tid];
    outp[tid * NC + b] = s;
  }
}

__global__ __launch_bounds__(256) void masked_stats_f32g(
    const float* __restrict__ feat, const unsigned* __restrict__ bits,
    float* __restrict__ outp, float* __restrict__ gout, int NC) {
  constexpr int NV = 27;
  const int b = blockIdx.x;
  const float* f = feat + (size_t)b * 16384;
  float acc[NV];
#pragma unroll
  for (int j = 0; j < NV; ++j) acc[j] = 0.f;
  for (int i = threadIdx.x; i < 16384; i += 256) {
    float v = f[i] + EPSF;
    float nz = (v != 0.f) ? 1.f : 0.f;
    float v2 = v * v;
    unsigned m = bits[i];
#pragma unroll
    for (int k = 0; k < 8; ++k) {
      float mk = (float)((m >> k) & 1u);
      acc[k * 3 + 0] += mk * nz;
      acc[k * 3 + 1] += mk * v;
      acc[k * 3 + 2] += mk * v2;
    }
    acc[24] += nz; acc[25] += v; acc[26] += v2;
  }
#pragma unroll
  for (int j = 0; j < NV; ++j) {
    float v = acc[j];
#pragma unroll
    for (int off = 32; off > 0; off >>= 1) v += __shfl_xor(v, off, 64);
    acc[j] = v;
  }
  __shared__ float red[4][NV];
  int lane = threadIdx.x & 63, wv = threadIdx.x >> 6;
  if (lane == 0) {
#pragma unroll
    for (int j = 0; j < NV; ++j) red[wv][j] = acc[j];
  }
  __syncthreads();
  int tid = threadIdx.x;
  if (tid < NV) {
    float s = red[0][tid] + red[1][tid] + red[2][tid] + red[3][tid];
    if (tid < 24) outp[tid * NC + b] = s;
    else gout[(tid - 24) * NC + b] = s;
  }
}

__global__ void finalize_ss(const float* __restrict__ cst, const float* __restrict__ sst,
                            const float* __restrict__ gst, const float* __restrict__ flagc,
                            const float* __restrict__ sany,
                            float* __restrict__ scal, float* __restrict__ shft, int NC) {
  int idx = blockIdx.x * blockDim.x + threadIdx.x;
  if (idx >= 8 * NC) return;
  int k = idx / NC, b = idx - k * NC;
  float ccnt = cst[(k * 3 + 0) * NC + b];
  float cs1  = cst[(k * 3 + 1) * NC + b];
  float cs2  = cst[(k * 3 + 2) * NC + b];
  float cmn  = cs1 / fmaxf(ccnt, 1.f);
  float cvv  = (cs2 - ccnt * cmn * cmn) / fmaxf(ccnt - 1.f, 1.f) + EPSF;
  float cstd = sqrtf(cvv);
  float scnt, ss1, ss2;
  if (sany[k] == 0.f) {
    scnt = gst[0 * NC + b]; ss1 = gst[1 * NC + b]; ss2 = gst[2 * NC + b];
  } else {
    scnt = sst[(k * 3 + 0) * NC + b];
    ss1  = sst[(k * 3 + 1) * NC + b];
    ss2  = sst[(k * 3 + 2) * NC + b];
  }
  float smn  = ss1 / fmaxf(scnt, 1.f);
  float svv  = (ss2 - scnt * smn * smn) / fmaxf(scnt - 1.f, 1.f) + EPSF;
  float sstd = sqrtf(svv);
  float fl = flagc[k];
  float r  = sstd / cstd;
  scal[idx] = fl * r;
  shft[idx] = fl * (smn - cmn * r);
}

// apply: grid (64, 16) — blockIdx.x = (n, c_hi), blockIdx.y = 1024-pixel chunk
__global__ void adain_apply_nc8(const unsigned short* __restrict__ content,
                                const unsigned* __restrict__ bits,
                                const float* __restrict__ scal, const float* __restrict__ shft,
                                unsigned short* __restrict__ out) {
  int ch = blockIdx.x & 15, n = blockIdx.x >> 4;
  __shared__ float ssc[8][8], ssh[8][8];
  if (threadIdx.x < 64) {
    int k = threadIdx.x >> 3, cl = threadIdx.x & 7;
    int c = ch * 8 + cl;
    ssc[k][cl] = scal[k * 512 + n * 128 + c];
    ssh[k][cl] = shft[k * 512 + n * 128 + c];
  }
  __syncthreads();
  const unsigned short* src = content + (size_t)blockIdx.x * 16384 * 8;
  unsigned short* dst = out + (size_t)blockIdx.x * 16384 * 8;
  const int p0 = blockIdx.y * 1024;
  for (int p = p0 + threadIdx.x; p < p0 + 1024; p += 256) {
    unsigned m = bits[p];
    float sc[8], sh[8];
#pragma unroll
    for (int cl = 0; cl < 8; ++cl) { sc[cl] = 0.f; sh[cl] = 0.f; }
    for (int k = 0; k < 8; ++k) {
      if ((m >> k) & 1u) {
#pragma unroll
        for (int cl = 0; cl < 8; ++cl) { sc[cl] += ssc[k][cl]; sh[cl] += ssh[k][cl]; }
      }
    }
    short8 v = *(const short8*)(src + (size_t)p * 8);
    short8 r;
#pragma unroll
    for (int cl = 0; cl < 8; ++cl) {
      float f = bf2f((unsigned short)v[cl]) + EPSF;
      r[cl] = (short)f2bf(f * sc[cl] + sh[cl]);
    }
    *(short8*)(dst + (size_t)p * 8) = r;
  }
}

// ---------------------------------------------------------------------------
static void launch_conv(const unsigned short* act, const unsigned short* wt,
                        const float* bias, unsigned short* out, float* partial,
                        int C, int K, int H, int W, int S, hipStream_t st) {
  dim3 g(W / 16, H / 16, 4 * (K / 64) * S);
  conv3x3_mfma<<<g, 256, 0, st>>>(act, wt, bias, out, partial, C, K, H, W, S);
  if (S > 1) {
    int total8 = 4 * (K >> 3) * H * W;
    combine_bias_relu<<<(total8 + 255) / 256, 256, 0, st>>>(
        partial, bias, out, S, K >> 3, H * W, total8);
  }
}

extern "C" void kernel_launch(void* const* d_in, const int* in_sizes, int n_in,
                              void* d_out, int out_size, void* d_ws, size_t ws_size,
                              hipStream_t stream) {
  const float* f1   = (const float*)d_in[0];
  const float* f2   = (const float*)d_in[1];
  const float* s2lh = (const float*)d_in[2];
  const float* s2hl = (const float*)d_in[3];
  const float* s2hh = (const float*)d_in[4];
  const float* s1lh = (const float*)d_in[5];
  const float* s1hl = (const float*)d_in[6];
  const float* s1hh = (const float*)d_in[7];
  const float* s0lh = (const float*)d_in[8];
  const float* s0hl = (const float*)d_in[9];
  const float* s0hh = (const float*)d_in[10];
  const float* cmask = (const float*)d_in[11];
  const float* smask = (const float*)d_in[12];
  const float* w11 = (const float*)d_in[13]; const float* b11 = (const float*)d_in[14];
  const float* w12 = (const float*)d_in[15]; const float* b12 = (const float*)d_in[16];
  const float* w21 = (const float*)d_in[17]; const float* b21 = (const float*)d_in[18];
  const float* w22 = (const float*)d_in[19]; const float* b22 = (const float*)d_in[20];
  const float* w23 = (const float*)d_in[21]; const float* b23 = (const float*)d_in[22];
  const float* w24 = (const float*)d_in[23]; const float* b24 = (const float*)d_in[24];
  const float* w31 = (const float*)d_in[25]; const float* b31 = (const float*)d_in[26];
  const float* w32 = (const float*)d_in[27]; const float* b32 = (const float*)d_in[28];
  const float* w33 = (const float*)d_in[29]; const float* b33 = (const float*)d_in[30];

  // d_out layout (68,161,536 B total):
  //   A bf16 [0, 16,777,216)   B bf16 [16,777,216, 33,554,432)
  //   P fp32 [33,554,432, 67,108,864)  -- split-C partials (exactly 32 MiB)
  unsigned short* A = (unsigned short*)d_out;
  unsigned short* B = A + 8388608;
  float* P = (float*)((char*)d_out + 33554432);

  // workspace layout (bytes)
  char* wsb = (char*)d_ws;
  unsigned short* wtb = (unsigned short*)wsb;          // 5,971,968 elems bf16
  const size_t o11 = 0,        o12 = 2359296, o21 = 3538944, o22 = 4128768,
               o23 = 4718592,  o24 = 5308416, o31 = 5603328, o32 = 5750784,
               o33 = 5898240;                           // total 5,971,968
  unsigned short* f2c = (unsigned short*)(wsb + 11943936);   // 2,097,152 elems
  unsigned* cbits = (unsigned*)(wsb + 16138240);             // 16384 u32
  unsigned* sbits = (unsigned*)(wsb + 16203776);
  float* cst  = (float*)(wsb + 16269312);                    // 24*512
  float* sst  = (float*)(wsb + 16318464);                    // 24*512
  float* gst  = (float*)(wsb + 16367616);                    // 3*512
  float* scal = (float*)(wsb + 16373760);                    // 8*512
  float* shft = (float*)(wsb + 16390144);                    // 8*512
  float* flagc = (float*)(wsb + 16406528);                   // 8
  float* sany  = (float*)(wsb + 16406560);                   // 8
  // t12 overlaps Wt11..Wt22 (all consumed before L9 runs); rewritten every call
  unsigned short* t12 = (unsigned short*)wsb;

  const int NC = 512;

  wt_prep<<<(512 * 64 + 255) / 256, 256, 0, stream>>>(w11, wtb + o11, 512, 512);
  wt_prep<<<(256 * 64 + 255) / 256, 256, 0, stream>>>(w12, wtb + o12, 512, 256);
  wt_prep<<<(256 * 32 + 255) / 256, 256, 0, stream>>>(w21, wtb + o21, 256, 256);
  wt_prep<<<(256 * 32 + 255) / 256, 256, 0, stream>>>(w22, wtb + o22, 256, 256);
  wt_prep<<<(256 * 32 + 255) / 256, 256, 0, stream>>>(w23, wtb + o23, 256, 256);
  wt_prep<<<(128 * 32 + 255) / 256, 256, 0, stream>>>(w24, wtb + o24, 256, 128);
  wt_prep<<<(128 * 16 + 255) / 256, 256, 0, stream>>>(w31, wtb + o31, 128, 128);
  wt_prep<<<(128 * 16 + 255) / 256, 256, 0, stream>>>(w32, wtb + o32, 128, 128);
  wt_prep<<<( 64 * 16 + 255) / 256, 256, 0, stream>>>(w33, wtb + o33, 128,  64);

  nchw_to_nc8<<<(262144 + 255) / 256, 256, 0, stream>>>(f2, f2c, 64, 1024, 262144);

  pack_masks<<<64, 256, 0, stream>>>(cmask, smask, cbits, sbits);
  mask_flags<<<8, 1024, 0, stream>>>(cmask, smask, flagc, sany);

  // conv chain (S chosen so every conv == 512 blocks)
  launch_conv(f2c, wtb + o11, b11, A, P, 512, 512, 32, 32, 4, stream);
  launch_conv(A,   wtb + o12, b12, B, P, 512, 256, 32, 32, 8, stream);
  unpool_shift_nc8<<<(524288 + 255) / 256, 256, 0, stream>>>(B, s2lh, s2hl, s2hh, A, 32, 32, 32, 524288);
  launch_conv(A,   wtb + o21, b21, B, P, 256, 256, 64, 64, 2, stream);
  launch_conv(B,   wtb + o22, b22, A, P, 256, 256, 64, 64, 2, stream);
  launch_conv(A,   wtb + o23, b23, B, P, 256, 256, 64, 64, 2, stream);
  launch_conv(B,   wtb + o24, b24, A, P, 256, 128, 64, 64, 4, stream);
  unpool_shift_nc8<<<(1048576 + 255) / 256, 256, 0, stream>>>(A, s1lh, s1hl, s1hh, B, 16, 64, 64, 1048576);

  // AdaIN: content=B (bf16), style=f1 (fp32) -> A
  masked_stats_bf16<<<512, 256, 0, stream>>>(B, cbits, cst, NC);
  masked_stats_f32g<<<512, 256, 0, stream>>>(f1, sbits, sst, gst, NC);
  finalize_ss<<<16, 256, 0, stream>>>(cst, sst, gst, flagc, sany, scal, shft, NC);
  adain_apply_nc8<<<dim3(64, 16), 256, 0, stream>>>(B, cbits, scal, shft, A);

  launch_conv(A, wtb + o31, b31, B, P, 128, 128, 128, 128, 1, stream);
  launch_conv(B, wtb + o32, b32, A, P, 128, 128, 128, 128, 1, stream);
  launch_conv(A, wtb + o33, b33, t12, P, 128, 64, 128, 128, 2, stream);

  // final unpool + rpad -> d_out fp32 NCHW (4,64,258,258)
  const int FIN_TOTAL = 4 * 64 * 258 * 258;   // 17,040,384
  unpool_rpad_final<<<(FIN_TOTAL + 255) / 256, 256, 0, stream>>>(
      t12, s0lh, s0hl, s0hh, (float*)d_out);
}

// Round 8
// 526.143 us; speedup vs baseline: 9.2489x; 1.0094x over previous
//
#include <hip/hip_runtime.h>

#define EPSF 1e-5f

typedef __attribute__((ext_vector_type(8)))  short short8;
typedef __attribute__((ext_vector_type(4)))  float f32x4;
typedef __attribute__((ext_vector_type(16))) float f32x16;

__device__ __forceinline__ unsigned short f2bf(float f) {
  unsigned u = __builtin_bit_cast(unsigned, f);
  unsigned r = (u + 0x7FFFu + ((u >> 16) & 1u)) >> 16;   // RNE
  return (unsigned short)r;
}
__device__ __forceinline__ float bf2f(unsigned short h) {
  unsigned u = ((unsigned)h) << 16;
  return __builtin_bit_cast(float, u);
}

// ---------------------------------------------------------------------------
// Weight pre-transpose: W[K][C][3][3] fp32 -> Wt[tap][C/8][K][8] bf16
// ---------------------------------------------------------------------------
__global__ void wt_prep(const float* __restrict__ w, unsigned short* __restrict__ wt,
                        int C, int K) {
  int C8 = C >> 3;
  int idx = blockIdx.x * 256 + threadIdx.x;
  if (idx >= K * C8) return;
  int k = idx / C8, ch = idx - k * C8;
  const float* src = w + ((size_t)k * C + ch * 8) * 9;
#pragma unroll
  for (int tap = 0; tap < 9; ++tap) {
    short8 v;
#pragma unroll
    for (int cl = 0; cl < 8; ++cl) v[cl] = (short)f2bf(src[cl * 9 + tap]);
    *(short8*)(wt + ((size_t)(tap * C8 + ch) * K + k) * 8) = v;
  }
}

// ---------------------------------------------------------------------------
// fp32 NCHW -> bf16 NC8HW8
// ---------------------------------------------------------------------------
__global__ void nchw_to_nc8(const float* __restrict__ in, unsigned short* __restrict__ out,
                            int C8, int HW, int total) {
  int idx = blockIdx.x * 256 + threadIdx.x;
  if (idx >= total) return;
  int pix = idx % HW; int t = idx / HW; int ch = t % C8; int n = t / C8;
  const float* s = in + ((size_t)(n * C8 + ch) * 8) * HW + pix;
  short8 v;
#pragma unroll
  for (int cl = 0; cl < 8; ++cl) v[cl] = (short)f2bf(s[(size_t)cl * HW]);
  *(short8*)(out + (size_t)idx * 8) = v;
}

// ---------------------------------------------------------------------------
// Conv 3x3 reflect-pad, bf16 MFMA implicit GEMM, split-C + 2-phase prefetch.
// act: NC8HW8 bf16, wt: [9][C/8][K][8] bf16.
// Block: 256 thr = 4 waves, tile 64 out-chans x 256 pixels (16x16).
// ---------------------------------------------------------------------------
__global__ __launch_bounds__(256) void conv3x3_mfma(
    const unsigned short* __restrict__ act, const unsigned short* __restrict__ wt,
    const float* __restrict__ bias, unsigned short* __restrict__ out,
    float* __restrict__ partial, int C, int K, int H, int W, int S) {
  const int C8 = C >> 3, K8 = K >> 3;
  const int HW = H * W;
  const int tid = threadIdx.x;
  const int lane = tid & 63, wid = tid >> 6;
  const int l31 = lane & 31, lhi = lane >> 5;
  const int w0 = blockIdx.x * 16, h0 = blockIdx.y * 16;
  const int kbn = K >> 6;
  int zz = blockIdx.z;
  const int sp = zz % S; zz /= S;
  const int kb = zz % kbn;
  const int n  = zz / kbn;
  const int k0 = kb * 64;

  __shared__ __align__(16) unsigned short smem[24576];  // 2 x 1536 slots x 16B
  __shared__ float sbias[64];
  if (tid < 64) sbias[tid] = bias[k0 + tid];

  // staging address precompute: 1296 slots (16B each), padded to 1536
  int g16[6];
#pragma unroll
  for (int it = 0; it < 6; ++it) {
    int slot = it * 256 + wid * 64 + lane;
    int s = slot < 1296 ? slot : 0;
    int chi = s / 324; int r = s - chi * 324;
    int y = r / 18, x = r - y * 18;
    int gy = h0 - 1 + y; gy = gy < 0 ? -gy : (gy >= H ? 2 * H - 2 - gy : gy);
    int gx = w0 - 1 + x; gx = gx < 0 ? -gx : (gx >= W ? 2 * W - 2 - gx : gx);
    g16[it] = ((n * C8 + chi) * H + gy) * W + gx;
  }

  // B-fragment pixel coords (fixed per lane)
  const int pbase = wid * 64;
  int pb[2];
#pragma unroll
  for (int nf = 0; nf < 2; ++nf) {
    int p = pbase + nf * 32 + l31;
    pb[nf] = (p >> 4) * 18 + (p & 15);
  }
  // A-fragment per-lane weight offsets
  int wb[2][2];
#pragma unroll
  for (int ks = 0; ks < 2; ++ks)
#pragma unroll
    for (int mf = 0; mf < 2; ++mf)
      wb[ks][mf] = (ks * 2 + lhi) * K + k0 + mf * 32 + l31;

  f32x16 acc[2][2] = {};

  const int cps = (C >> 5) / S;   // chunks (of 32 chans) per split
  const int c0 = sp * cps;

#define STAGE(BSEL, CI)                                                          \
  {                                                                              \
    _Pragma("unroll")                                                            \
    for (int it = 0; it < 6; ++it) {                                             \
      const unsigned short* g = act + ((size_t)g16[it] + (size_t)(CI) * 4 * HW) * 8; \
      __builtin_amdgcn_global_load_lds(                                          \
          (const __attribute__((address_space(1))) unsigned int*)g,              \
          (__attribute__((address_space(3))) unsigned int*)                      \
              &smem[(BSEL) * 12288 + (it * 256 + wid * 64) * 8],                 \
          16, 0, 0);                                                             \
    }                                                                            \
  }

  STAGE(0, c0)

  for (int i = 0; i < cps; ++i) {
    __syncthreads();                       // buf (i&1) staged; prev reads done
    const int bsel = i & 1;
    const int boff = bsel * 12288;
    const int ci = c0 + i;
    for (int tap = 0; tap < 9; ++tap) {
      if (tap == 5 && i + 1 < cps) STAGE(bsel ^ 1, ci + 1)   // prefetch next
      int ty = tap / 3, txx = tap - ty * 3;
      int tapoff = ty * 18 + txx;
      short8 a[2][2], b[2][2];
#pragma unroll
      for (int ks = 0; ks < 2; ++ks) {
#pragma unroll
        for (int mf = 0; mf < 2; ++mf) {
          size_t off = ((size_t)(tap * C8 + ci * 4) * K + wb[ks][mf]) * 8;
          a[mf][ks] = *(const short8*)(wt + off);
        }
#pragma unroll
        for (int nf = 0; nf < 2; ++nf) {
          int ls = boff + ((ks * 2 + lhi) * 324 + pb[nf] + tapoff) * 8;
          b[nf][ks] = *(const short8*)&smem[ls];
        }
      }
#pragma unroll
      for (int ks = 0; ks < 2; ++ks)
#pragma unroll
        for (int mf = 0; mf < 2; ++mf)
#pragma unroll
          for (int nf = 0; nf < 2; ++nf)
            acc[mf][nf] = __builtin_amdgcn_mfma_f32_32x32x16_bf16(
                a[mf][ks], b[nf][ks], acc[mf][nf], 0, 0, 0);
    }
  }

  if (S > 1) {
    // fp32 partial write, NC8HW8 ordering; pixel is GLOBAL (h0/w0 applied).
    float* P = partial + (size_t)sp * ((size_t)4 * K * HW);
#pragma unroll
    for (int mf = 0; mf < 2; ++mf)
#pragma unroll
      for (int nf = 0; nf < 2; ++nf) {
        int p = pbase + nf * 32 + l31;
        int gp = (h0 + (p >> 4)) * W + (w0 + (p & 15));
#pragma unroll
        for (int q = 0; q < 4; ++q) {
          size_t ad = ((size_t)(n * K8 + (k0 >> 3) + mf * 4 + q) * HW + gp) * 8 + 4 * lhi;
          f32x4 v = { acc[mf][nf][4 * q], acc[mf][nf][4 * q + 1],
                      acc[mf][nf][4 * q + 2], acc[mf][nf][4 * q + 3] };
          *(f32x4*)(P + ad) = v;
        }
      }
    return;
  }

  // S==1 epilogue: bias + relu + pack bf16 via LDS transpose
  __syncthreads();
#pragma unroll
  for (int mf = 0; mf < 2; ++mf)
#pragma unroll
    for (int nf = 0; nf < 2; ++nf) {
      int pix = pbase + nf * 32 + l31;
#pragma unroll
      for (int rp = 0; rp < 8; ++rp) {
        const int r0 = rp * 2;
        int row0 = (r0 & 3) + 8 * (r0 >> 2) + 4 * lhi;   // row within 32
        int c64 = mf * 32 + row0;
        float v0 = acc[mf][nf][r0]     + sbias[c64];
        float v1 = acc[mf][nf][r0 + 1] + sbias[c64 + 1];
        v0 = v0 > 0.f ? v0 : 0.f;
        v1 = v1 > 0.f ? v1 : 0.f;
        unsigned pk = (unsigned)f2bf(v0) | ((unsigned)f2bf(v1) << 16);
        int chh = mf * 4 + (r0 >> 2);
        int clo = (r0 & 3) + 4 * lhi;
        *(unsigned*)&smem[((chh * 256 + pix) * 8 + clo)] = pk;
      }
    }
  __syncthreads();
#pragma unroll
  for (int i = 0; i < 8; ++i) {
    int slot = i * 256 + tid;           // 2048 slots of 16B
    int ch = slot >> 8;
    int p = slot & 255;
    int py = p >> 4, px = p & 15;
    short8 v = *(const short8*)&smem[slot * 8];
    *(short8*)(out + (((size_t)(n * K8 + (k0 >> 3) + ch) * H + h0 + py) * W + w0 + px) * 8) = v;
  }
#undef STAGE
}

// ---------------------------------------------------------------------------
// combine split-C partials: sum + bias + relu + pack bf16 NC8HW8
// ---------------------------------------------------------------------------
__global__ void combine_bias_relu(const float* __restrict__ P, const float* __restrict__ bias,
                                  unsigned short* __restrict__ out, int S, int K8, int HW,
                                  int total8) {
  int idx = blockIdx.x * 256 + threadIdx.x;
  if (idx >= total8) return;
  int k8 = (idx / HW) % K8;
  const float* p = P + (size_t)idx * 8;
  size_t stride = (size_t)total8 * 8;
  float v[8];
#pragma unroll
  for (int c = 0; c < 8; ++c) v[c] = p[c];
  for (int s = 1; s < S; ++s) {
#pragma unroll
    for (int c = 0; c < 8; ++c) v[c] += p[(size_t)s * stride + c];
  }
  short8 r;
#pragma unroll
  for (int c = 0; c < 8; ++c) {
    float x = v[c] + bias[k8 * 8 + c];
    x = x > 0.f ? x : 0.f;
    r[c] = (short)f2bf(x);
  }
  *(short8*)(out + (size_t)idx * 8) = r;
}

// ---------------------------------------------------------------------------
// Wavelet unpool fused with rpad(1)+crop shift, NC8HW8 bf16 ll / fp32 bands.
// ---------------------------------------------------------------------------
__global__ void unpool_shift_nc8(const unsigned short* __restrict__ ll,
                                 const float* __restrict__ lh, const float* __restrict__ hl,
                                 const float* __restrict__ hh, unsigned short* __restrict__ out,
                                 int C8, int Hh, int Wh, int total) {
  int idx = blockIdx.x * 256 + threadIdx.x;
  if (idx >= total) return;
  const int Ho = 2 * Hh, Wo = 2 * Wh;
  int j = idx % Wo; int t = idx / Wo;
  int i = t % Ho; t /= Ho;
  int ch = t % C8; int n = t / C8;
  int si = (i == 0) ? 1 : i - 1;
  int sj = (j == 0) ? 1 : j - 1;
  float sa = (si & 1) ? 1.f : -1.f;
  float sb = (sj & 1) ? 1.f : -1.f;
  int hy = si >> 1, hx = sj >> 1;
  size_t HWh = (size_t)Hh * Wh;
  const unsigned short* lp = ll + ((size_t)(n * C8 + ch) * HWh + hy * Wh + hx) * 8;
  size_t bb = ((size_t)(n * C8 + ch) * 8 * Hh + hy) * Wh + hx;
  short8 res;
#pragma unroll
  for (int cl = 0; cl < 8; ++cl) {
    float v = 0.5f * (bf2f(lp[cl]) + sb * lh[bb + cl * HWh] + sa * hl[bb + cl * HWh]
                      + sa * sb * hh[bb + cl * HWh]);
    res[cl] = (short)f2bf(v);
  }
  *(short8*)(out + (size_t)idx * 8) = res;
}

// ---------------------------------------------------------------------------
// Final unpool + rpad, pair-vectorized: ll = t12 (bf16 NC8HW8, K=64),
// out fp32 NCHW (4,64,258,258). One thread per (img, row, col-pair).
// Derivation (matches the scalar reference kernel): output col j=2jm has
// sj odd -> sb=+1, hx0 = jm==0 ? 0 : jm-1; j=2jm+1 has sj even -> sb=-1,
// hx1 = jm==128 ? 127 : jm. Row: si = i==0 ? 1 : i-1, reflected at 256.
// ---------------------------------------------------------------------------
__global__ void unpool_rpad_final_v2(const unsigned short* __restrict__ ll,
                                     const float* __restrict__ lh, const float* __restrict__ hl,
                                     const float* __restrict__ hh, float* __restrict__ out) {
  const int img = blockIdx.y;                 // n*64 + c
  int idx = blockIdx.x * 256 + threadIdx.x;   // over 258 rows * 129 pairs
  if (idx >= 258 * 129) return;
  int i = idx / 129, jm = idx - i * 129;
  const int n = img >> 6, c = img & 63;

  int si = (i == 0) ? 1 : i - 1; if (si >= 256) si = 254;
  float sa = (si & 1) ? 1.f : -1.f;
  int hy = si >> 1;
  int hx0 = (jm == 0) ? 0 : jm - 1;
  int hx1 = (jm == 128) ? 127 : jm;

  size_t lb = ((size_t)(n * 8 + (c >> 3)) * 16384 + hy * 128) * 8 + (c & 7);
  float lv0 = bf2f(ll[lb + hx0 * 8]);
  float lv1 = bf2f(ll[lb + hx1 * 8]);

  size_t bb = ((size_t)img * 128 + hy) * 128;
  float l0 = lh[bb + hx0], g0 = hl[bb + hx0], h0 = hh[bb + hx0];
  float l1 = lh[bb + hx1], g1 = hl[bb + hx1], h1 = hh[bb + hx1];
  float o0 = 0.5f * (lv0 + l0 + sa * (g0 + h0));
  float o1 = 0.5f * (lv1 - l1 + sa * (g1 - h1));
  float2 r = make_float2(o0, o1);
  *(float2*)&out[((size_t)img * 258 + i) * 258 + 2 * jm] = r;
}

// ---------------------------------------------------------------------------
// AdaIN support
// ---------------------------------------------------------------------------
__global__ void pack_masks(const float* __restrict__ cmask, const float* __restrict__ smask,
                           unsigned* __restrict__ cbits, unsigned* __restrict__ sbits) {
  int idx = blockIdx.x * 256 + threadIdx.x;
  if (idx >= 16384) return;
  int h = idx >> 7, w = idx & 127;
  unsigned cb = 0, sb = 0;
#pragma unroll
  for (int k = 0; k < 8; ++k) {
    int off = (k * 256 + 2 * h) * 256 + 2 * w;
    if (cmask[off] != 0.f) cb |= (1u << k);
    if (smask[off] != 0.f) sb |= (1u << k);
  }
  cbits[idx] = cb;
  sbits[idx] = sb;
}

// 1024 threads/block, one block per class
__global__ __launch_bounds__(1024) void mask_flags(
    const float* __restrict__ cmask, const float* __restrict__ smask,
    float* __restrict__ flagc, float* __restrict__ sany) {
  int k = blockIdx.x;
  const float* cm = cmask + (size_t)k * 65536;
  const float* sm = smask + (size_t)k * 65536;
  int ca = 0, sa = 0;
  for (int i = threadIdx.x; i < 65536; i += 1024) {
    ca |= (cm[i] != 0.f);
    sa |= (sm[i] != 0.f);
  }
#pragma unroll
  for (int off = 32; off > 0; off >>= 1) {
    ca |= __shfl_xor(ca, off, 64);
    sa |= __shfl_xor(sa, off, 64);
  }
  __shared__ int rc[16], rs[16];
  int wv = threadIdx.x >> 6;
  if ((threadIdx.x & 63) == 0) { rc[wv] = ca; rs[wv] = sa; }
  __syncthreads();
  if (threadIdx.x == 0) {
    int c = 0, s = 0;
#pragma unroll
    for (int i = 0; i < 16; ++i) { c |= rc[i]; s |= rs[i]; }
    flagc[k] = c ? 1.f : 0.f;
    sany[k]  = s ? 1.f : 0.f;
  }
}

__global__ __launch_bounds__(256) void masked_stats_bf16(
    const unsigned short* __restrict__ feat, const unsigned* __restrict__ bits,
    float* __restrict__ outp, int NC) {
  constexpr int NV = 24;
  int b = blockIdx.x; int n = b >> 7, c = b & 127;
  const unsigned short* f = feat + (size_t)(n * 16 + (c >> 3)) * 16384 * 8 + (c & 7);
  float acc[NV];
#pragma unroll
  for (int j = 0; j < NV; ++j) acc[j] = 0.f;
  for (int i = threadIdx.x; i < 16384; i += 256) {
    float v = bf2f(f[(size_t)i * 8]) + EPSF;
    float nz = (v != 0.f) ? 1.f : 0.f;
    float v2 = v * v;
    unsigned m = bits[i];
#pragma unroll
    for (int k = 0; k < 8; ++k) {
      float mk = (float)((m >> k) & 1u);
      acc[k * 3 + 0] += mk * nz;
      acc[k * 3 + 1] += mk * v;
      acc[k * 3 + 2] += mk * v2;
    }
  }
#pragma unroll
  for (int j = 0; j < NV; ++j) {
    float v = acc[j];
#pragma unroll
    for (int off = 32; off > 0; off >>= 1) v += __shfl_xor(v, off, 64);
    acc[j] = v;
  }
  __shared__ float red[4][NV];
  int lane = threadIdx.x & 63, wv = threadIdx.x >> 6;
  if (lane == 0) {
#pragma unroll
    for (int j = 0; j < NV; ++j) red[wv][j] = acc[j];
  }
  __syncthreads();
  int tid = threadIdx.x;
  if (tid < NV) {
    float s = red[0][tid] + red[1][tid] + red[2][tid] + red[3][tid];
    outp[tid * NC + b] = s;
  }
}

__global__ __launch_bounds__(256) void masked_stats_f32g(
    const float* __restrict__ feat, const unsigned* __restrict__ bits,
    float* __restrict__ outp, float* __restrict__ gout, int NC) {
  constexpr int NV = 27;
  const int b = blockIdx.x;
  const float* f = feat + (size_t)b * 16384;
  float acc[NV];
#pragma unroll
  for (int j = 0; j < NV; ++j) acc[j] = 0.f;
  for (int i = threadIdx.x; i < 16384; i += 256) {
    float v = f[i] + EPSF;
    float nz = (v != 0.f) ? 1.f : 0.f;
    float v2 = v * v;
    unsigned m = bits[i];
#pragma unroll
    for (int k = 0; k < 8; ++k) {
      float mk = (float)((m >> k) & 1u);
      acc[k * 3 + 0] += mk * nz;
      acc[k * 3 + 1] += mk * v;
      acc[k * 3 + 2] += mk * v2;
    }
    acc[24] += nz; acc[25] += v; acc[26] += v2;
  }
#pragma unroll
  for (int j = 0; j < NV; ++j) {
    float v = acc[j];
#pragma unroll
    for (int off = 32; off > 0; off >>= 1) v += __shfl_xor(v, off, 64);
    acc[j] = v;
  }
  __shared__ float red[4][NV];
  int lane = threadIdx.x & 63, wv = threadIdx.x >> 6;
  if (lane == 0) {
#pragma unroll
    for (int j = 0; j < NV; ++j) red[wv][j] = acc[j];
  }
  __syncthreads();
  int tid = threadIdx.x;
  if (tid < NV) {
    float s = red[0][tid] + red[1][tid] + red[2][tid] + red[3][tid];
    if (tid < 24) outp[tid * NC + b] = s;
    else gout[(tid - 24) * NC + b] = s;
  }
}

__global__ void finalize_ss(const float* __restrict__ cst, const float* __restrict__ sst,
                            const float* __restrict__ gst, const float* __restrict__ flagc,
                            const float* __restrict__ sany,
                            float* __restrict__ scal, float* __restrict__ shft, int NC) {
  int idx = blockIdx.x * blockDim.x + threadIdx.x;
  if (idx >= 8 * NC) return;
  int k = idx / NC, b = idx - k * NC;
  float ccnt = cst[(k * 3 + 0) * NC + b];
  float cs1  = cst[(k * 3 + 1) * NC + b];
  float cs2  = cst[(k * 3 + 2) * NC + b];
  float cmn  = cs1 / fmaxf(ccnt, 1.f);
  float cvv  = (cs2 - ccnt * cmn * cmn) / fmaxf(ccnt - 1.f, 1.f) + EPSF;
  float cstd = sqrtf(cvv);
  float scnt, ss1, ss2;
  if (sany[k] == 0.f) {
    scnt = gst[0 * NC + b]; ss1 = gst[1 * NC + b]; ss2 = gst[2 * NC + b];
  } else {
    scnt = sst[(k * 3 + 0) * NC + b];
    ss1  = sst[(k * 3 + 1) * NC + b];
    ss2  = sst[(k * 3 + 2) * NC + b];
  }
  float smn  = ss1 / fmaxf(scnt, 1.f);
  float svv  = (ss2 - scnt * smn * smn) / fmaxf(scnt - 1.f, 1.f) + EPSF;
  float sstd = sqrtf(svv);
  float fl = flagc[k];
  float r  = sstd / cstd;
  scal[idx] = fl * r;
  shft[idx] = fl * (smn - cmn * r);
}

// apply: grid (64, 16) — blockIdx.x = (n, c_hi), blockIdx.y = 1024-pixel chunk
__global__ void adain_apply_nc8(const unsigned short* __restrict__ content,
                                const unsigned* __restrict__ bits,
                                const float* __restrict__ scal, const float* __restrict__ shft,
                                unsigned short* __restrict__ out) {
  int ch = blockIdx.x & 15, n = blockIdx.x >> 4;
  __shared__ float ssc[8][8], ssh[8][8];
  if (threadIdx.x < 64) {
    int k = threadIdx.x >> 3, cl = threadIdx.x & 7;
    int c = ch * 8 + cl;
    ssc[k][cl] = scal[k * 512 + n * 128 + c];
    ssh[k][cl] = shft[k * 512 + n * 128 + c];
  }
  __syncthreads();
  const unsigned short* src = content + (size_t)blockIdx.x * 16384 * 8;
  unsigned short* dst = out + (size_t)blockIdx.x * 16384 * 8;
  const int p0 = blockIdx.y * 1024;
  for (int p = p0 + threadIdx.x; p < p0 + 1024; p += 256) {
    unsigned m = bits[p];
    float sc[8], sh[8];
#pragma unroll
    for (int cl = 0; cl < 8; ++cl) { sc[cl] = 0.f; sh[cl] = 0.f; }
    for (int k = 0; k < 8; ++k) {
      if ((m >> k) & 1u) {
#pragma unroll
        for (int cl = 0; cl < 8; ++cl) { sc[cl] += ssc[k][cl]; sh[cl] += ssh[k][cl]; }
      }
    }
    short8 v = *(const short8*)(src + (size_t)p * 8);
    short8 r;
#pragma unroll
    for (int cl = 0; cl < 8; ++cl) {
      float f = bf2f((unsigned short)v[cl]) + EPSF;
      r[cl] = (short)f2bf(f * sc[cl] + sh[cl]);
    }
    *(short8*)(dst + (size_t)p * 8) = r;
  }
}

// ---------------------------------------------------------------------------
static void launch_conv(const unsigned short* act, const unsigned short* wt,
                        const float* bias, unsigned short* out, float* partial,
                        int C, int K, int H, int W, int S, hipStream_t st) {
  dim3 g(W / 16, H / 16, 4 * (K / 64) * S);
  conv3x3_mfma<<<g, 256, 0, st>>>(act, wt, bias, out, partial, C, K, H, W, S);
  if (S > 1) {
    int total8 = 4 * (K >> 3) * H * W;
    combine_bias_relu<<<(total8 + 255) / 256, 256, 0, st>>>(
        partial, bias, out, S, K >> 3, H * W, total8);
  }
}

extern "C" void kernel_launch(void* const* d_in, const int* in_sizes, int n_in,
                              void* d_out, int out_size, void* d_ws, size_t ws_size,
                              hipStream_t stream) {
  const float* f1   = (const float*)d_in[0];
  const float* f2   = (const float*)d_in[1];
  const float* s2lh = (const float*)d_in[2];
  const float* s2hl = (const float*)d_in[3];
  const float* s2hh = (const float*)d_in[4];
  const float* s1lh = (const float*)d_in[5];
  const float* s1hl = (const float*)d_in[6];
  const float* s1hh = (const float*)d_in[7];
  const float* s0lh = (const float*)d_in[8];
  const float* s0hl = (const float*)d_in[9];
  const float* s0hh = (const float*)d_in[10];
  const float* cmask = (const float*)d_in[11];
  const float* smask = (const float*)d_in[12];
  const float* w11 = (const float*)d_in[13]; const float* b11 = (const float*)d_in[14];
  const float* w12 = (const float*)d_in[15]; const float* b12 = (const float*)d_in[16];
  const float* w21 = (const float*)d_in[17]; const float* b21 = (const float*)d_in[18];
  const float* w22 = (const float*)d_in[19]; const float* b22 = (const float*)d_in[20];
  const float* w23 = (const float*)d_in[21]; const float* b23 = (const float*)d_in[22];
  const float* w24 = (const float*)d_in[23]; const float* b24 = (const float*)d_in[24];
  const float* w31 = (const float*)d_in[25]; const float* b31 = (const float*)d_in[26];
  const float* w32 = (const float*)d_in[27]; const float* b32 = (const float*)d_in[28];
  const float* w33 = (const float*)d_in[29]; const float* b33 = (const float*)d_in[30];

  // d_out layout (68,161,536 B total):
  //   A bf16 [0, 16,777,216)   B bf16 [16,777,216, 33,554,432)
  //   P fp32 [33,554,432, 67,108,864)  -- split-C partials (exactly 32 MiB)
  // NOTE: the FINAL kernel writes all of d_out, so its inputs (t12) must
  // live in d_ws, never in d_out (round-7 aliasing bug).
  unsigned short* A = (unsigned short*)d_out;
  unsigned short* B = A + 8388608;
  float* P = (float*)((char*)d_out + 33554432);

  // workspace layout (bytes)
  char* wsb = (char*)d_ws;
  unsigned short* wtb = (unsigned short*)wsb;          // 5,971,968 elems bf16
  const size_t o11 = 0,        o12 = 2359296, o21 = 3538944, o22 = 4128768,
               o23 = 4718592,  o24 = 5308416, o31 = 5603328, o32 = 5750784,
               o33 = 5898240;                           // total 5,971,968
  unsigned short* f2c = (unsigned short*)(wsb + 11943936);   // 2,097,152 elems
  unsigned* cbits = (unsigned*)(wsb + 16138240);             // 16384 u32
  unsigned* sbits = (unsigned*)(wsb + 16203776);
  float* cst  = (float*)(wsb + 16269312);                    // 24*512
  float* sst  = (float*)(wsb + 16318464);                    // 24*512
  float* gst  = (float*)(wsb + 16367616);                    // 3*512
  float* scal = (float*)(wsb + 16373760);                    // 8*512
  float* shft = (float*)(wsb + 16390144);                    // 8*512
  float* flagc = (float*)(wsb + 16406528);                   // 8
  float* sany  = (float*)(wsb + 16406560);                   // 8
  // t12 (L9 output bf16, 8,388,608 B) overlaps Wt o11..part of o22 — all
  // consumed before L9 runs; wt_prep rewrites them every call.
  unsigned short* t12 = (unsigned short*)wsb;

  const int NC = 512;

  wt_prep<<<(512 * 64 + 255) / 256, 256, 0, stream>>>(w11, wtb + o11, 512, 512);
  wt_prep<<<(256 * 64 + 255) / 256, 256, 0, stream>>>(w12, wtb + o12, 512, 256);
  wt_prep<<<(256 * 32 + 255) / 256, 256, 0, stream>>>(w21, wtb + o21, 256, 256);
  wt_prep<<<(256 * 32 + 255) / 256, 256, 0, stream>>>(w22, wtb + o22, 256, 256);
  wt_prep<<<(256 * 32 + 255) / 256, 256, 0, stream>>>(w23, wtb + o23, 256, 256);
  wt_prep<<<(128 * 32 + 255) / 256, 256, 0, stream>>>(w24, wtb + o24, 256, 128);
  wt_prep<<<(128 * 16 + 255) / 256, 256, 0, stream>>>(w31, wtb + o31, 128, 128);
  wt_prep<<<(128 * 16 + 255) / 256, 256, 0, stream>>>(w32, wtb + o32, 128, 128);
  wt_prep<<<( 64 * 16 + 255) / 256, 256, 0, stream>>>(w33, wtb + o33, 128,  64);

  nchw_to_nc8<<<(262144 + 255) / 256, 256, 0, stream>>>(f2, f2c, 64, 1024, 262144);

  pack_masks<<<64, 256, 0, stream>>>(cmask, smask, cbits, sbits);
  mask_flags<<<8, 1024, 0, stream>>>(cmask, smask, flagc, sany);

  // conv chain (S chosen so every conv == 512 blocks)
  launch_conv(f2c, wtb + o11, b11, A, P, 512, 512, 32, 32, 4, stream);
  launch_conv(A,   wtb + o12, b12, B, P, 512, 256, 32, 32, 8, stream);
  unpool_shift_nc8<<<(524288 + 255) / 256, 256, 0, stream>>>(B, s2lh, s2hl, s2hh, A, 32, 32, 32, 524288);
  launch_conv(A,   wtb + o21, b21, B, P, 256, 256, 64, 64, 2, stream);
  launch_conv(B,   wtb + o22, b22, A, P, 256, 256, 64, 64, 2, stream);
  launch_conv(A,   wtb + o23, b23, B, P, 256, 256, 64, 64, 2, stream);
  launch_conv(B,   wtb + o24, b24, A, P, 256, 128, 64, 64, 4, stream);
  unpool_shift_nc8<<<(1048576 + 255) / 256, 256, 0, stream>>>(A, s1lh, s1hl, s1hh, B, 16, 64, 64, 1048576);

  // AdaIN: content=B (bf16), style=f1 (fp32) -> A
  masked_stats_bf16<<<512, 256, 0, stream>>>(B, cbits, cst, NC);
  masked_stats_f32g<<<512, 256, 0, stream>>>(f1, sbits, sst, gst, NC);
  finalize_ss<<<16, 256, 0, stream>>>(cst, sst, gst, flagc, sany, scal, shft, NC);
  adain_apply_nc8<<<dim3(64, 16), 256, 0, stream>>>(B, cbits, scal, shft, A);

  launch_conv(A, wtb + o31, b31, B, P, 128, 128, 128, 128, 1, stream);
  launch_conv(B, wtb + o32, b32, A, P, 128, 128, 128, 128, 1, stream);
  launch_conv(A, wtb + o33, b33, t12, P, 128, 64, 128, 128, 2, stream);

  // final: pair-vectorized unpool + rpad, reads t12 (d_ws) -> all of d_out
  unpool_rpad_final_v2<<<dim3(131, 256), 256, 0, stream>>>(
      t12, s0lh, s0hl, s0hh, (float*)d_out);
}

// Round 9
// 504.578 us; speedup vs baseline: 9.6442x; 1.0427x over previous
//
#include <hip/hip_runtime.h>

#define EPSF 1e-5f

typedef __attribute__((ext_vector_type(8)))  short short8;
typedef __attribute__((ext_vector_type(4)))  float f32x4;
typedef __attribute__((ext_vector_type(16))) float f32x16;

__device__ __forceinline__ unsigned short f2bf(float f) {
  unsigned u = __builtin_bit_cast(unsigned, f);
  unsigned r = (u + 0x7FFFu + ((u >> 16) & 1u)) >> 16;   // RNE
  return (unsigned short)r;
}
__device__ __forceinline__ float bf2f(unsigned short h) {
  unsigned u = ((unsigned)h) << 16;
  return __builtin_bit_cast(float, u);
}

// ---------------------------------------------------------------------------
// Weight pre-transpose: W[K][C][3][3] fp32 -> Wt[tap][C/8][K][8] bf16
// ---------------------------------------------------------------------------
__global__ void wt_prep(const float* __restrict__ w, unsigned short* __restrict__ wt,
                        int C, int K) {
  int C8 = C >> 3;
  int idx = blockIdx.x * 256 + threadIdx.x;
  if (idx >= K * C8) return;
  int k = idx / C8, ch = idx - k * C8;
  const float* src = w + ((size_t)k * C + ch * 8) * 9;
#pragma unroll
  for (int tap = 0; tap < 9; ++tap) {
    short8 v;
#pragma unroll
    for (int cl = 0; cl < 8; ++cl) v[cl] = (short)f2bf(src[cl * 9 + tap]);
    *(short8*)(wt + ((size_t)(tap * C8 + ch) * K + k) * 8) = v;
  }
}

// ---------------------------------------------------------------------------
// fp32 NCHW -> bf16 NC8HW8
// ---------------------------------------------------------------------------
__global__ void nchw_to_nc8(const float* __restrict__ in, unsigned short* __restrict__ out,
                            int C8, int HW, int total) {
  int idx = blockIdx.x * 256 + threadIdx.x;
  if (idx >= total) return;
  int pix = idx % HW; int t = idx / HW; int ch = t % C8; int n = t / C8;
  const float* s = in + ((size_t)(n * C8 + ch) * 8) * HW + pix;
  short8 v;
#pragma unroll
  for (int cl = 0; cl < 8; ++cl) v[cl] = (short)f2bf(s[(size_t)cl * HW]);
  *(short8*)(out + (size_t)idx * 8) = v;
}

// ---------------------------------------------------------------------------
// Conv 3x3 reflect-pad, bf16 MFMA implicit GEMM, split-C + 2-phase prefetch.
// act: NC8HW8 bf16, wt: [9][C/8][K][8] bf16.
// Block: 256 thr = 4 waves, tile 64 out-chans x 256 pixels (16x16).
// ---------------------------------------------------------------------------
__global__ __launch_bounds__(256) void conv3x3_mfma(
    const unsigned short* __restrict__ act, const unsigned short* __restrict__ wt,
    const float* __restrict__ bias, unsigned short* __restrict__ out,
    float* __restrict__ partial, int C, int K, int H, int W, int S) {
  const int C8 = C >> 3, K8 = K >> 3;
  const int HW = H * W;
  const int tid = threadIdx.x;
  const int lane = tid & 63, wid = tid >> 6;
  const int l31 = lane & 31, lhi = lane >> 5;
  const int w0 = blockIdx.x * 16, h0 = blockIdx.y * 16;
  const int kbn = K >> 6;
  int zz = blockIdx.z;
  const int sp = zz % S; zz /= S;
  const int kb = zz % kbn;
  const int n  = zz / kbn;
  const int k0 = kb * 64;

  __shared__ __align__(16) unsigned short smem[24576];  // 2 x 1536 slots x 16B
  __shared__ float sbias[64];
  if (tid < 64) sbias[tid] = bias[k0 + tid];

  // staging address precompute: 1296 slots (16B each), padded to 1536
  int g16[6];
#pragma unroll
  for (int it = 0; it < 6; ++it) {
    int slot = it * 256 + wid * 64 + lane;
    int s = slot < 1296 ? slot : 0;
    int chi = s / 324; int r = s - chi * 324;
    int y = r / 18, x = r - y * 18;
    int gy = h0 - 1 + y; gy = gy < 0 ? -gy : (gy >= H ? 2 * H - 2 - gy : gy);
    int gx = w0 - 1 + x; gx = gx < 0 ? -gx : (gx >= W ? 2 * W - 2 - gx : gx);
    g16[it] = ((n * C8 + chi) * H + gy) * W + gx;
  }

  // B-fragment pixel coords (fixed per lane)
  const int pbase = wid * 64;
  int pb[2];
#pragma unroll
  for (int nf = 0; nf < 2; ++nf) {
    int p = pbase + nf * 32 + l31;
    pb[nf] = (p >> 4) * 18 + (p & 15);
  }
  // A-fragment per-lane weight offsets
  int wb[2][2];
#pragma unroll
  for (int ks = 0; ks < 2; ++ks)
#pragma unroll
    for (int mf = 0; mf < 2; ++mf)
      wb[ks][mf] = (ks * 2 + lhi) * K + k0 + mf * 32 + l31;

  f32x16 acc[2][2] = {};

  const int cps = (C >> 5) / S;   // chunks (of 32 chans) per split
  const int c0 = sp * cps;

#define STAGE(BSEL, CI)                                                          \
  {                                                                              \
    _Pragma("unroll")                                                            \
    for (int it = 0; it < 6; ++it) {                                             \
      const unsigned short* g = act + ((size_t)g16[it] + (size_t)(CI) * 4 * HW) * 8; \
      __builtin_amdgcn_global_load_lds(                                          \
          (const __attribute__((address_space(1))) unsigned int*)g,              \
          (__attribute__((address_space(3))) unsigned int*)                      \
              &smem[(BSEL) * 12288 + (it * 256 + wid * 64) * 8],                 \
          16, 0, 0);                                                             \
    }                                                                            \
  }

  STAGE(0, c0)

  for (int i = 0; i < cps; ++i) {
    __syncthreads();                       // buf (i&1) staged; prev reads done
    const int bsel = i & 1;
    const int boff = bsel * 12288;
    const int ci = c0 + i;
    for (int tap = 0; tap < 9; ++tap) {
      if (tap == 5 && i + 1 < cps) STAGE(bsel ^ 1, ci + 1)   // prefetch next
      int ty = tap / 3, txx = tap - ty * 3;
      int tapoff = ty * 18 + txx;
      short8 a[2][2], b[2][2];
#pragma unroll
      for (int ks = 0; ks < 2; ++ks) {
#pragma unroll
        for (int mf = 0; mf < 2; ++mf) {
          size_t off = ((size_t)(tap * C8 + ci * 4) * K + wb[ks][mf]) * 8;
          a[mf][ks] = *(const short8*)(wt + off);
        }
#pragma unroll
        for (int nf = 0; nf < 2; ++nf) {
          int ls = boff + ((ks * 2 + lhi) * 324 + pb[nf] + tapoff) * 8;
          b[nf][ks] = *(const short8*)&smem[ls];
        }
      }
#pragma unroll
      for (int ks = 0; ks < 2; ++ks)
#pragma unroll
        for (int mf = 0; mf < 2; ++mf)
#pragma unroll
          for (int nf = 0; nf < 2; ++nf)
            acc[mf][nf] = __builtin_amdgcn_mfma_f32_32x32x16_bf16(
                a[mf][ks], b[nf][ks], acc[mf][nf], 0, 0, 0);
    }
  }

  if (S > 1) {
    // fp32 partial write, NC8HW8 ordering; pixel is GLOBAL (h0/w0 applied).
    float* P = partial + (size_t)sp * ((size_t)4 * K * HW);
#pragma unroll
    for (int mf = 0; mf < 2; ++mf)
#pragma unroll
      for (int nf = 0; nf < 2; ++nf) {
        int p = pbase + nf * 32 + l31;
        int gp = (h0 + (p >> 4)) * W + (w0 + (p & 15));
#pragma unroll
        for (int q = 0; q < 4; ++q) {
          size_t ad = ((size_t)(n * K8 + (k0 >> 3) + mf * 4 + q) * HW + gp) * 8 + 4 * lhi;
          f32x4 v = { acc[mf][nf][4 * q], acc[mf][nf][4 * q + 1],
                      acc[mf][nf][4 * q + 2], acc[mf][nf][4 * q + 3] };
          *(f32x4*)(P + ad) = v;
        }
      }
    return;
  }

  // S==1 epilogue: bias + relu + pack bf16 via LDS transpose
  __syncthreads();
#pragma unroll
  for (int mf = 0; mf < 2; ++mf)
#pragma unroll
    for (int nf = 0; nf < 2; ++nf) {
      int pix = pbase + nf * 32 + l31;
#pragma unroll
      for (int rp = 0; rp < 8; ++rp) {
        const int r0 = rp * 2;
        int row0 = (r0 & 3) + 8 * (r0 >> 2) + 4 * lhi;   // row within 32
        int c64 = mf * 32 + row0;
        float v0 = acc[mf][nf][r0]     + sbias[c64];
        float v1 = acc[mf][nf][r0 + 1] + sbias[c64 + 1];
        v0 = v0 > 0.f ? v0 : 0.f;
        v1 = v1 > 0.f ? v1 : 0.f;
        unsigned pk = (unsigned)f2bf(v0) | ((unsigned)f2bf(v1) << 16);
        int chh = mf * 4 + (r0 >> 2);
        int clo = (r0 & 3) + 4 * lhi;
        *(unsigned*)&smem[((chh * 256 + pix) * 8 + clo)] = pk;
      }
    }
  __syncthreads();
#pragma unroll
  for (int i = 0; i < 8; ++i) {
    int slot = i * 256 + tid;           // 2048 slots of 16B
    int ch = slot >> 8;
    int p = slot & 255;
    int py = p >> 4, px = p & 15;
    short8 v = *(const short8*)&smem[slot * 8];
    *(short8*)(out + (((size_t)(n * K8 + (k0 >> 3) + ch) * H + h0 + py) * W + w0 + px) * 8) = v;
  }
#undef STAGE
}

// ---------------------------------------------------------------------------
// combine split-C partials: sum + bias + relu + pack bf16 NC8HW8
// ---------------------------------------------------------------------------
__global__ void combine_bias_relu(const float* __restrict__ P, const float* __restrict__ bias,
                                  unsigned short* __restrict__ out, int S, int K8, int HW,
                                  int total8) {
  int idx = blockIdx.x * 256 + threadIdx.x;
  if (idx >= total8) return;
  int k8 = (idx / HW) % K8;
  const float* p = P + (size_t)idx * 8;
  size_t stride = (size_t)total8 * 8;
  float v[8];
#pragma unroll
  for (int c = 0; c < 8; ++c) v[c] = p[c];
  for (int s = 1; s < S; ++s) {
#pragma unroll
    for (int c = 0; c < 8; ++c) v[c] += p[(size_t)s * stride + c];
  }
  short8 r;
#pragma unroll
  for (int c = 0; c < 8; ++c) {
    float x = v[c] + bias[k8 * 8 + c];
    x = x > 0.f ? x : 0.f;
    r[c] = (short)f2bf(x);
  }
  *(short8*)(out + (size_t)idx * 8) = r;
}

// ---------------------------------------------------------------------------
// Wavelet unpool fused with rpad(1)+crop shift, NC8HW8 bf16 ll / fp32 bands.
// ---------------------------------------------------------------------------
__global__ void unpool_shift_nc8(const unsigned short* __restrict__ ll,
                                 const float* __restrict__ lh, const float* __restrict__ hl,
                                 const float* __restrict__ hh, unsigned short* __restrict__ out,
                                 int C8, int Hh, int Wh, int total) {
  int idx = blockIdx.x * 256 + threadIdx.x;
  if (idx >= total) return;
  const int Ho = 2 * Hh, Wo = 2 * Wh;
  int j = idx % Wo; int t = idx / Wo;
  int i = t % Ho; t /= Ho;
  int ch = t % C8; int n = t / C8;
  int si = (i == 0) ? 1 : i - 1;
  int sj = (j == 0) ? 1 : j - 1;
  float sa = (si & 1) ? 1.f : -1.f;
  float sb = (sj & 1) ? 1.f : -1.f;
  int hy = si >> 1, hx = sj >> 1;
  size_t HWh = (size_t)Hh * Wh;
  const unsigned short* lp = ll + ((size_t)(n * C8 + ch) * HWh + hy * Wh + hx) * 8;
  size_t bb = ((size_t)(n * C8 + ch) * 8 * Hh + hy) * Wh + hx;
  short8 res;
#pragma unroll
  for (int cl = 0; cl < 8; ++cl) {
    float v = 0.5f * (bf2f(lp[cl]) + sb * lh[bb + cl * HWh] + sa * hl[bb + cl * HWh]
                      + sa * sb * hh[bb + cl * HWh]);
    res[cl] = (short)f2bf(v);
  }
  *(short8*)(out + (size_t)idx * 8) = res;
}

// ---------------------------------------------------------------------------
// Final unpool + rpad, pair-vectorized: ll = t12 (bf16 NC8HW8, K=64),
// out fp32 NCHW (4,64,258,258). One thread per (img, row, col-pair).
// ---------------------------------------------------------------------------
__global__ void unpool_rpad_final_v2(const unsigned short* __restrict__ ll,
                                     const float* __restrict__ lh, const float* __restrict__ hl,
                                     const float* __restrict__ hh, float* __restrict__ out) {
  const int img = blockIdx.y;                 // n*64 + c
  int idx = blockIdx.x * 256 + threadIdx.x;   // over 258 rows * 129 pairs
  if (idx >= 258 * 129) return;
  int i = idx / 129, jm = idx - i * 129;
  const int n = img >> 6, c = img & 63;

  int si = (i == 0) ? 1 : i - 1; if (si >= 256) si = 254;
  float sa = (si & 1) ? 1.f : -1.f;
  int hy = si >> 1;
  int hx0 = (jm == 0) ? 0 : jm - 1;
  int hx1 = (jm == 128) ? 127 : jm;

  size_t lb = ((size_t)(n * 8 + (c >> 3)) * 16384 + hy * 128) * 8 + (c & 7);
  float lv0 = bf2f(ll[lb + hx0 * 8]);
  float lv1 = bf2f(ll[lb + hx1 * 8]);

  size_t bb = ((size_t)img * 128 + hy) * 128;
  float l0 = lh[bb + hx0], g0 = hl[bb + hx0], h0 = hh[bb + hx0];
  float l1 = lh[bb + hx1], g1 = hl[bb + hx1], h1 = hh[bb + hx1];
  float o0 = 0.5f * (lv0 + l0 + sa * (g0 + h0));
  float o1 = 0.5f * (lv1 - l1 + sa * (g1 - h1));
  float2 r = make_float2(o0, o1);
  *(float2*)&out[((size_t)img * 258 + i) * 258 + 2 * jm] = r;
}

// ---------------------------------------------------------------------------
// AdaIN support
// ---------------------------------------------------------------------------
__global__ void pack_masks(const float* __restrict__ cmask, const float* __restrict__ smask,
                           unsigned* __restrict__ cbits, unsigned* __restrict__ sbits) {
  int idx = blockIdx.x * 256 + threadIdx.x;
  if (idx >= 16384) return;
  int h = idx >> 7, w = idx & 127;
  unsigned cb = 0, sb = 0;
#pragma unroll
  for (int k = 0; k < 8; ++k) {
    int off = (k * 256 + 2 * h) * 256 + 2 * w;
    if (cmask[off] != 0.f) cb |= (1u << k);
    if (smask[off] != 0.f) sb |= (1u << k);
  }
  cbits[idx] = cb;
  sbits[idx] = sb;
}

// 1024 threads/block, one block per class
__global__ __launch_bounds__(1024) void mask_flags(
    const float* __restrict__ cmask, const float* __restrict__ smask,
    float* __restrict__ flagc, float* __restrict__ sany) {
  int k = blockIdx.x;
  const float* cm = cmask + (size_t)k * 65536;
  const float* sm = smask + (size_t)k * 65536;
  int ca = 0, sa = 0;
  for (int i = threadIdx.x; i < 65536; i += 1024) {
    ca |= (cm[i] != 0.f);
    sa |= (sm[i] != 0.f);
  }
#pragma unroll
  for (int off = 32; off > 0; off >>= 1) {
    ca |= __shfl_xor(ca, off, 64);
    sa |= __shfl_xor(sa, off, 64);
  }
  __shared__ int rc[16], rs[16];
  int wv = threadIdx.x >> 6;
  if ((threadIdx.x & 63) == 0) { rc[wv] = ca; rs[wv] = sa; }
  __syncthreads();
  if (threadIdx.x == 0) {
    int c = 0, s = 0;
#pragma unroll
    for (int i = 0; i < 16; ++i) { c |= rc[i]; s |= rs[i]; }
    flagc[k] = c ? 1.f : 0.f;
    sany[k]  = s ? 1.f : 0.f;
  }
}

// content stats (bf16 NC8HW8), 4-way pixel split via blockIdx.y.
// output: outp[sp][24][NC]
__global__ __launch_bounds__(256) void masked_stats_bf16(
    const unsigned short* __restrict__ feat, const unsigned* __restrict__ bits,
    float* __restrict__ outp, int NC) {
  constexpr int NV = 24;
  int b = blockIdx.x; int n = b >> 7, c = b & 127;
  const int sp = blockIdx.y;
  const unsigned short* f = feat + (size_t)(n * 16 + (c >> 3)) * 16384 * 8 + (c & 7);
  float acc[NV];
#pragma unroll
  for (int j = 0; j < NV; ++j) acc[j] = 0.f;
  const int p0 = sp * 4096;
  for (int it = 0; it < 16; ++it) {
    int i = p0 + it * 256 + threadIdx.x;
    float v = bf2f(f[(size_t)i * 8]) + EPSF;
    float nz = (v != 0.f) ? 1.f : 0.f;
    float v2 = v * v;
    unsigned m = bits[i];
#pragma unroll
    for (int k = 0; k < 8; ++k) {
      float mk = (float)((m >> k) & 1u);
      acc[k * 3 + 0] += mk * nz;
      acc[k * 3 + 1] += mk * v;
      acc[k * 3 + 2] += mk * v2;
    }
  }
#pragma unroll
  for (int j = 0; j < NV; ++j) {
    float v = acc[j];
#pragma unroll
    for (int off = 32; off > 0; off >>= 1) v += __shfl_xor(v, off, 64);
    acc[j] = v;
  }
  __shared__ float red[4][NV];
  int lane = threadIdx.x & 63, wv = threadIdx.x >> 6;
  if (lane == 0) {
#pragma unroll
    for (int j = 0; j < NV; ++j) red[wv][j] = acc[j];
  }
  __syncthreads();
  int tid = threadIdx.x;
  if (tid < NV) {
    float s = red[0][tid] + red[1][tid] + red[2][tid] + red[3][tid];
    outp[(sp * NV + tid) * NC + b] = s;
  }
}

// style stats (fp32 NCHW) + global, 4-way pixel split, float4-vectorized.
// output: sstp[sp][24][NC], gstp[sp][3][NC]
__global__ __launch_bounds__(256) void masked_stats_f32g(
    const float* __restrict__ feat, const unsigned* __restrict__ bits,
    float* __restrict__ sstp, float* __restrict__ gstp, int NC) {
  constexpr int NV = 27;
  const int b = blockIdx.x;
  const int sp = blockIdx.y;
  const float* f = feat + (size_t)b * 16384;
  float acc[NV];
#pragma unroll
  for (int j = 0; j < NV; ++j) acc[j] = 0.f;
  const int p0 = sp * 4096;
#pragma unroll 1
  for (int it = 0; it < 4; ++it) {
    int p = p0 + it * 1024 + threadIdx.x * 4;
    float4 v4 = *(const float4*)&f[p];
    uint4 m4 = *(const uint4*)&bits[p];
#pragma unroll
    for (int e = 0; e < 4; ++e) {
      float v = (&v4.x)[e] + EPSF;
      unsigned m = (&m4.x)[e];
      float nz = (v != 0.f) ? 1.f : 0.f;
      float v2 = v * v;
#pragma unroll
      for (int k = 0; k < 8; ++k) {
        float mk = (float)((m >> k) & 1u);
        acc[k * 3 + 0] += mk * nz;
        acc[k * 3 + 1] += mk * v;
        acc[k * 3 + 2] += mk * v2;
      }
      acc[24] += nz; acc[25] += v; acc[26] += v2;
    }
  }
#pragma unroll
  for (int j = 0; j < NV; ++j) {
    float v = acc[j];
#pragma unroll
    for (int off = 32; off > 0; off >>= 1) v += __shfl_xor(v, off, 64);
    acc[j] = v;
  }
  __shared__ float red[4][NV];
  int lane = threadIdx.x & 63, wv = threadIdx.x >> 6;
  if (lane == 0) {
#pragma unroll
    for (int j = 0; j < NV; ++j) red[wv][j] = acc[j];
  }
  __syncthreads();
  int tid = threadIdx.x;
  if (tid < NV) {
    float s = red[0][tid] + red[1][tid] + red[2][tid] + red[3][tid];
    if (tid < 24) sstp[(sp * 24 + tid) * NC + b] = s;
    else gstp[(sp * 3 + (tid - 24)) * NC + b] = s;
  }
}

// sums the 4 pixel-split partials (fixed order -> deterministic)
__global__ void finalize_ss(const float* __restrict__ cstp, const float* __restrict__ sstp,
                            const float* __restrict__ gstp, const float* __restrict__ flagc,
                            const float* __restrict__ sany,
                            float* __restrict__ scal, float* __restrict__ shft, int NC) {
  int idx = blockIdx.x * blockDim.x + threadIdx.x;
  if (idx >= 8 * NC) return;
  int k = idx / NC, b = idx - k * NC;
  bool useg = (sany[k] == 0.f);
  float ccnt = 0.f, cs1 = 0.f, cs2 = 0.f, scnt = 0.f, ss1 = 0.f, ss2 = 0.f;
#pragma unroll
  for (int s = 0; s < 4; ++s) {
    const float* cp = cstp + s * 24 * NC;
    ccnt += cp[(k * 3 + 0) * NC + b];
    cs1  += cp[(k * 3 + 1) * NC + b];
    cs2  += cp[(k * 3 + 2) * NC + b];
    if (useg) {
      const float* gp = gstp + s * 3 * NC;
      scnt += gp[0 * NC + b]; ss1 += gp[1 * NC + b]; ss2 += gp[2 * NC + b];
    } else {
      const float* spp = sstp + s * 24 * NC;
      scnt += spp[(k * 3 + 0) * NC + b];
      ss1  += spp[(k * 3 + 1) * NC + b];
      ss2  += spp[(k * 3 + 2) * NC + b];
    }
  }
  float cmn  = cs1 / fmaxf(ccnt, 1.f);
  float cvv  = (cs2 - ccnt * cmn * cmn) / fmaxf(ccnt - 1.f, 1.f) + EPSF;
  float cstd = sqrtf(cvv);
  float smn  = ss1 / fmaxf(scnt, 1.f);
  float svv  = (ss2 - scnt * smn * smn) / fmaxf(scnt - 1.f, 1.f) + EPSF;
  float sstd = sqrtf(svv);
  float fl = flagc[k];
  float r  = sstd / cstd;
  scal[idx] = fl * r;
  shft[idx] = fl * (smn - cmn * r);
}

// apply: grid (64, 16) — blockIdx.x = (n, c_hi), blockIdx.y = 1024-pixel chunk
__global__ void adain_apply_nc8(const unsigned short* __restrict__ content,
                                const unsigned* __restrict__ bits,
                                const float* __restrict__ scal, const float* __restrict__ shft,
                                unsigned short* __restrict__ out) {
  int ch = blockIdx.x & 15, n = blockIdx.x >> 4;
  __shared__ float ssc[8][8], ssh[8][8];
  if (threadIdx.x < 64) {
    int k = threadIdx.x >> 3, cl = threadIdx.x & 7;
    int c = ch * 8 + cl;
    ssc[k][cl] = scal[k * 512 + n * 128 + c];
    ssh[k][cl] = shft[k * 512 + n * 128 + c];
  }
  __syncthreads();
  const unsigned short* src = content + (size_t)blockIdx.x * 16384 * 8;
  unsigned short* dst = out + (size_t)blockIdx.x * 16384 * 8;
  const int p0 = blockIdx.y * 1024;
  for (int p = p0 + threadIdx.x; p < p0 + 1024; p += 256) {
    unsigned m = bits[p];
    float sc[8], sh[8];
#pragma unroll
    for (int cl = 0; cl < 8; ++cl) { sc[cl] = 0.f; sh[cl] = 0.f; }
    for (int k = 0; k < 8; ++k) {
      if ((m >> k) & 1u) {
#pragma unroll
        for (int cl = 0; cl < 8; ++cl) { sc[cl] += ssc[k][cl]; sh[cl] += ssh[k][cl]; }
      }
    }
    short8 v = *(const short8*)(src + (size_t)p * 8);
    short8 r;
#pragma unroll
    for (int cl = 0; cl < 8; ++cl) {
      float f = bf2f((unsigned short)v[cl]) + EPSF;
      r[cl] = (short)f2bf(f * sc[cl] + sh[cl]);
    }
    *(short8*)(dst + (size_t)p * 8) = r;
  }
}

// ---------------------------------------------------------------------------
static void launch_conv(const unsigned short* act, const unsigned short* wt,
                        const float* bias, unsigned short* out, float* partial,
                        int C, int K, int H, int W, int S, hipStream_t st) {
  dim3 g(W / 16, H / 16, 4 * (K / 64) * S);
  conv3x3_mfma<<<g, 256, 0, st>>>(act, wt, bias, out, partial, C, K, H, W, S);
  if (S > 1) {
    int total8 = 4 * (K >> 3) * H * W;
    combine_bias_relu<<<(total8 + 255) / 256, 256, 0, st>>>(
        partial, bias, out, S, K >> 3, H * W, total8);
  }
}

extern "C" void kernel_launch(void* const* d_in, const int* in_sizes, int n_in,
                              void* d_out, int out_size, void* d_ws, size_t ws_size,
                              hipStream_t stream) {
  const float* f1   = (const float*)d_in[0];
  const float* f2   = (const float*)d_in[1];
  const float* s2lh = (const float*)d_in[2];
  const float* s2hl = (const float*)d_in[3];
  const float* s2hh = (const float*)d_in[4];
  const float* s1lh = (const float*)d_in[5];
  const float* s1hl = (const float*)d_in[6];
  const float* s1hh = (const float*)d_in[7];
  const float* s0lh = (const float*)d_in[8];
  const float* s0hl = (const float*)d_in[9];
  const float* s0hh = (const float*)d_in[10];
  const float* cmask = (const float*)d_in[11];
  const float* smask = (const float*)d_in[12];
  const float* w11 = (const float*)d_in[13]; const float* b11 = (const float*)d_in[14];
  const float* w12 = (const float*)d_in[15]; const float* b12 = (const float*)d_in[16];
  const float* w21 = (const float*)d_in[17]; const float* b21 = (const float*)d_in[18];
  const float* w22 = (const float*)d_in[19]; const float* b22 = (const float*)d_in[20];
  const float* w23 = (const float*)d_in[21]; const float* b23 = (const float*)d_in[22];
  const float* w24 = (const float*)d_in[23]; const float* b24 = (const float*)d_in[24];
  const float* w31 = (const float*)d_in[25]; const float* b31 = (const float*)d_in[26];
  const float* w32 = (const float*)d_in[27]; const float* b32 = (const float*)d_in[28];
  const float* w33 = (const float*)d_in[29]; const float* b33 = (const float*)d_in[30];

  // d_out layout (68,161,536 B total):
  //   A bf16 [0, 16,777,216)   B bf16 [16,777,216, 33,554,432)
  //   P fp32 [33,554,432, 67,108,864)  -- split-C partials (exactly 32 MiB)
  // NOTE: the FINAL kernel writes all of d_out, so its inputs (t12) must
  // live in d_ws, never in d_out (round-7 aliasing lesson).
  unsigned short* A = (unsigned short*)d_out;
  unsigned short* B = A + 8388608;
  float* P = (float*)((char*)d_out + 33554432);

  // workspace layout (bytes)
  char* wsb = (char*)d_ws;
  unsigned short* wtb = (unsigned short*)wsb;          // 5,971,968 elems bf16
  const size_t o11 = 0,        o12 = 2359296, o21 = 3538944, o22 = 4128768,
               o23 = 4718592,  o24 = 5308416, o31 = 5603328, o32 = 5750784,
               o33 = 5898240;                           // total 5,971,968
  unsigned short* f2c = (unsigned short*)(wsb + 11943936);   // 2,097,152 elems
  unsigned* cbits = (unsigned*)(wsb + 16138240);             // 16384 u32
  unsigned* sbits = (unsigned*)(wsb + 16203776);
  float* cstp = (float*)(wsb + 16269312);                    // 4*24*512 = 196,608 B
  float* sstp = (float*)(wsb + 16465920);                    // 4*24*512 = 196,608 B
  float* gstp = (float*)(wsb + 16662528);                    // 4*3*512  =  24,576 B
  float* scal = (float*)(wsb + 16687104);                    // 8*512
  float* shft = (float*)(wsb + 16703488);                    // 8*512
  float* flagc = (float*)(wsb + 16719872);                   // 8
  float* sany  = (float*)(wsb + 16719904);                   // 8
  // t12 (L9 output bf16, 8,388,608 B) overlaps Wt o11..part of o22 — all
  // consumed before L9 runs; wt_prep rewrites them every call.
  unsigned short* t12 = (unsigned short*)wsb;

  const int NC = 512;

  wt_prep<<<(512 * 64 + 255) / 256, 256, 0, stream>>>(w11, wtb + o11, 512, 512);
  wt_prep<<<(256 * 64 + 255) / 256, 256, 0, stream>>>(w12, wtb + o12, 512, 256);
  wt_prep<<<(256 * 32 + 255) / 256, 256, 0, stream>>>(w21, wtb + o21, 256, 256);
  wt_prep<<<(256 * 32 + 255) / 256, 256, 0, stream>>>(w22, wtb + o22, 256, 256);
  wt_prep<<<(256 * 32 + 255) / 256, 256, 0, stream>>>(w23, wtb + o23, 256, 256);
  wt_prep<<<(128 * 32 + 255) / 256, 256, 0, stream>>>(w24, wtb + o24, 256, 128);
  wt_prep<<<(128 * 16 + 255) / 256, 256, 0, stream>>>(w31, wtb + o31, 128, 128);
  wt_prep<<<(128 * 16 + 255) / 256, 256, 0, stream>>>(w32, wtb + o32, 128, 128);
  wt_prep<<<( 64 * 16 + 255) / 256, 256, 0, stream>>>(w33, wtb + o33, 128,  64);

  nchw_to_nc8<<<(262144 + 255) / 256, 256, 0, stream>>>(f2, f2c, 64, 1024, 262144);

  pack_masks<<<64, 256, 0, stream>>>(cmask, smask, cbits, sbits);
  mask_flags<<<8, 1024, 0, stream>>>(cmask, smask, flagc, sany);

  // conv chain (S chosen so every conv == 512 blocks)
  launch_conv(f2c, wtb + o11, b11, A, P, 512, 512, 32, 32, 4, stream);
  launch_conv(A,   wtb + o12, b12, B, P, 512, 256, 32, 32, 8, stream);
  unpool_shift_nc8<<<(524288 + 255) / 256, 256, 0, stream>>>(B, s2lh, s2hl, s2hh, A, 32, 32, 32, 524288);
  launch_conv(A,   wtb + o21, b21, B, P, 256, 256, 64, 64, 2, stream);
  launch_conv(B,   wtb + o22, b22, A, P, 256, 256, 64, 64, 2, stream);
  launch_conv(A,   wtb + o23, b23, B, P, 256, 256, 64, 64, 2, stream);
  launch_conv(B,   wtb + o24, b24, A, P, 256, 128, 64, 64, 4, stream);
  unpool_shift_nc8<<<(1048576 + 255) / 256, 256, 0, stream>>>(A, s1lh, s1hl, s1hh, B, 16, 64, 64, 1048576);

  // AdaIN: content=B (bf16), style=f1 (fp32) -> A
  masked_stats_bf16<<<dim3(512, 4), 256, 0, stream>>>(B, cbits, cstp, NC);
  masked_stats_f32g<<<dim3(512, 4), 256, 0, stream>>>(f1, sbits, sstp, gstp, NC);
  finalize_ss<<<16, 256, 0, stream>>>(cstp, sstp, gstp, flagc, sany, scal, shft, NC);
  adain_apply_nc8<<<dim3(64, 16), 256, 0, stream>>>(B, cbits, scal, shft, A);

  launch_conv(A, wtb + o31, b31, B, P, 128, 128, 128, 128, 1, stream);
  launch_conv(B, wtb + o32, b32, A, P, 128, 128, 128, 128, 1, stream);
  launch_conv(A, wtb + o33, b33, t12, P, 128, 64, 128, 128, 2, stream);

  // final: pair-vectorized unpool + rpad, reads t12 (d_ws) -> all of d_out
  unpool_rpad_final_v2<<<dim3(131, 256), 256, 0, stream>>>(
      t12, s0lh, s0hl, s0hh, (float*)d_out);
}

// Round 10
// 489.861 us; speedup vs baseline: 9.9339x; 1.0300x over previous
//
#include <hip/hip_runtime.h>

#define EPSF 1e-5f

typedef __attribute__((ext_vector_type(8)))  short short8;
typedef __attribute__((ext_vector_type(4)))  float f32x4;
typedef __attribute__((ext_vector_type(16))) float f32x16;

__device__ __forceinline__ unsigned short f2bf(float f) {
  unsigned u = __builtin_bit_cast(unsigned, f);
  unsigned r = (u + 0x7FFFu + ((u >> 16) & 1u)) >> 16;   // RNE
  return (unsigned short)r;
}
__device__ __forceinline__ float bf2f(unsigned short h) {
  unsigned u = ((unsigned)h) << 16;
  return __builtin_bit_cast(float, u);
}

// ---------------------------------------------------------------------------
// Weight pre-transpose: W[K][C][3][3] fp32 -> Wt[tap][C/8][K][8] bf16
// ---------------------------------------------------------------------------
__global__ void wt_prep(const float* __restrict__ w, unsigned short* __restrict__ wt,
                        int C, int K) {
  int C8 = C >> 3;
  int idx = blockIdx.x * 256 + threadIdx.x;
  if (idx >= K * C8) return;
  int k = idx / C8, ch = idx - k * C8;
  const float* src = w + ((size_t)k * C + ch * 8) * 9;
#pragma unroll
  for (int tap = 0; tap < 9; ++tap) {
    short8 v;
#pragma unroll
    for (int cl = 0; cl < 8; ++cl) v[cl] = (short)f2bf(src[cl * 9 + tap]);
    *(short8*)(wt + ((size_t)(tap * C8 + ch) * K + k) * 8) = v;
  }
}

// ---------------------------------------------------------------------------
// fp32 NCHW -> bf16 NC8HW8
// ---------------------------------------------------------------------------
__global__ void nchw_to_nc8(const float* __restrict__ in, unsigned short* __restrict__ out,
                            int C8, int HW, int total) {
  int idx = blockIdx.x * 256 + threadIdx.x;
  if (idx >= total) return;
  int pix = idx % HW; int t = idx / HW; int ch = t % C8; int n = t / C8;
  const float* s = in + ((size_t)(n * C8 + ch) * 8) * HW + pix;
  short8 v;
#pragma unroll
  for (int cl = 0; cl < 8; ++cl) v[cl] = (short)f2bf(s[(size_t)cl * HW]);
  *(short8*)(out + (size_t)idx * 8) = v;
}

// ---------------------------------------------------------------------------
// Conv 3x3 reflect-pad, bf16 MFMA implicit GEMM, split-C + 2-phase prefetch.
// act: NC8HW8 bf16, wt: [9][C/8][K][8] bf16.
// Block: 256 thr = 4 waves, tile 64 out-chans x 256 pixels (16x16).
// Round-10: strength-reduced A/B addressing, A-prefetch depth 1,
// STAGE issued after the last A-load of the chunk (vmcnt in-order safety).
// ---------------------------------------------------------------------------
__global__ __launch_bounds__(256) void conv3x3_mfma(
    const unsigned short* __restrict__ act, const unsigned short* __restrict__ wt,
    const float* __restrict__ bias, unsigned short* __restrict__ out,
    float* __restrict__ partial, int C, int K, int H, int W, int S) {
  const int C8 = C >> 3, K8 = K >> 3;
  const int HW = H * W;
  const int tid = threadIdx.x;
  const int lane = tid & 63, wid = tid >> 6;
  const int l31 = lane & 31, lhi = lane >> 5;
  const int w0 = blockIdx.x * 16, h0 = blockIdx.y * 16;
  const int kbn = K >> 6;
  int zz = blockIdx.z;
  const int sp = zz % S; zz /= S;
  const int kb = zz % kbn;
  const int n  = zz / kbn;
  const int k0 = kb * 64;

  __shared__ __align__(16) unsigned short smem[24576];  // 2 x 1536 slots x 16B
  __shared__ float sbias[64];
  if (tid < 64) sbias[tid] = bias[k0 + tid];

  // staging address precompute: 1296 slots (16B each), padded to 1536
  int g16[6];
#pragma unroll
  for (int it = 0; it < 6; ++it) {
    int slot = it * 256 + wid * 64 + lane;
    int s = slot < 1296 ? slot : 0;
    int chi = s / 324; int r = s - chi * 324;
    int y = r / 18, x = r - y * 18;
    int gy = h0 - 1 + y; gy = gy < 0 ? -gy : (gy >= H ? 2 * H - 2 - gy : gy);
    int gx = w0 - 1 + x; gx = gx < 0 ? -gx : (gx >= W ? 2 * W - 2 - gx : gx);
    g16[it] = ((n * C8 + chi) * H + gy) * W + gx;
  }

  // B-fragment pixel coords (fixed per lane)
  const int pbase = wid * 64;
  int pb[2];
#pragma unroll
  for (int nf = 0; nf < 2; ++nf) {
    int p = pbase + nf * 32 + l31;
    pb[nf] = (p >> 4) * 18 + (p & 15);
  }
  // B base indices (shorts) per (ks,nf), excluding buffer offset; per-tap
  // delta is (ty*18+txx)*8 shorts -> folds to ds_read immediate offsets.
  int bb8[2][2];
#pragma unroll
  for (int ks = 0; ks < 2; ++ks)
#pragma unroll
    for (int nf = 0; nf < 2; ++nf)
      bb8[ks][nf] = ((ks * 2 + lhi) * 324 + pb[nf]) * 8;

  // A rolling pointers per (ks,mf): strength-reduced addressing.
  const size_t tapStep   = (size_t)C8 * K * 8;   // shorts per tap plane
  const size_t chunkStep = (size_t)4 * K * 8;    // shorts per 4-c8row chunk
  const int cps = (C >> 5) / S;                  // chunks per split
  const int c0 = sp * cps;
  const unsigned short* ap[2][2];
#pragma unroll
  for (int ks = 0; ks < 2; ++ks)
#pragma unroll
    for (int mf = 0; mf < 2; ++mf)
      ap[ks][mf] = wt + ((size_t)(c0 * 4) * K
                  + (size_t)((ks * 2 + lhi) * K + k0 + mf * 32 + l31)) * 8;

  f32x16 acc[2][2] = {};

#define STAGE(BSEL, CI)                                                          \
  {                                                                              \
    _Pragma("unroll")                                                            \
    for (int it = 0; it < 6; ++it) {                                             \
      const unsigned short* g = act + ((size_t)g16[it] + (size_t)(CI) * 4 * HW) * 8; \
      __builtin_amdgcn_global_load_lds(                                          \
          (const __attribute__((address_space(1))) unsigned int*)g,              \
          (__attribute__((address_space(3))) unsigned int*)                      \
              &smem[(BSEL) * 12288 + (it * 256 + wid * 64) * 8],                 \
          16, 0, 0);                                                             \
    }                                                                            \
  }

  STAGE(0, c0)

  for (int i = 0; i < cps; ++i) {
    __syncthreads();                       // buf (i&1) staged; prev reads done
    const int boff = (i & 1) * 12288;
    const unsigned short* aw[2][2];
    short8 acur[2][2], anx[2][2];
#pragma unroll
    for (int ks = 0; ks < 2; ++ks)
#pragma unroll
      for (int mf = 0; mf < 2; ++mf) {
        aw[ks][mf] = ap[ks][mf];
        acur[ks][mf] = *(const short8*)aw[ks][mf];     // tap 0
        aw[ks][mf] += tapStep;
      }
#pragma unroll
    for (int tap = 0; tap < 9; ++tap) {
      if (tap < 8) {                       // prefetch tap+1 A-fragments
#pragma unroll
        for (int ks = 0; ks < 2; ++ks)
#pragma unroll
          for (int mf = 0; mf < 2; ++mf) {
            anx[ks][mf] = *(const short8*)aw[ks][mf];
            aw[ks][mf] += tapStep;
          }
      }
      // after the LAST A-issue: no A-wait drains the staging prefetch
      if (tap == 7 && i + 1 < cps) STAGE((i & 1) ^ 1, c0 + i + 1)
      const int ty = tap / 3, txx = tap - ty * 3;
      const int toff = (ty * 18 + txx) * 8;
      short8 b[2][2];
#pragma unroll
      for (int ks = 0; ks < 2; ++ks)
#pragma unroll
        for (int nf = 0; nf < 2; ++nf)
          b[nf][ks] = *(const short8*)&smem[boff + bb8[ks][nf] + toff];
#pragma unroll
      for (int ks = 0; ks < 2; ++ks)
#pragma unroll
        for (int mf = 0; mf < 2; ++mf)
#pragma unroll
          for (int nf = 0; nf < 2; ++nf)
            acc[mf][nf] = __builtin_amdgcn_mfma_f32_32x32x16_bf16(
                acur[ks][mf], b[nf][ks], acc[mf][nf], 0, 0, 0);
#pragma unroll
      for (int ks = 0; ks < 2; ++ks)
#pragma unroll
        for (int mf = 0; mf < 2; ++mf)
          acur[ks][mf] = anx[ks][mf];
    }
#pragma unroll
    for (int ks = 0; ks < 2; ++ks)
#pragma unroll
      for (int mf = 0; mf < 2; ++mf)
        ap[ks][mf] += chunkStep;
  }

  if (S > 1) {
    // fp32 partial write, NC8HW8 ordering; pixel is GLOBAL (h0/w0 applied).
    float* P = partial + (size_t)sp * ((size_t)4 * K * HW);
#pragma unroll
    for (int mf = 0; mf < 2; ++mf)
#pragma unroll
      for (int nf = 0; nf < 2; ++nf) {
        int p = pbase + nf * 32 + l31;
        int gp = (h0 + (p >> 4)) * W + (w0 + (p & 15));
#pragma unroll
        for (int q = 0; q < 4; ++q) {
          size_t ad = ((size_t)(n * K8 + (k0 >> 3) + mf * 4 + q) * HW + gp) * 8 + 4 * lhi;
          f32x4 v = { acc[mf][nf][4 * q], acc[mf][nf][4 * q + 1],
                      acc[mf][nf][4 * q + 2], acc[mf][nf][4 * q + 3] };
          *(f32x4*)(P + ad) = v;
        }
      }
    return;
  }

  // S==1 epilogue: bias + relu + pack bf16 via LDS transpose
  __syncthreads();
#pragma unroll
  for (int mf = 0; mf < 2; ++mf)
#pragma unroll
    for (int nf = 0; nf < 2; ++nf) {
      int pix = pbase + nf * 32 + l31;
#pragma unroll
      for (int rp = 0; rp < 8; ++rp) {
        const int r0 = rp * 2;
        int row0 = (r0 & 3) + 8 * (r0 >> 2) + 4 * lhi;   // row within 32
        int c64 = mf * 32 + row0;
        float v0 = acc[mf][nf][r0]     + sbias[c64];
        float v1 = acc[mf][nf][r0 + 1] + sbias[c64 + 1];
        v0 = v0 > 0.f ? v0 : 0.f;
        v1 = v1 > 0.f ? v1 : 0.f;
        unsigned pk = (unsigned)f2bf(v0) | ((unsigned)f2bf(v1) << 16);
        int chh = mf * 4 + (r0 >> 2);
        int clo = (r0 & 3) + 4 * lhi;
        *(unsigned*)&smem[((chh * 256 + pix) * 8 + clo)] = pk;
      }
    }
  __syncthreads();
#pragma unroll
  for (int i = 0; i < 8; ++i) {
    int slot = i * 256 + tid;           // 2048 slots of 16B
    int ch = slot >> 8;
    int p = slot & 255;
    int py = p >> 4, px = p & 15;
    short8 v = *(const short8*)&smem[slot * 8];
    *(short8*)(out + (((size_t)(n * K8 + (k0 >> 3) + ch) * H + h0 + py) * W + w0 + px) * 8) = v;
  }
#undef STAGE
}

// ---------------------------------------------------------------------------
// combine split-C partials: sum + bias + relu + pack bf16 NC8HW8
// ---------------------------------------------------------------------------
__global__ void combine_bias_relu(const float* __restrict__ P, const float* __restrict__ bias,
                                  unsigned short* __restrict__ out, int S, int K8, int HW,
                                  int total8) {
  int idx = blockIdx.x * 256 + threadIdx.x;
  if (idx >= total8) return;
  int k8 = (idx / HW) % K8;
  const float* p = P + (size_t)idx * 8;
  size_t stride = (size_t)total8 * 8;
  float v[8];
#pragma unroll
  for (int c = 0; c < 8; ++c) v[c] = p[c];
  for (int s = 1; s < S; ++s) {
#pragma unroll
    for (int c = 0; c < 8; ++c) v[c] += p[(size_t)s * stride + c];
  }
  short8 r;
#pragma unroll
  for (int c = 0; c < 8; ++c) {
    float x = v[c] + bias[k8 * 8 + c];
    x = x > 0.f ? x : 0.f;
    r[c] = (short)f2bf(x);
  }
  *(short8*)(out + (size_t)idx * 8) = r;
}

// ---------------------------------------------------------------------------
// Wavelet unpool fused with rpad(1)+crop shift, NC8HW8 bf16 ll / fp32 bands.
// ---------------------------------------------------------------------------
__global__ void unpool_shift_nc8(const unsigned short* __restrict__ ll,
                                 const float* __restrict__ lh, const float* __restrict__ hl,
                                 const float* __restrict__ hh, unsigned short* __restrict__ out,
                                 int C8, int Hh, int Wh, int total) {
  int idx = blockIdx.x * 256 + threadIdx.x;
  if (idx >= total) return;
  const int Ho = 2 * Hh, Wo = 2 * Wh;
  int j = idx % Wo; int t = idx / Wo;
  int i = t % Ho; t /= Ho;
  int ch = t % C8; int n = t / C8;
  int si = (i == 0) ? 1 : i - 1;
  int sj = (j == 0) ? 1 : j - 1;
  float sa = (si & 1) ? 1.f : -1.f;
  float sb = (sj & 1) ? 1.f : -1.f;
  int hy = si >> 1, hx = sj >> 1;
  size_t HWh = (size_t)Hh * Wh;
  const unsigned short* lp = ll + ((size_t)(n * C8 + ch) * HWh + hy * Wh + hx) * 8;
  size_t bb = ((size_t)(n * C8 + ch) * 8 * Hh + hy) * Wh + hx;
  short8 res;
#pragma unroll
  for (int cl = 0; cl < 8; ++cl) {
    float v = 0.5f * (bf2f(lp[cl]) + sb * lh[bb + cl * HWh] + sa * hl[bb + cl * HWh]
                      + sa * sb * hh[bb + cl * HWh]);
    res[cl] = (short)f2bf(v);
  }
  *(short8*)(out + (size_t)idx * 8) = res;
}

// ---------------------------------------------------------------------------
// Final unpool + rpad, pair-vectorized: ll = t12 (bf16 NC8HW8, K=64),
// out fp32 NCHW (4,64,258,258). One thread per (img, row, col-pair).
// ---------------------------------------------------------------------------
__global__ void unpool_rpad_final_v2(const unsigned short* __restrict__ ll,
                                     const float* __restrict__ lh, const float* __restrict__ hl,
                                     const float* __restrict__ hh, float* __restrict__ out) {
  const int img = blockIdx.y;                 // n*64 + c
  int idx = blockIdx.x * 256 + threadIdx.x;   // over 258 rows * 129 pairs
  if (idx >= 258 * 129) return;
  int i = idx / 129, jm = idx - i * 129;
  const int n = img >> 6, c = img & 63;

  int si = (i == 0) ? 1 : i - 1; if (si >= 256) si = 254;
  float sa = (si & 1) ? 1.f : -1.f;
  int hy = si >> 1;
  int hx0 = (jm == 0) ? 0 : jm - 1;
  int hx1 = (jm == 128) ? 127 : jm;

  size_t lb = ((size_t)(n * 8 + (c >> 3)) * 16384 + hy * 128) * 8 + (c & 7);
  float lv0 = bf2f(ll[lb + hx0 * 8]);
  float lv1 = bf2f(ll[lb + hx1 * 8]);

  size_t bb = ((size_t)img * 128 + hy) * 128;
  float l0 = lh[bb + hx0], g0 = hl[bb + hx0], h0 = hh[bb + hx0];
  float l1 = lh[bb + hx1], g1 = hl[bb + hx1], h1 = hh[bb + hx1];
  float o0 = 0.5f * (lv0 + l0 + sa * (g0 + h0));
  float o1 = 0.5f * (lv1 - l1 + sa * (g1 - h1));
  float2 r = make_float2(o0, o1);
  *(float2*)&out[((size_t)img * 258 + i) * 258 + 2 * jm] = r;
}

// ---------------------------------------------------------------------------
// AdaIN support
// ---------------------------------------------------------------------------
__global__ void pack_masks(const float* __restrict__ cmask, const float* __restrict__ smask,
                           unsigned* __restrict__ cbits, unsigned* __restrict__ sbits) {
  int idx = blockIdx.x * 256 + threadIdx.x;
  if (idx >= 16384) return;
  int h = idx >> 7, w = idx & 127;
  unsigned cb = 0, sb = 0;
#pragma unroll
  for (int k = 0; k < 8; ++k) {
    int off = (k * 256 + 2 * h) * 256 + 2 * w;
    if (cmask[off] != 0.f) cb |= (1u << k);
    if (smask[off] != 0.f) sb |= (1u << k);
  }
  cbits[idx] = cb;
  sbits[idx] = sb;
}

// 1024 threads/block, one block per class
__global__ __launch_bounds__(1024) void mask_flags(
    const float* __restrict__ cmask, const float* __restrict__ smask,
    float* __restrict__ flagc, float* __restrict__ sany) {
  int k = blockIdx.x;
  const float* cm = cmask + (size_t)k * 65536;
  const float* sm = smask + (size_t)k * 65536;
  int ca = 0, sa = 0;
  for (int i = threadIdx.x; i < 65536; i += 1024) {
    ca |= (cm[i] != 0.f);
    sa |= (sm[i] != 0.f);
  }
#pragma unroll
  for (int off = 32; off > 0; off >>= 1) {
    ca |= __shfl_xor(ca, off, 64);
    sa |= __shfl_xor(sa, off, 64);
  }
  __shared__ int rc[16], rs[16];
  int wv = threadIdx.x >> 6;
  if ((threadIdx.x & 63) == 0) { rc[wv] = ca; rs[wv] = sa; }
  __syncthreads();
  if (threadIdx.x == 0) {
    int c = 0, s = 0;
#pragma unroll
    for (int i = 0; i < 16; ++i) { c |= rc[i]; s |= rs[i]; }
    flagc[k] = c ? 1.f : 0.f;
    sany[k]  = s ? 1.f : 0.f;
  }
}

// content stats (bf16 NC8HW8), 4-way pixel split via blockIdx.y.
__global__ __launch_bounds__(256) void masked_stats_bf16(
    const unsigned short* __restrict__ feat, const unsigned* __restrict__ bits,
    float* __restrict__ outp, int NC) {
  constexpr int NV = 24;
  int b = blockIdx.x; int n = b >> 7, c = b & 127;
  const int sp = blockIdx.y;
  const unsigned short* f = feat + (size_t)(n * 16 + (c >> 3)) * 16384 * 8 + (c & 7);
  float acc[NV];
#pragma unroll
  for (int j = 0; j < NV; ++j) acc[j] = 0.f;
  const int p0 = sp * 4096;
  for (int it = 0; it < 16; ++it) {
    int i = p0 + it * 256 + threadIdx.x;
    float v = bf2f(f[(size_t)i * 8]) + EPSF;
    float nz = (v != 0.f) ? 1.f : 0.f;
    float v2 = v * v;
    unsigned m = bits[i];
#pragma unroll
    for (int k = 0; k < 8; ++k) {
      float mk = (float)((m >> k) & 1u);
      acc[k * 3 + 0] += mk * nz;
      acc[k * 3 + 1] += mk * v;
      acc[k * 3 + 2] += mk * v2;
    }
  }
#pragma unroll
  for (int j = 0; j < NV; ++j) {
    float v = acc[j];
#pragma unroll
    for (int off = 32; off > 0; off >>= 1) v += __shfl_xor(v, off, 64);
    acc[j] = v;
  }
  __shared__ float red[4][NV];
  int lane = threadIdx.x & 63, wv = threadIdx.x >> 6;
  if (lane == 0) {
#pragma unroll
    for (int j = 0; j < NV; ++j) red[wv][j] = acc[j];
  }
  __syncthreads();
  int tid = threadIdx.x;
  if (tid < NV) {
    float s = red[0][tid] + red[1][tid] + red[2][tid] + red[3][tid];
    outp[(sp * NV + tid) * NC + b] = s;
  }
}

// style stats (fp32 NCHW) + global, 4-way pixel split, float4-vectorized.
__global__ __launch_bounds__(256) void masked_stats_f32g(
    const float* __restrict__ feat, const unsigned* __restrict__ bits,
    float* __restrict__ sstp, float* __restrict__ gstp, int NC) {
  constexpr int NV = 27;
  const int b = blockIdx.x;
  const int sp = blockIdx.y;
  const float* f = feat + (size_t)b * 16384;
  float acc[NV];
#pragma unroll
  for (int j = 0; j < NV; ++j) acc[j] = 0.f;
  const int p0 = sp * 4096;
#pragma unroll 1
  for (int it = 0; it < 4; ++it) {
    int p = p0 + it * 1024 + threadIdx.x * 4;
    float4 v4 = *(const float4*)&f[p];
    uint4 m4 = *(const uint4*)&bits[p];
#pragma unroll
    for (int e = 0; e < 4; ++e) {
      float v = (&v4.x)[e] + EPSF;
      unsigned m = (&m4.x)[e];
      float nz = (v != 0.f) ? 1.f : 0.f;
      float v2 = v * v;
#pragma unroll
      for (int k = 0; k < 8; ++k) {
        float mk = (float)((m >> k) & 1u);
        acc[k * 3 + 0] += mk * nz;
        acc[k * 3 + 1] += mk * v;
        acc[k * 3 + 2] += mk * v2;
      }
      acc[24] += nz; acc[25] += v; acc[26] += v2;
    }
  }
#pragma unroll
  for (int j = 0; j < NV; ++j) {
    float v = acc[j];
#pragma unroll
    for (int off = 32; off > 0; off >>= 1) v += __shfl_xor(v, off, 64);
    acc[j] = v;
  }
  __shared__ float red[4][NV];
  int lane = threadIdx.x & 63, wv = threadIdx.x >> 6;
  if (lane == 0) {
#pragma unroll
    for (int j = 0; j < NV; ++j) red[wv][j] = acc[j];
  }
  __syncthreads();
  int tid = threadIdx.x;
  if (tid < NV) {
    float s = red[0][tid] + red[1][tid] + red[2][tid] + red[3][tid];
    if (tid < 24) sstp[(sp * 24 + tid) * NC + b] = s;
    else gstp[(sp * 3 + (tid - 24)) * NC + b] = s;
  }
}

// sums the 4 pixel-split partials (fixed order -> deterministic)
__global__ void finalize_ss(const float* __restrict__ cstp, const float* __restrict__ sstp,
                            const float* __restrict__ gstp, const float* __restrict__ flagc,
                            const float* __restrict__ sany,
                            float* __restrict__ scal, float* __restrict__ shft, int NC) {
  int idx = blockIdx.x * blockDim.x + threadIdx.x;
  if (idx >= 8 * NC) return;
  int k = idx / NC, b = idx - k * NC;
  bool useg = (sany[k] == 0.f);
  float ccnt = 0.f, cs1 = 0.f, cs2 = 0.f, scnt = 0.f, ss1 = 0.f, ss2 = 0.f;
#pragma unroll
  for (int s = 0; s < 4; ++s) {
    const float* cp = cstp + s * 24 * NC;
    ccnt += cp[(k * 3 + 0) * NC + b];
    cs1  += cp[(k * 3 + 1) * NC + b];
    cs2  += cp[(k * 3 + 2) * NC + b];
    if (useg) {
      const float* gp = gstp + s * 3 * NC;
      scnt += gp[0 * NC + b]; ss1 += gp[1 * NC + b]; ss2 += gp[2 * NC + b];
    } else {
      const float* spp = sstp + s * 24 * NC;
      scnt += spp[(k * 3 + 0) * NC + b];
      ss1  += spp[(k * 3 + 1) * NC + b];
      ss2  += spp[(k * 3 + 2) * NC + b];
    }
  }
  float cmn  = cs1 / fmaxf(ccnt, 1.f);
  float cvv  = (cs2 - ccnt * cmn * cmn) / fmaxf(ccnt - 1.f, 1.f) + EPSF;
  float cstd = sqrtf(cvv);
  float smn  = ss1 / fmaxf(scnt, 1.f);
  float svv  = (ss2 - scnt * smn * smn) / fmaxf(scnt - 1.f, 1.f) + EPSF;
  float sstd = sqrtf(svv);
  float fl = flagc[k];
  float r  = sstd / cstd;
  scal[idx] = fl * r;
  shft[idx] = fl * (smn - cmn * r);
}

// apply: grid (64, 16) — blockIdx.x = (n, c_hi), blockIdx.y = 1024-pixel chunk
__global__ void adain_apply_nc8(const unsigned short* __restrict__ content,
                                const unsigned* __restrict__ bits,
                                const float* __restrict__ scal, const float* __restrict__ shft,
                                unsigned short* __restrict__ out) {
  int ch = blockIdx.x & 15, n = blockIdx.x >> 4;
  __shared__ float ssc[8][8], ssh[8][8];
  if (threadIdx.x < 64) {
    int k = threadIdx.x >> 3, cl = threadIdx.x & 7;
    int c = ch * 8 + cl;
    ssc[k][cl] = scal[k * 512 + n * 128 + c];
    ssh[k][cl] = shft[k * 512 + n * 128 + c];
  }
  __syncthreads();
  const unsigned short* src = content + (size_t)blockIdx.x * 16384 * 8;
  unsigned short* dst = out + (size_t)blockIdx.x * 16384 * 8;
  const int p0 = blockIdx.y * 1024;
  for (int p = p0 + threadIdx.x; p < p0 + 1024; p += 256) {
    unsigned m = bits[p];
    float sc[8], sh[8];
#pragma unroll
    for (int cl = 0; cl < 8; ++cl) { sc[cl] = 0.f; sh[cl] = 0.f; }
    for (int k = 0; k < 8; ++k) {
      if ((m >> k) & 1u) {
#pragma unroll
        for (int cl = 0; cl < 8; ++cl) { sc[cl] += ssc[k][cl]; sh[cl] += ssh[k][cl]; }
      }
    }
    short8 v = *(const short8*)(src + (size_t)p * 8);
    short8 r;
#pragma unroll
    for (int cl = 0; cl < 8; ++cl) {
      float f = bf2f((unsigned short)v[cl]) + EPSF;
      r[cl] = (short)f2bf(f * sc[cl] + sh[cl]);
    }
    *(short8*)(dst + (size_t)p * 8) = r;
  }
}

// ---------------------------------------------------------------------------
static void launch_conv(const unsigned short* act, const unsigned short* wt,
                        const float* bias, unsigned short* out, float* partial,
                        int C, int K, int H, int W, int S, hipStream_t st) {
  dim3 g(W / 16, H / 16, 4 * (K / 64) * S);
  conv3x3_mfma<<<g, 256, 0, st>>>(act, wt, bias, out, partial, C, K, H, W, S);
  if (S > 1) {
    int total8 = 4 * (K >> 3) * H * W;
    combine_bias_relu<<<(total8 + 255) / 256, 256, 0, st>>>(
        partial, bias, out, S, K >> 3, H * W, total8);
  }
}

extern "C" void kernel_launch(void* const* d_in, const int* in_sizes, int n_in,
                              void* d_out, int out_size, void* d_ws, size_t ws_size,
                              hipStream_t stream) {
  const float* f1   = (const float*)d_in[0];
  const float* f2   = (const float*)d_in[1];
  const float* s2lh = (const float*)d_in[2];
  const float* s2hl = (const float*)d_in[3];
  const float* s2hh = (const float*)d_in[4];
  const float* s1lh = (const float*)d_in[5];
  const float* s1hl = (const float*)d_in[6];
  const float* s1hh = (const float*)d_in[7];
  const float* s0lh = (const float*)d_in[8];
  const float* s0hl = (const float*)d_in[9];
  const float* s0hh = (const float*)d_in[10];
  const float* cmask = (const float*)d_in[11];
  const float* smask = (const float*)d_in[12];
  const float* w11 = (const float*)d_in[13]; const float* b11 = (const float*)d_in[14];
  const float* w12 = (const float*)d_in[15]; const float* b12 = (const float*)d_in[16];
  const float* w21 = (const float*)d_in[17]; const float* b21 = (const float*)d_in[18];
  const float* w22 = (const float*)d_in[19]; const float* b22 = (const float*)d_in[20];
  const float* w23 = (const float*)d_in[21]; const float* b23 = (const float*)d_in[22];
  const float* w24 = (const float*)d_in[23]; const float* b24 = (const float*)d_in[24];
  const float* w31 = (const float*)d_in[25]; const float* b31 = (const float*)d_in[26];
  const float* w32 = (const float*)d_in[27]; const float* b32 = (const float*)d_in[28];
  const float* w33 = (const float*)d_in[29]; const float* b33 = (const float*)d_in[30];

  // d_out layout (68,161,536 B total):
  //   A bf16 [0, 16,777,216)   B bf16 [16,777,216, 33,554,432)
  //   P fp32 [33,554,432, 67,108,864)  -- split-C partials (exactly 32 MiB)
  // NOTE: the FINAL kernel writes all of d_out, so its inputs (t12) must
  // live in d_ws, never in d_out (round-7 aliasing lesson).
  unsigned short* A = (unsigned short*)d_out;
  unsigned short* B = A + 8388608;
  float* P = (float*)((char*)d_out + 33554432);

  // workspace layout (bytes)
  char* wsb = (char*)d_ws;
  unsigned short* wtb = (unsigned short*)wsb;          // 5,971,968 elems bf16
  const size_t o11 = 0,        o12 = 2359296, o21 = 3538944, o22 = 4128768,
               o23 = 4718592,  o24 = 5308416, o31 = 5603328, o32 = 5750784,
               o33 = 5898240;                           // total 5,971,968
  unsigned short* f2c = (unsigned short*)(wsb + 11943936);   // 2,097,152 elems
  unsigned* cbits = (unsigned*)(wsb + 16138240);             // 16384 u32
  unsigned* sbits = (unsigned*)(wsb + 16203776);
  float* cstp = (float*)(wsb + 16269312);                    // 4*24*512
  float* sstp = (float*)(wsb + 16465920);                    // 4*24*512
  float* gstp = (float*)(wsb + 16662528);                    // 4*3*512
  float* scal = (float*)(wsb + 16687104);                    // 8*512
  float* shft = (float*)(wsb + 16703488);                    // 8*512
  float* flagc = (float*)(wsb + 16719872);                   // 8
  float* sany  = (float*)(wsb + 16719904);                   // 8
  // t12 (L9 output bf16, 8,388,608 B) overlaps Wt o11..part of o22 — all
  // consumed before L9 runs; wt_prep rewrites them every call.
  unsigned short* t12 = (unsigned short*)wsb;

  const int NC = 512;

  wt_prep<<<(512 * 64 + 255) / 256, 256, 0, stream>>>(w11, wtb + o11, 512, 512);
  wt_prep<<<(256 * 64 + 255) / 256, 256, 0, stream>>>(w12, wtb + o12, 512, 256);
  wt_prep<<<(256 * 32 + 255) / 256, 256, 0, stream>>>(w21, wtb + o21, 256, 256);
  wt_prep<<<(256 * 32 + 255) / 256, 256, 0, stream>>>(w22, wtb + o22, 256, 256);
  wt_prep<<<(256 * 32 + 255) / 256, 256, 0, stream>>>(w23, wtb + o23, 256, 256);
  wt_prep<<<(128 * 32 + 255) / 256, 256, 0, stream>>>(w24, wtb + o24, 256, 128);
  wt_prep<<<(128 * 16 + 255) / 256, 256, 0, stream>>>(w31, wtb + o31, 128, 128);
  wt_prep<<<(128 * 16 + 255) / 256, 256, 0, stream>>>(w32, wtb + o32, 128, 128);
  wt_prep<<<( 64 * 16 + 255) / 256, 256, 0, stream>>>(w33, wtb + o33, 128,  64);

  nchw_to_nc8<<<(262144 + 255) / 256, 256, 0, stream>>>(f2, f2c, 64, 1024, 262144);

  pack_masks<<<64, 256, 0, stream>>>(cmask, smask, cbits, sbits);
  mask_flags<<<8, 1024, 0, stream>>>(cmask, smask, flagc, sany);

  // conv chain (S chosen so every conv == 512 blocks)
  launch_conv(f2c, wtb + o11, b11, A, P, 512, 512, 32, 32, 4, stream);
  launch_conv(A,   wtb + o12, b12, B, P, 512, 256, 32, 32, 8, stream);
  unpool_shift_nc8<<<(524288 + 255) / 256, 256, 0, stream>>>(B, s2lh, s2hl, s2hh, A, 32, 32, 32, 524288);
  launch_conv(A,   wtb + o21, b21, B, P, 256, 256, 64, 64, 2, stream);
  launch_conv(B,   wtb + o22, b22, A, P, 256, 256, 64, 64, 2, stream);
  launch_conv(A,   wtb + o23, b23, B, P, 256, 256, 64, 64, 2, stream);
  launch_conv(B,   wtb + o24, b24, A, P, 256, 128, 64, 64, 4, stream);
  unpool_shift_nc8<<<(1048576 + 255) / 256, 256, 0, stream>>>(A, s1lh, s1hl, s1hh, B, 16, 64, 64, 1048576);

  // AdaIN: content=B (bf16), style=f1 (fp32) -> A
  masked_stats_bf16<<<dim3(512, 4), 256, 0, stream>>>(B, cbits, cstp, NC);
  masked_stats_f32g<<<dim3(512, 4), 256, 0, stream>>>(f1, sbits, sstp, gstp, NC);
  finalize_ss<<<16, 256, 0, stream>>>(cstp, sstp, gstp, flagc, sany, scal, shft, NC);
  adain_apply_nc8<<<dim3(64, 16), 256, 0, stream>>>(B, cbits, scal, shft, A);

  launch_conv(A, wtb + o31, b31, B, P, 128, 128, 128, 128, 1, stream);
  launch_conv(B, wtb + o32, b32, A, P, 128, 128, 128, 128, 1, stream);
  launch_conv(A, wtb + o33, b33, t12, P, 128, 64, 128, 128, 2, stream);

  // final: pair-vectorized unpool + rpad, reads t12 (d_ws) -> all of d_out
  unpool_rpad_final_v2<<<dim3(131, 256), 256, 0, stream>>>(
      t12, s0lh, s0hl, s0hh, (float*)d_out);
}